// Round 1
// baseline (515.114 us; speedup 1.0000x reference)
//
#include <hip/hip_runtime.h>
#include <hip/hip_bf16.h>

static constexpr int HEADS = 8;
static constexpr int HID = 32;
static constexpr int D1 = 256;      // HEADS*HID
static constexpr int ODIM = 64;
static constexpr float NEG = 0.2f;

__device__ __forceinline__ float lrelu(float x) { return fmaxf(x, NEG * x); }
__device__ __forceinline__ float elu1(float x) { return x > 0.f ? x : expm1f(x); }

// ---------------- CSR build ----------------
__global__ void k_zero(int* __restrict__ p, int n) {
  int i = blockIdx.x * blockDim.x + threadIdx.x;
  if (i < n) p[i] = 0;
}

__global__ void k_hist(const int* __restrict__ dst, int E, int TE, int* __restrict__ deg) {
  int i = blockIdx.x * blockDim.x + threadIdx.x;
  if (i >= TE) return;
  int d = (i < E) ? dst[i] : (i - E);
  atomicAdd(&deg[d], 1);
}

__global__ void k_scan1(const int* __restrict__ deg, int n,
                        int* __restrict__ excl, int* __restrict__ partial) {
  __shared__ int sm[256];
  int i = blockIdx.x * 256 + threadIdx.x;
  int v = (i < n) ? deg[i] : 0;
  sm[threadIdx.x] = v;
  __syncthreads();
  for (int off = 1; off < 256; off <<= 1) {
    int t = (threadIdx.x >= off) ? sm[threadIdx.x - off] : 0;
    __syncthreads();
    sm[threadIdx.x] += t;
    __syncthreads();
  }
  if (i < n) excl[i] = sm[threadIdx.x] - v;
  if (threadIdx.x == 255) partial[blockIdx.x] = sm[255];
}

__global__ void k_scan2(int* __restrict__ partial, int nb) {
  __shared__ int sm[256];
  int v = (threadIdx.x < nb) ? partial[threadIdx.x] : 0;
  sm[threadIdx.x] = v;
  __syncthreads();
  for (int off = 1; off < 256; off <<= 1) {
    int t = (threadIdx.x >= off) ? sm[threadIdx.x - off] : 0;
    __syncthreads();
    sm[threadIdx.x] += t;
    __syncthreads();
  }
  if (threadIdx.x < nb) partial[threadIdx.x] = sm[threadIdx.x] - v;  // exclusive
}

__global__ void k_scan3(const int* __restrict__ excl, const int* __restrict__ partial,
                        int n, int TE, int* __restrict__ offs, int* __restrict__ cursor) {
  int i = blockIdx.x * 256 + threadIdx.x;
  if (i < n) {
    int o = excl[i] + partial[i >> 8];
    offs[i] = o;
    cursor[i] = o;
  }
  if (i == 0) offs[n] = TE;
}

__global__ void k_scatter(const int* __restrict__ src, const int* __restrict__ dst,
                          int E, int TE, int* __restrict__ cursor, int* __restrict__ csr_src) {
  int i = blockIdx.x * blockDim.x + threadIdx.x;
  if (i >= TE) return;
  int s, d;
  if (i < E) { s = src[i]; d = dst[i]; } else { s = i - E; d = i - E; }
  int p = atomicAdd(&cursor[d], 1);
  csr_src[p] = s;
}

// ---------------- fp32 GEMM: C[M,N] = A[M,K] @ B[K,N] ----------------
// BM=128, BN=64, BK=16, 256 threads, 8x4 per thread.
__global__ __launch_bounds__(256) void k_gemm(const float* __restrict__ A,
                                              const float* __restrict__ B,
                                              float* __restrict__ C,
                                              int M, int N, int K) {
  __shared__ float As[16][136];  // [k][m], row stride 136 floats (544B, 16B-aligned)
  __shared__ float Bs[16][64];
  const int bm = blockIdx.x * 128;
  const int bn = blockIdx.y * 64;
  const int tid = threadIdx.x;
  const int tx = tid & 15;   // col group (4 cols)
  const int ty = tid >> 4;   // row group (8 rows)
  float acc[8][4] = {};
  for (int k0 = 0; k0 < K; k0 += 16) {
#pragma unroll
    for (int q = 0; q < 2; ++q) {
      int idx = tid + q * 256;          // 0..511
      int r = idx >> 2;                 // 0..127
      int kk = (idx & 3) * 4;
      float4 av = make_float4(0.f, 0.f, 0.f, 0.f);
      int gr = bm + r;
      if (gr < M) av = *(const float4*)&A[(size_t)gr * K + k0 + kk];
      As[kk + 0][r] = av.x; As[kk + 1][r] = av.y;
      As[kk + 2][r] = av.z; As[kk + 3][r] = av.w;
    }
    {
      int k = tid >> 4;
      int n4 = (tid & 15) * 4;
      *(float4*)&Bs[k][n4] = *(const float4*)&B[(size_t)(k0 + k) * N + bn + n4];
    }
    __syncthreads();
#pragma unroll
    for (int k = 0; k < 16; ++k) {
      float4 a0 = *(const float4*)&As[k][ty * 8];
      float4 a1 = *(const float4*)&As[k][ty * 8 + 4];
      float4 b = *(const float4*)&Bs[k][tx * 4];
      float ar[8] = {a0.x, a0.y, a0.z, a0.w, a1.x, a1.y, a1.z, a1.w};
#pragma unroll
      for (int i2 = 0; i2 < 8; ++i2) {
        acc[i2][0] += ar[i2] * b.x;
        acc[i2][1] += ar[i2] * b.y;
        acc[i2][2] += ar[i2] * b.z;
        acc[i2][3] += ar[i2] * b.w;
      }
    }
    __syncthreads();
  }
#pragma unroll
  for (int i2 = 0; i2 < 8; ++i2) {
    int row = bm + ty * 8 + i2;
    if (row < M) {
      float4 v = make_float4(acc[i2][0], acc[i2][1], acc[i2][2], acc[i2][3]);
      *(float4*)&C[(size_t)row * N + bn + tx * 4] = v;
    }
  }
}

// ---------------- per-node attention coefficients ----------------
// layer 1: one wave per node; lane = (head 0..7) x (chan-group 0..7, 4 ch each)
__global__ void k_alpha1(const float* __restrict__ h, const float* __restrict__ a_src,
                         const float* __restrict__ a_dst, int n,
                         float* __restrict__ asrc, float* __restrict__ adst) {
  int wave = (blockIdx.x * blockDim.x + threadIdx.x) >> 6;
  int lane = threadIdx.x & 63;
  if (wave >= n) return;
  int hh = lane >> 3;
  int cg = lane & 7;
  int base = hh * 32 + cg * 4;
  float4 hv = *(const float4*)&h[(size_t)wave * D1 + base];
  float4 as = *(const float4*)&a_src[base];
  float4 ad = *(const float4*)&a_dst[base];
  float ps = hv.x * as.x + hv.y * as.y + hv.z * as.z + hv.w * as.w;
  float pd = hv.x * ad.x + hv.y * ad.y + hv.z * ad.z + hv.w * ad.w;
#pragma unroll
  for (int off = 1; off < 8; off <<= 1) {
    ps += __shfl_xor(ps, off);
    pd += __shfl_xor(pd, off);
  }
  if (cg == 0) { asrc[wave * 8 + hh] = ps; adst[wave * 8 + hh] = pd; }
}

// layer 2: one wave per node; lane = channel 0..63
__global__ void k_alpha2(const float* __restrict__ h, const float* __restrict__ a_src,
                         const float* __restrict__ a_dst, int n,
                         float* __restrict__ asrc, float* __restrict__ adst) {
  int wave = (blockIdx.x * blockDim.x + threadIdx.x) >> 6;
  int lane = threadIdx.x & 63;
  if (wave >= n) return;
  float hv = h[(size_t)wave * ODIM + lane];
  float ps = hv * a_src[lane];
  float pd = hv * a_dst[lane];
#pragma unroll
  for (int off = 1; off < 64; off <<= 1) {
    ps += __shfl_xor(ps, off);
    pd += __shfl_xor(pd, off);
  }
  if (lane == 0) { asrc[wave] = ps; adst[wave] = pd; }
}

// ---------------- segment-softmax stats (max, 1/sum) ----------------
__global__ void k_stats(const int* __restrict__ offs, const int* __restrict__ csr_src,
                        const float* __restrict__ asrc, const float* __restrict__ adst,
                        int n, int H, float* __restrict__ mo, float* __restrict__ iso) {
  int t = blockIdx.x * blockDim.x + threadIdx.x;
  if (t >= n * H) return;
  int node = t / H, h = t - (t / H) * H;
  int b = offs[node], e2 = offs[node + 1];
  float ad = adst[node * H + h];
  float m = -1e30f;
  for (int i = b; i < e2; ++i) {
    float lg = lrelu(asrc[csr_src[i] * H + h] + ad);
    m = fmaxf(m, lg);
  }
  float s = 0.f;
  for (int i = b; i < e2; ++i) {
    float lg = lrelu(asrc[csr_src[i] * H + h] + ad);
    s += __expf(lg - m);
  }
  mo[node * H + h] = m;
  iso[node * H + h] = 1.f / s;
}

// ---------------- layer-1 aggregation + bias + ELU ----------------
// one wave per dst node; lane = (head, chan-group of 4)
__global__ void k_agg1(const int* __restrict__ offs, const int* __restrict__ csr_src,
                       const float* __restrict__ h1, const float* __restrict__ asrc,
                       const float* __restrict__ adst, const float* __restrict__ m1,
                       const float* __restrict__ is1, const float* __restrict__ b1,
                       int n, float* __restrict__ helu) {
  int wave = (blockIdx.x * blockDim.x + threadIdx.x) >> 6;
  int lane = threadIdx.x & 63;
  if (wave >= n) return;
  int hh = lane >> 3;
  int cg = lane & 7;
  int hb = hh * 32 + cg * 4;
  float ad = adst[wave * 8 + hh];
  float m = m1[wave * 8 + hh];
  float is = is1[wave * 8 + hh];
  float4 acc = make_float4(0.f, 0.f, 0.f, 0.f);
  int b = offs[wave], e2 = offs[wave + 1];
  for (int i = b; i < e2; ++i) {
    int s = csr_src[i];
    float w = __expf(lrelu(asrc[s * 8 + hh] + ad) - m) * is;
    float4 hv = *(const float4*)&h1[(size_t)s * D1 + hb];
    acc.x += w * hv.x; acc.y += w * hv.y;
    acc.z += w * hv.z; acc.w += w * hv.w;
  }
  float4 bb = *(const float4*)&b1[hb];
  float4 o;
  o.x = elu1(acc.x + bb.x);
  o.y = elu1(acc.y + bb.y);
  o.z = elu1(acc.z + bb.z);
  o.w = elu1(acc.w + bb.w);
  *(float4*)&helu[(size_t)wave * D1 + hb] = o;
}

// ---------------- layer-2 aggregation + bias ----------------
// one wave per dst node; lane = channel 0..63
__global__ void k_agg2(const int* __restrict__ offs, const int* __restrict__ csr_src,
                       const float* __restrict__ h2, const float* __restrict__ asrc,
                       const float* __restrict__ adst, const float* __restrict__ m2,
                       const float* __restrict__ is2, const float* __restrict__ b2,
                       int n, float* __restrict__ out) {
  int wave = (blockIdx.x * blockDim.x + threadIdx.x) >> 6;
  int lane = threadIdx.x & 63;
  if (wave >= n) return;
  float ad = adst[wave], m = m2[wave], is = is2[wave];
  float acc = 0.f;
  int b = offs[wave], e2 = offs[wave + 1];
  for (int i = b; i < e2; ++i) {
    int s = csr_src[i];
    float w = __expf(lrelu(asrc[s] + ad) - m) * is;
    acc += w * h2[(size_t)s * ODIM + lane];
  }
  out[(size_t)wave * ODIM + lane] = acc + b2[lane];
}

extern "C" void kernel_launch(void* const* d_in, const int* in_sizes, int n_in,
                              void* d_out, int out_size, void* d_ws, size_t ws_size,
                              hipStream_t stream) {
  const float* x     = (const float*)d_in[0];
  const int* eidx    = (const int*)d_in[1];
  const float* W1    = (const float*)d_in[2];
  const float* asrc1w = (const float*)d_in[3];
  const float* adst1w = (const float*)d_in[4];
  const float* b1    = (const float*)d_in[5];
  const float* W2    = (const float*)d_in[6];
  const float* asrc2w = (const float*)d_in[7];
  const float* adst2w = (const float*)d_in[8];
  const float* b2    = (const float*)d_in[9];
  float* out = (float*)d_out;

  const int N = in_sizes[0] / D1;     // 50000
  const int E = in_sizes[1] / 2;      // 800000
  const int TE = E + N;               // with self-loops
  const int* src = eidx;
  const int* dst = eidx + E;

  // ---- workspace carve-up ----
  char* ws = (char*)d_ws;
  size_t off = 0;
  auto carve = [&](size_t bytes) -> char* {
    char* p = ws + off;
    off = (off + bytes + 255) & ~(size_t)255;
    return p;
  };
  float* h1    = (float*)carve((size_t)N * D1 * 4);
  float* helu  = (float*)carve((size_t)N * D1 * 4);
  float* h2    = (float*)carve((size_t)N * ODIM * 4);
  float* asrc1 = (float*)carve((size_t)N * HEADS * 4);
  float* adst1 = (float*)carve((size_t)N * HEADS * 4);
  float* m1    = (float*)carve((size_t)N * HEADS * 4);
  float* is1   = (float*)carve((size_t)N * HEADS * 4);
  float* asrc2 = (float*)carve((size_t)N * 4);
  float* adst2 = (float*)carve((size_t)N * 4);
  float* m2    = (float*)carve((size_t)N * 4);
  float* is2   = (float*)carve((size_t)N * 4);
  int* deg     = (int*)carve((size_t)N * 4);
  int* offs    = (int*)carve((size_t)(N + 1) * 4);
  int* cursor  = (int*)carve((size_t)N * 4);
  int* partial = (int*)carve(1024);
  int* csr_src = (int*)carve((size_t)TE * 4);

  const int nb_n = (N + 255) / 256;       // blocks covering N
  const int nb_te = (TE + 255) / 256;     // blocks covering TE

  // ---- CSR build (by dst) ----
  k_zero<<<nb_n, 256, 0, stream>>>(deg, N);
  k_hist<<<nb_te, 256, 0, stream>>>(dst, E, TE, deg);
  k_scan1<<<nb_n, 256, 0, stream>>>(deg, N, cursor /*excl temp*/, partial);
  k_scan2<<<1, 256, 0, stream>>>(partial, nb_n);
  k_scan3<<<nb_n, 256, 0, stream>>>(cursor, partial, N, TE, offs, cursor);
  k_scatter<<<nb_te, 256, 0, stream>>>(src, dst, E, TE, cursor, csr_src);

  // ---- layer 1 ----
  {
    dim3 g((N + 127) / 128, D1 / 64);
    k_gemm<<<g, 256, 0, stream>>>(x, W1, h1, N, D1, D1);
  }
  k_alpha1<<<(N + 3) / 4, 256, 0, stream>>>(h1, asrc1w, adst1w, N, asrc1, adst1);
  k_stats<<<(N * HEADS + 255) / 256, 256, 0, stream>>>(offs, csr_src, asrc1, adst1,
                                                       N, HEADS, m1, is1);
  k_agg1<<<(N + 3) / 4, 256, 0, stream>>>(offs, csr_src, h1, asrc1, adst1, m1, is1,
                                          b1, N, helu);

  // ---- layer 2 ----
  {
    dim3 g((N + 127) / 128, ODIM / 64);
    k_gemm<<<g, 256, 0, stream>>>(helu, W2, h2, N, ODIM, D1);
  }
  k_alpha2<<<(N + 3) / 4, 256, 0, stream>>>(h2, asrc2w, adst2w, N, asrc2, adst2);
  k_stats<<<(N + 255) / 256, 256, 0, stream>>>(offs, csr_src, asrc2, adst2,
                                               N, 1, m2, is2);
  k_agg2<<<(N + 3) / 4, 256, 0, stream>>>(offs, csr_src, h2, asrc2, adst2, m2, is2,
                                          b2, N, out);
}

// Round 2
// 428.303 us; speedup vs baseline: 1.2027x; 1.2027x over previous
//
#include <hip/hip_runtime.h>
#include <hip/hip_bf16.h>

static constexpr int HEADS = 8;
static constexpr int D1 = 256;      // HEADS*HID
static constexpr int ODIM = 64;
static constexpr float NEG = 0.2f;

typedef __attribute__((ext_vector_type(8))) short bf16x8;
typedef __attribute__((ext_vector_type(4))) float f32x4;

__device__ __forceinline__ float lrelu(float x) { return fmaxf(x, NEG * x); }
__device__ __forceinline__ float elu1(float x) { return x > 0.f ? x : expm1f(x); }

__device__ __forceinline__ unsigned short f2bf(float f) {
  unsigned u = __float_as_uint(f);
  unsigned r = (u + 0x7fffu + ((u >> 16) & 1u)) >> 16;
  return (unsigned short)r;
}
__device__ __forceinline__ float bf2f(unsigned short h) {
  return __uint_as_float((unsigned)h << 16);
}

__device__ __forceinline__ void gload_lds16(const void* g, void* l) {
  __builtin_amdgcn_global_load_lds(
      (const __attribute__((address_space(1))) void*)g,
      (__attribute__((address_space(3))) void*)l, 16, 0, 0);
}

// ---------------- CSR build ----------------
__global__ void k_zero(int* __restrict__ p, int n) {
  int i = blockIdx.x * blockDim.x + threadIdx.x;
  if (i < n) p[i] = 0;
}

__global__ void k_hist(const int* __restrict__ dst, int E, int TE, int* __restrict__ deg) {
  int i = blockIdx.x * blockDim.x + threadIdx.x;
  if (i >= TE) return;
  int d = (i < E) ? dst[i] : (i - E);
  atomicAdd(&deg[d], 1);
}

__global__ void k_scan1(const int* __restrict__ deg, int n,
                        int* __restrict__ excl, int* __restrict__ partial) {
  __shared__ int sm[256];
  int i = blockIdx.x * 256 + threadIdx.x;
  int v = (i < n) ? deg[i] : 0;
  sm[threadIdx.x] = v;
  __syncthreads();
  for (int off = 1; off < 256; off <<= 1) {
    int t = (threadIdx.x >= off) ? sm[threadIdx.x - off] : 0;
    __syncthreads();
    sm[threadIdx.x] += t;
    __syncthreads();
  }
  if (i < n) excl[i] = sm[threadIdx.x] - v;
  if (threadIdx.x == 255) partial[blockIdx.x] = sm[255];
}

__global__ void k_scan2(int* __restrict__ partial, int nb) {
  __shared__ int sm[256];
  int v = (threadIdx.x < nb) ? partial[threadIdx.x] : 0;
  sm[threadIdx.x] = v;
  __syncthreads();
  for (int off = 1; off < 256; off <<= 1) {
    int t = (threadIdx.x >= off) ? sm[threadIdx.x - off] : 0;
    __syncthreads();
    sm[threadIdx.x] += t;
    __syncthreads();
  }
  if (threadIdx.x < nb) partial[threadIdx.x] = sm[threadIdx.x] - v;  // exclusive
}

__global__ void k_scan3(const int* __restrict__ excl, const int* __restrict__ partial,
                        int n, int TE, int* __restrict__ offs, int* __restrict__ cursor) {
  int i = blockIdx.x * 256 + threadIdx.x;
  if (i < n) {
    int o = excl[i] + partial[i >> 8];
    offs[i] = o;
    cursor[i] = o;
  }
  if (i == 0) offs[n] = TE;
}

__global__ void k_scatter(const int* __restrict__ src, const int* __restrict__ dst,
                          int E, int TE, int* __restrict__ cursor, int* __restrict__ csr_src) {
  int i = blockIdx.x * blockDim.x + threadIdx.x;
  if (i >= TE) return;
  int s, d;
  if (i < E) { s = src[i]; d = dst[i]; } else { s = i - E; d = i - E; }
  int p = atomicAdd(&cursor[d], 1);
  csr_src[p] = s;
}

// ---------------- split-bf16 operand prep ----------------
// A2[m][0..255] = hi(x), A2[m][256..511] = lo(x).   [Mpad][512]
__global__ void k_splitA(const float* __restrict__ X, unsigned short* __restrict__ A2, int M) {
  int t = blockIdx.x * blockDim.x + threadIdx.x;
  if (t >= M * 64) return;
  int m = t >> 6, c4 = (t & 63) * 4;
  float4 v = *(const float4*)&X[(size_t)m * 256 + c4];
  float vv[4] = {v.x, v.y, v.z, v.w};
  unsigned short hi[4], lo[4];
#pragma unroll
  for (int j = 0; j < 4; ++j) {
    hi[j] = f2bf(vv[j]);
    lo[j] = f2bf(vv[j] - bf2f(hi[j]));
  }
  *(ushort4*)&A2[(size_t)m * 512 + c4] = make_ushort4(hi[0], hi[1], hi[2], hi[3]);
  *(ushort4*)&A2[(size_t)m * 512 + 256 + c4] = make_ushort4(lo[0], lo[1], lo[2], lo[3]);
}

// B2T[n][k]: k<256 -> hi(W[k][n]); 256..511 -> lo(W[k-256][n]); 512..767 -> hi(W[k-512][n])
__global__ void k_splitB(const float* __restrict__ W, unsigned short* __restrict__ B2T) {
  int t = blockIdx.x * blockDim.x + threadIdx.x;
  if (t >= 256 * 256) return;
  int k = t >> 8, n = t & 255;
  float v = W[k * 256 + n];
  unsigned short hi = f2bf(v);
  unsigned short lo = f2bf(v - bf2f(hi));
  B2T[(size_t)n * 768 + k] = hi;
  B2T[(size_t)n * 768 + 256 + k] = lo;
  B2T[(size_t)n * 768 + 512 + k] = hi;
}

// ---------------- MFMA GEMM: C[M,256] = splitA @ splitB (3-term bf16) ----------------
// BM=128, BN=64, BK=64, 256 threads = 4 waves (2x2), wave tile 64x32.
__global__ __launch_bounds__(256) void k_gemm_mfma(
    const unsigned short* __restrict__ A2,   // [Mpad][512]
    const unsigned short* __restrict__ B2T,  // [256][768]
    float* __restrict__ C, int M, int N) {
  __shared__ __align__(128) char As[16384];  // [128 rows][128B], XOR-swizzled
  __shared__ __align__(128) char Bs[8192];   // [64 cols][128B], XOR-swizzled
  const int tid = threadIdx.x;
  const int lane = tid & 63;
  const int wid = tid >> 6;
  const int bm = blockIdx.x * 128;
  const int bn = blockIdx.y * 64;
  const int wm = wid >> 1, wn = wid & 1;
  f32x4 acc[4][2] = {};
  for (int kb = 0; kb < 768; kb += 64) {
    int a_k0 = kb < 256 ? kb : kb - 256;
    // stage A: linear LDS dest, pre-swizzled global source (involution XOR)
#pragma unroll
    for (int q = 0; q < 4; ++q) {
      int c = q * 256 + tid;
      int r = c >> 3;                          // 0..127
      int b = ((c & 7) * 16) ^ ((r & 7) << 4); // in-row byte
      const void* g = A2 + (size_t)(bm + r) * 512 + a_k0 + (b >> 1);
      void* l = As + (size_t)(q * 256 + (tid & ~63)) * 16;
      gload_lds16(g, l);
    }
#pragma unroll
    for (int q = 0; q < 2; ++q) {
      int c = q * 256 + tid;
      int col = c >> 3;                        // 0..63
      int b = ((c & 7) * 16) ^ ((col & 7) << 4);
      const void* g = B2T + (size_t)(bn + col) * 768 + kb + (b >> 1);
      void* l = Bs + (size_t)(q * 256 + (tid & ~63)) * 16;
      gload_lds16(g, l);
    }
    __syncthreads();
#pragma unroll
    for (int ks = 0; ks < 2; ++ks) {
      bf16x8 af[4], bfr[2];
      int bb = ks * 64 + (lane >> 4) * 16;
#pragma unroll
      for (int mi = 0; mi < 4; ++mi) {
        int row = wm * 64 + mi * 16 + (lane & 15);
        af[mi] = *(const bf16x8*)(As + row * 128 + (bb ^ ((row & 7) << 4)));
      }
#pragma unroll
      for (int ni = 0; ni < 2; ++ni) {
        int col = wn * 32 + ni * 16 + (lane & 15);
        bfr[ni] = *(const bf16x8*)(Bs + col * 128 + (bb ^ ((col & 7) << 4)));
      }
#pragma unroll
      for (int mi = 0; mi < 4; ++mi)
#pragma unroll
        for (int ni = 0; ni < 2; ++ni)
          acc[mi][ni] = __builtin_amdgcn_mfma_f32_16x16x32_bf16(af[mi], bfr[ni],
                                                                acc[mi][ni], 0, 0, 0);
    }
    __syncthreads();
  }
#pragma unroll
  for (int mi = 0; mi < 4; ++mi) {
    int gr0 = bm + wm * 64 + mi * 16 + (lane >> 4) * 4;
#pragma unroll
    for (int ni = 0; ni < 2; ++ni) {
      int gc = bn + wn * 32 + ni * 16 + (lane & 15);
#pragma unroll
      for (int j = 0; j < 4; ++j) {
        int gr = gr0 + j;
        if (gr < M) C[(size_t)gr * N + gc] = acc[mi][ni][j];
      }
    }
  }
}

// ---------------- fp32 GEMM (layer 2): C[M,N] = A[M,K] @ B[K,N] ----------------
__global__ __launch_bounds__(256) void k_gemm(const float* __restrict__ A,
                                              const float* __restrict__ B,
                                              float* __restrict__ C,
                                              int M, int N, int K) {
  __shared__ float As[16][136];
  __shared__ float Bs[16][64];
  const int bm = blockIdx.x * 128;
  const int bn = blockIdx.y * 64;
  const int tid = threadIdx.x;
  const int tx = tid & 15;
  const int ty = tid >> 4;
  float acc[8][4] = {};
  for (int k0 = 0; k0 < K; k0 += 16) {
#pragma unroll
    for (int q = 0; q < 2; ++q) {
      int idx = tid + q * 256;
      int r = idx >> 2;
      int kk = (idx & 3) * 4;
      float4 av = make_float4(0.f, 0.f, 0.f, 0.f);
      int gr = bm + r;
      if (gr < M) av = *(const float4*)&A[(size_t)gr * K + k0 + kk];
      As[kk + 0][r] = av.x; As[kk + 1][r] = av.y;
      As[kk + 2][r] = av.z; As[kk + 3][r] = av.w;
    }
    {
      int k = tid >> 4;
      int n4 = (tid & 15) * 4;
      *(float4*)&Bs[k][n4] = *(const float4*)&B[(size_t)(k0 + k) * N + bn + n4];
    }
    __syncthreads();
#pragma unroll
    for (int k = 0; k < 16; ++k) {
      float4 a0 = *(const float4*)&As[k][ty * 8];
      float4 a1 = *(const float4*)&As[k][ty * 8 + 4];
      float4 b = *(const float4*)&Bs[k][tx * 4];
      float ar[8] = {a0.x, a0.y, a0.z, a0.w, a1.x, a1.y, a1.z, a1.w};
#pragma unroll
      for (int i2 = 0; i2 < 8; ++i2) {
        acc[i2][0] += ar[i2] * b.x;
        acc[i2][1] += ar[i2] * b.y;
        acc[i2][2] += ar[i2] * b.z;
        acc[i2][3] += ar[i2] * b.w;
      }
    }
    __syncthreads();
  }
#pragma unroll
  for (int i2 = 0; i2 < 8; ++i2) {
    int row = bm + ty * 8 + i2;
    if (row < M) {
      float4 v = make_float4(acc[i2][0], acc[i2][1], acc[i2][2], acc[i2][3]);
      *(float4*)&C[(size_t)row * N + bn + tx * 4] = v;
    }
  }
}

// ---------------- per-node attention coefficients ----------------
__global__ void k_alpha1(const float* __restrict__ h, const float* __restrict__ a_src,
                         const float* __restrict__ a_dst, int n,
                         float* __restrict__ asrc, float* __restrict__ adst) {
  int wave = (blockIdx.x * blockDim.x + threadIdx.x) >> 6;
  int lane = threadIdx.x & 63;
  if (wave >= n) return;
  int hh = lane >> 3;
  int cg = lane & 7;
  int base = hh * 32 + cg * 4;
  float4 hv = *(const float4*)&h[(size_t)wave * D1 + base];
  float4 as = *(const float4*)&a_src[base];
  float4 ad = *(const float4*)&a_dst[base];
  float ps = hv.x * as.x + hv.y * as.y + hv.z * as.z + hv.w * as.w;
  float pd = hv.x * ad.x + hv.y * ad.y + hv.z * ad.z + hv.w * ad.w;
#pragma unroll
  for (int off = 1; off < 8; off <<= 1) {
    ps += __shfl_xor(ps, off);
    pd += __shfl_xor(pd, off);
  }
  if (cg == 0) { asrc[wave * 8 + hh] = ps; adst[wave * 8 + hh] = pd; }
}

__global__ void k_alpha2(const float* __restrict__ h, const float* __restrict__ a_src,
                         const float* __restrict__ a_dst, int n,
                         float* __restrict__ asrc, float* __restrict__ adst) {
  int wave = (blockIdx.x * blockDim.x + threadIdx.x) >> 6;
  int lane = threadIdx.x & 63;
  if (wave >= n) return;
  float hv = h[(size_t)wave * ODIM + lane];
  float ps = hv * a_src[lane];
  float pd = hv * a_dst[lane];
#pragma unroll
  for (int off = 1; off < 64; off <<= 1) {
    ps += __shfl_xor(ps, off);
    pd += __shfl_xor(pd, off);
  }
  if (lane == 0) { asrc[wave] = ps; adst[wave] = pd; }
}

// ---------------- layer-1 aggregation: online softmax + bias + ELU ----------------
__global__ void k_agg1(const int* __restrict__ offs, const int* __restrict__ csr_src,
                       const float* __restrict__ h1, const float* __restrict__ asrc,
                       const float* __restrict__ adst, const float* __restrict__ b1,
                       int n, float* __restrict__ helu) {
  int wave = (blockIdx.x * blockDim.x + threadIdx.x) >> 6;
  int lane = threadIdx.x & 63;
  if (wave >= n) return;
  int hh = lane >> 3;
  int cg = lane & 7;
  int hb = hh * 32 + cg * 4;
  float ad = adst[wave * 8 + hh];
  float m = -1e30f, ssum = 0.f;
  float ax = 0.f, ay = 0.f, az = 0.f, aw = 0.f;
  int b = offs[wave], e2 = offs[wave + 1];
  int i = b;
  for (; i + 1 < e2; i += 2) {
    int s0 = csr_src[i], s1 = csr_src[i + 1];
    float as0 = asrc[s0 * 8 + hh], as1 = asrc[s1 * 8 + hh];
    float4 h0 = *(const float4*)&h1[(size_t)s0 * D1 + hb];
    float4 hv1 = *(const float4*)&h1[(size_t)s1 * D1 + hb];
    float lg0 = lrelu(as0 + ad), lg1 = lrelu(as1 + ad);
    float mx = fmaxf(lg0, lg1);
    if (mx > m) {
      float c = __expf(m - mx);
      ssum *= c; ax *= c; ay *= c; az *= c; aw *= c;
      m = mx;
    }
    float w0 = __expf(lg0 - m), w1 = __expf(lg1 - m);
    ssum += w0 + w1;
    ax += w0 * h0.x + w1 * hv1.x;
    ay += w0 * h0.y + w1 * hv1.y;
    az += w0 * h0.z + w1 * hv1.z;
    aw += w0 * h0.w + w1 * hv1.w;
  }
  if (i < e2) {
    int s0 = csr_src[i];
    float as0 = asrc[s0 * 8 + hh];
    float4 h0 = *(const float4*)&h1[(size_t)s0 * D1 + hb];
    float lg0 = lrelu(as0 + ad);
    if (lg0 > m) {
      float c = __expf(m - lg0);
      ssum *= c; ax *= c; ay *= c; az *= c; aw *= c;
      m = lg0;
    }
    float w0 = __expf(lg0 - m);
    ssum += w0;
    ax += w0 * h0.x; ay += w0 * h0.y; az += w0 * h0.z; aw += w0 * h0.w;
  }
  float r = 1.f / ssum;
  float4 bb = *(const float4*)&b1[hb];
  float4 o;
  o.x = elu1(ax * r + bb.x);
  o.y = elu1(ay * r + bb.y);
  o.z = elu1(az * r + bb.z);
  o.w = elu1(aw * r + bb.w);
  *(float4*)&helu[(size_t)wave * D1 + hb] = o;
}

// ---------------- layer-2 aggregation: online softmax + bias ----------------
__global__ void k_agg2(const int* __restrict__ offs, const int* __restrict__ csr_src,
                       const float* __restrict__ h2, const float* __restrict__ asrc,
                       const float* __restrict__ adst, const float* __restrict__ b2,
                       int n, float* __restrict__ out) {
  int wave = (blockIdx.x * blockDim.x + threadIdx.x) >> 6;
  int lane = threadIdx.x & 63;
  if (wave >= n) return;
  float ad = adst[wave];
  float m = -1e30f, ssum = 0.f, acc = 0.f;
  int b = offs[wave], e2 = offs[wave + 1];
  int i = b;
  for (; i + 1 < e2; i += 2) {
    int s0 = csr_src[i], s1 = csr_src[i + 1];
    float as0 = asrc[s0], as1 = asrc[s1];
    float h0 = h2[(size_t)s0 * ODIM + lane];
    float hv1 = h2[(size_t)s1 * ODIM + lane];
    float lg0 = lrelu(as0 + ad), lg1 = lrelu(as1 + ad);
    float mx = fmaxf(lg0, lg1);
    if (mx > m) {
      float c = __expf(m - mx);
      ssum *= c; acc *= c; m = mx;
    }
    float w0 = __expf(lg0 - m), w1 = __expf(lg1 - m);
    ssum += w0 + w1;
    acc += w0 * h0 + w1 * hv1;
  }
  if (i < e2) {
    int s0 = csr_src[i];
    float as0 = asrc[s0];
    float h0 = h2[(size_t)s0 * ODIM + lane];
    float lg0 = lrelu(as0 + ad);
    if (lg0 > m) {
      float c = __expf(m - lg0);
      ssum *= c; acc *= c; m = lg0;
    }
    float w0 = __expf(lg0 - m);
    ssum += w0;
    acc += w0 * h0;
  }
  out[(size_t)wave * ODIM + lane] = acc / ssum + b2[lane];
}

extern "C" void kernel_launch(void* const* d_in, const int* in_sizes, int n_in,
                              void* d_out, int out_size, void* d_ws, size_t ws_size,
                              hipStream_t stream) {
  const float* x      = (const float*)d_in[0];
  const int* eidx     = (const int*)d_in[1];
  const float* W1     = (const float*)d_in[2];
  const float* asrc1w = (const float*)d_in[3];
  const float* adst1w = (const float*)d_in[4];
  const float* b1     = (const float*)d_in[5];
  const float* W2     = (const float*)d_in[6];
  const float* asrc2w = (const float*)d_in[7];
  const float* adst2w = (const float*)d_in[8];
  const float* b2     = (const float*)d_in[9];
  float* out = (float*)d_out;

  const int N = in_sizes[0] / D1;     // 50000
  const int E = in_sizes[1] / 2;      // 800000
  const int TE = E + N;
  const int* src = eidx;
  const int* dst = eidx + E;
  const int Mblk = (N + 127) / 128;   // 391
  const int Mpad = Mblk * 128;        // 50048

  // ---- workspace carve-up ----
  char* ws = (char*)d_ws;
  size_t off = 0;
  auto carve = [&](size_t bytes) -> char* {
    char* p = ws + off;
    off = (off + bytes + 255) & ~(size_t)255;
    return p;
  };
  // A2 (pre-GEMM1) and helu (post-GEMM1) never live simultaneously -> union
  char* unionAB    = carve((size_t)Mpad * 512 * 2);     // 51.25 MB
  unsigned short* A2 = (unsigned short*)unionAB;
  float* helu      = (float*)unionAB;
  float* h1    = (float*)carve((size_t)N * D1 * 4);
  float* h2    = (float*)carve((size_t)N * ODIM * 4);
  unsigned short* B2T = (unsigned short*)carve((size_t)256 * 768 * 2);
  float* asrc1 = (float*)carve((size_t)N * HEADS * 4);
  float* adst1 = (float*)carve((size_t)N * HEADS * 4);
  float* asrc2 = (float*)carve((size_t)N * 4);
  float* adst2 = (float*)carve((size_t)N * 4);
  int* deg     = (int*)carve((size_t)N * 4);
  int* offs    = (int*)carve((size_t)(N + 1) * 4);
  int* cursor  = (int*)carve((size_t)N * 4);
  int* partial = (int*)carve(1024);
  int* csr_src = (int*)carve((size_t)TE * 4);

  const int nb_n = (N + 255) / 256;
  const int nb_te = (TE + 255) / 256;

  // ---- CSR build (by dst) ----
  k_zero<<<nb_n, 256, 0, stream>>>(deg, N);
  k_hist<<<nb_te, 256, 0, stream>>>(dst, E, TE, deg);
  k_scan1<<<nb_n, 256, 0, stream>>>(deg, N, cursor, partial);
  k_scan2<<<1, 256, 0, stream>>>(partial, nb_n);
  k_scan3<<<nb_n, 256, 0, stream>>>(cursor, partial, N, TE, offs, cursor);
  k_scatter<<<nb_te, 256, 0, stream>>>(src, dst, E, TE, cursor, csr_src);

  // ---- layer 1: split-bf16 MFMA GEMM ----
  k_splitA<<<(N * 64 + 255) / 256, 256, 0, stream>>>(x, A2, N);
  k_splitB<<<(256 * 256 + 255) / 256, 256, 0, stream>>>(W1, B2T);
  {
    dim3 g(Mblk, D1 / 64);
    k_gemm_mfma<<<g, 256, 0, stream>>>(A2, B2T, h1, N, D1);
  }
  k_alpha1<<<(N + 3) / 4, 256, 0, stream>>>(h1, asrc1w, adst1w, N, asrc1, adst1);
  k_agg1<<<(N + 3) / 4, 256, 0, stream>>>(offs, csr_src, h1, asrc1, adst1, b1, N, helu);

  // ---- layer 2 ----
  {
    dim3 g(Mblk, ODIM / 64);
    k_gemm<<<g, 256, 0, stream>>>(helu, W2, h2, N, ODIM, D1);
  }
  k_alpha2<<<(N + 3) / 4, 256, 0, stream>>>(h2, asrc2w, adst2w, N, asrc2, adst2);
  k_agg2<<<(N + 3) / 4, 256, 0, stream>>>(offs, csr_src, h2, asrc2, adst2, b2, N, out);
}

// Round 3
// 312.233 us; speedup vs baseline: 1.6498x; 1.3717x over previous
//
#include <hip/hip_runtime.h>
#include <hip/hip_bf16.h>

static constexpr int HEADS = 8;
static constexpr int D1 = 256;      // HEADS*HID
static constexpr int ODIM = 64;
static constexpr float NEG = 0.2f;

typedef __attribute__((ext_vector_type(8))) short bf16x8;
typedef __attribute__((ext_vector_type(4))) float f32x4;

__device__ __forceinline__ float lrelu(float x) { return fmaxf(x, NEG * x); }
__device__ __forceinline__ float elu1(float x) { return x > 0.f ? x : expm1f(x); }

__device__ __forceinline__ unsigned short f2bf(float f) {
  unsigned u = __float_as_uint(f);
  unsigned r = (u + 0x7fffu + ((u >> 16) & 1u)) >> 16;
  return (unsigned short)r;
}
__device__ __forceinline__ float bf2f(unsigned short h) {
  return __uint_as_float((unsigned)h << 16);
}

__device__ __forceinline__ void gload_lds16(const void* g, void* l) {
  __builtin_amdgcn_global_load_lds(
      (const __attribute__((address_space(1))) void*)g,
      (__attribute__((address_space(3))) void*)l, 16, 0, 0);
}

// ---------------- CSR build ----------------
__global__ void k_zero(int* __restrict__ p, int n) {
  int i = blockIdx.x * blockDim.x + threadIdx.x;
  if (i < n) p[i] = 0;
}

__global__ void k_hist(const int* __restrict__ dst, int E, int TE, int* __restrict__ deg) {
  int i = blockIdx.x * blockDim.x + threadIdx.x;
  if (i >= TE) return;
  int d = (i < E) ? dst[i] : (i - E);
  atomicAdd(&deg[d], 1);
}

__global__ void k_scan1(const int* __restrict__ deg, int n,
                        int* __restrict__ excl, int* __restrict__ partial) {
  __shared__ int sm[256];
  int i = blockIdx.x * 256 + threadIdx.x;
  int v = (i < n) ? deg[i] : 0;
  sm[threadIdx.x] = v;
  __syncthreads();
  for (int off = 1; off < 256; off <<= 1) {
    int t = (threadIdx.x >= off) ? sm[threadIdx.x - off] : 0;
    __syncthreads();
    sm[threadIdx.x] += t;
    __syncthreads();
  }
  if (i < n) excl[i] = sm[threadIdx.x] - v;
  if (threadIdx.x == 255) partial[blockIdx.x] = sm[255];
}

__global__ void k_scan2(int* __restrict__ partial, int nb) {
  __shared__ int sm[256];
  int v = (threadIdx.x < nb) ? partial[threadIdx.x] : 0;
  sm[threadIdx.x] = v;
  __syncthreads();
  for (int off = 1; off < 256; off <<= 1) {
    int t = (threadIdx.x >= off) ? sm[threadIdx.x - off] : 0;
    __syncthreads();
    sm[threadIdx.x] += t;
    __syncthreads();
  }
  if (threadIdx.x < nb) partial[threadIdx.x] = sm[threadIdx.x] - v;  // exclusive
}

__global__ void k_scan3(const int* __restrict__ excl, const int* __restrict__ partial,
                        int n, int TE, int* __restrict__ offs, int* __restrict__ cursor) {
  int i = blockIdx.x * 256 + threadIdx.x;
  if (i < n) {
    int o = excl[i] + partial[i >> 8];
    offs[i] = o;
    cursor[i] = o;
  }
  if (i == 0) offs[n] = TE;
}

__global__ void k_scatter(const int* __restrict__ src, const int* __restrict__ dst,
                          int E, int TE, int* __restrict__ cursor, int* __restrict__ csr_src) {
  int i = blockIdx.x * blockDim.x + threadIdx.x;
  if (i >= TE) return;
  int s, d;
  if (i < E) { s = src[i]; d = dst[i]; } else { s = i - E; d = i - E; }
  int p = atomicAdd(&cursor[d], 1);
  csr_src[p] = s;
}

// ---------------- split-bf16 operand prep ----------------
__global__ void k_splitA(const float* __restrict__ X, unsigned short* __restrict__ A2, int M) {
  int t = blockIdx.x * blockDim.x + threadIdx.x;
  if (t >= M * 64) return;
  int m = t >> 6, c4 = (t & 63) * 4;
  float4 v = *(const float4*)&X[(size_t)m * 256 + c4];
  float vv[4] = {v.x, v.y, v.z, v.w};
  unsigned short hi[4], lo[4];
#pragma unroll
  for (int j = 0; j < 4; ++j) {
    hi[j] = f2bf(vv[j]);
    lo[j] = f2bf(vv[j] - bf2f(hi[j]));
  }
  *(ushort4*)&A2[(size_t)m * 512 + c4] = make_ushort4(hi[0], hi[1], hi[2], hi[3]);
  *(ushort4*)&A2[(size_t)m * 512 + 256 + c4] = make_ushort4(lo[0], lo[1], lo[2], lo[3]);
}

// B2T[n][k]: k<256 hi(W[k][n]); 256..511 lo; 512..767 hi
__global__ void k_splitB(const float* __restrict__ W, unsigned short* __restrict__ B2T) {
  int t = blockIdx.x * blockDim.x + threadIdx.x;
  if (t >= 256 * 256) return;
  int k = t >> 8, n = t & 255;
  float v = W[k * 256 + n];
  unsigned short hi = f2bf(v);
  unsigned short lo = f2bf(v - bf2f(hi));
  B2T[(size_t)n * 768 + k] = hi;
  B2T[(size_t)n * 768 + 256 + k] = lo;
  B2T[(size_t)n * 768 + 512 + k] = hi;
}

// ---------------- MFMA GEMM layer 1: h1b[M,256] (bf16) = splitA @ splitB ----------------
// BM=128, BN=128, BK=64, 512 threads = 8 waves (2x4), wave tile 64x32.
__global__ __launch_bounds__(512) void k_gemm_mfma(
    const unsigned short* __restrict__ A2,   // [Mpad][512]
    const unsigned short* __restrict__ B2T,  // [256][768]
    unsigned short* __restrict__ C, int M) {
  __shared__ __align__(128) char As[16384];  // [128 rows][128B], XOR-swizzled
  __shared__ __align__(128) char Bs[16384];  // [128 cols][128B], XOR-swizzled
  const int tid = threadIdx.x;
  const int lane = tid & 63;
  const int wid = tid >> 6;
  const int bm = blockIdx.x * 128;
  const int bn = blockIdx.y * 128;
  const int wm = wid >> 2, wn = wid & 3;
  f32x4 acc[4][2] = {};
  for (int kb = 0; kb < 768; kb += 64) {
    // A term schedule: hi (kb<256), hi (256..511 vs B-lo), lo (512..767 vs B-hi)
    int a_k0 = kb < 256 ? kb : kb - 256;
#pragma unroll
    for (int q = 0; q < 2; ++q) {
      int c = q * 512 + tid;
      int r = c >> 3;                          // 0..127
      int b = ((c & 7) * 16) ^ ((r & 7) << 4);
      gload_lds16(A2 + (size_t)(bm + r) * 512 + a_k0 + (b >> 1),
                  As + (size_t)(q * 512 + (tid & ~63)) * 16);
    }
#pragma unroll
    for (int q = 0; q < 2; ++q) {
      int c = q * 512 + tid;
      int col = c >> 3;                        // 0..127
      int b = ((c & 7) * 16) ^ ((col & 7) << 4);
      gload_lds16(B2T + (size_t)(bn + col) * 768 + kb + (b >> 1),
                  Bs + (size_t)(q * 512 + (tid & ~63)) * 16);
    }
    __syncthreads();
#pragma unroll
    for (int ks = 0; ks < 2; ++ks) {
      bf16x8 af[4], bfr[2];
      int bb = ks * 64 + (lane >> 4) * 16;
#pragma unroll
      for (int mi = 0; mi < 4; ++mi) {
        int row = wm * 64 + mi * 16 + (lane & 15);
        af[mi] = *(const bf16x8*)(As + row * 128 + (bb ^ ((row & 7) << 4)));
      }
#pragma unroll
      for (int ni = 0; ni < 2; ++ni) {
        int col = wn * 32 + ni * 16 + (lane & 15);
        bfr[ni] = *(const bf16x8*)(Bs + col * 128 + (bb ^ ((col & 7) << 4)));
      }
#pragma unroll
      for (int mi = 0; mi < 4; ++mi)
#pragma unroll
        for (int ni = 0; ni < 2; ++ni)
          acc[mi][ni] = __builtin_amdgcn_mfma_f32_16x16x32_bf16(af[mi], bfr[ni],
                                                                acc[mi][ni], 0, 0, 0);
    }
    __syncthreads();
  }
#pragma unroll
  for (int mi = 0; mi < 4; ++mi) {
    int gr0 = bm + wm * 64 + mi * 16 + (lane >> 4) * 4;
#pragma unroll
    for (int ni = 0; ni < 2; ++ni) {
      int gc = bn + wn * 32 + ni * 16 + (lane & 15);
#pragma unroll
      for (int j = 0; j < 4; ++j) {
        int gr = gr0 + j;
        if (gr < M) C[(size_t)gr * 256 + gc] = f2bf(acc[mi][ni][j]);
      }
    }
  }
}

// ---------------- fp32 GEMM (layer 2): h2b[M,64] (bf16) = A[M,256] @ B[256,64] ----------------
__global__ __launch_bounds__(256) void k_gemm(const float* __restrict__ A,
                                              const float* __restrict__ B,
                                              unsigned short* __restrict__ C,
                                              int M, int N, int K) {
  __shared__ float As[16][136];
  __shared__ float Bs[16][64];
  const int bm = blockIdx.x * 128;
  const int bn = blockIdx.y * 64;
  const int tid = threadIdx.x;
  const int tx = tid & 15;
  const int ty = tid >> 4;
  float acc[8][4] = {};
  for (int k0 = 0; k0 < K; k0 += 16) {
#pragma unroll
    for (int q = 0; q < 2; ++q) {
      int idx = tid + q * 256;
      int r = idx >> 2;
      int kk = (idx & 3) * 4;
      float4 av = make_float4(0.f, 0.f, 0.f, 0.f);
      int gr = bm + r;
      if (gr < M) av = *(const float4*)&A[(size_t)gr * K + k0 + kk];
      As[kk + 0][r] = av.x; As[kk + 1][r] = av.y;
      As[kk + 2][r] = av.z; As[kk + 3][r] = av.w;
    }
    {
      int k = tid >> 4;
      int n4 = (tid & 15) * 4;
      *(float4*)&Bs[k][n4] = *(const float4*)&B[(size_t)(k0 + k) * N + bn + n4];
    }
    __syncthreads();
#pragma unroll
    for (int k = 0; k < 16; ++k) {
      float4 a0 = *(const float4*)&As[k][ty * 8];
      float4 a1 = *(const float4*)&As[k][ty * 8 + 4];
      float4 b = *(const float4*)&Bs[k][tx * 4];
      float ar[8] = {a0.x, a0.y, a0.z, a0.w, a1.x, a1.y, a1.z, a1.w};
#pragma unroll
      for (int i2 = 0; i2 < 8; ++i2) {
        acc[i2][0] += ar[i2] * b.x;
        acc[i2][1] += ar[i2] * b.y;
        acc[i2][2] += ar[i2] * b.z;
        acc[i2][3] += ar[i2] * b.w;
      }
    }
    __syncthreads();
  }
#pragma unroll
  for (int i2 = 0; i2 < 8; ++i2) {
    int row = bm + ty * 8 + i2;
    if (row < M) {
      ushort4 v = make_ushort4(f2bf(acc[i2][0]), f2bf(acc[i2][1]),
                               f2bf(acc[i2][2]), f2bf(acc[i2][3]));
      *(ushort4*)&C[(size_t)row * N + bn + tx * 4] = v;
    }
  }
}

// ---------------- per-node attention coefficients ----------------
// layer 1 from bf16 h: one wave per node, lane = channel-group of 4 (lane*4)
__global__ void k_alpha1(const unsigned short* __restrict__ h1b,
                         const float* __restrict__ a_src, const float* __restrict__ a_dst,
                         int n, float* __restrict__ asrc, float* __restrict__ adst) {
  int wave = (blockIdx.x * blockDim.x + threadIdx.x) >> 6;
  int lane = threadIdx.x & 63;
  if (wave >= n) return;
  int hh = lane >> 3;
  ushort4 hv4 = *(const ushort4*)&h1b[(size_t)wave * D1 + lane * 4];
  float4 as = *(const float4*)&a_src[lane * 4];
  float4 ad = *(const float4*)&a_dst[lane * 4];
  float hx = bf2f(hv4.x), hy = bf2f(hv4.y), hz = bf2f(hv4.z), hw = bf2f(hv4.w);
  float ps = hx * as.x + hy * as.y + hz * as.z + hw * as.w;
  float pd = hx * ad.x + hy * ad.y + hz * ad.z + hw * ad.w;
#pragma unroll
  for (int off = 1; off < 8; off <<= 1) {
    ps += __shfl_xor(ps, off);
    pd += __shfl_xor(pd, off);
  }
  if ((lane & 7) == 0) { asrc[wave * 8 + hh] = ps; adst[wave * 8 + hh] = pd; }
}

// layer 2 from bf16 h: one wave per node, lane = channel
__global__ void k_alpha2(const unsigned short* __restrict__ h2b,
                         const float* __restrict__ a_src, const float* __restrict__ a_dst,
                         int n, float* __restrict__ asrc, float* __restrict__ adst) {
  int wave = (blockIdx.x * blockDim.x + threadIdx.x) >> 6;
  int lane = threadIdx.x & 63;
  if (wave >= n) return;
  float hv = bf2f(h2b[(size_t)wave * ODIM + lane]);
  float ps = hv * a_src[lane];
  float pd = hv * a_dst[lane];
#pragma unroll
  for (int off = 1; off < 64; off <<= 1) {
    ps += __shfl_xor(ps, off);
    pd += __shfl_xor(pd, off);
  }
  if (lane == 0) { asrc[wave] = ps; adst[wave] = pd; }
}

// ---------------- layer-1 aggregation: bf16 gather, online softmax, bias+ELU ----------------
__global__ void k_agg1(const int* __restrict__ offs, const int* __restrict__ csr_src,
                       const unsigned short* __restrict__ h1b, const float* __restrict__ asrc,
                       const float* __restrict__ adst, const float* __restrict__ b1,
                       int n, float* __restrict__ helu) {
  int wave = (blockIdx.x * blockDim.x + threadIdx.x) >> 6;
  int lane = threadIdx.x & 63;
  if (wave >= n) return;
  int wv = __builtin_amdgcn_readfirstlane(wave);
  int hh = lane >> 3;
  float ad = adst[wv * 8 + hh];
  int b = offs[wv], e2 = offs[wv + 1];
  float m = -1e30f, ssum = 0.f;
  float ax = 0.f, ay = 0.f, az = 0.f, aw = 0.f;
  int i = b;
  for (; i + 3 < e2; i += 4) {
    int s0 = csr_src[i], s1 = csr_src[i + 1], s2 = csr_src[i + 2], s3 = csr_src[i + 3];
    ushort4 r0 = *(const ushort4*)&h1b[(size_t)s0 * D1 + lane * 4];
    ushort4 r1 = *(const ushort4*)&h1b[(size_t)s1 * D1 + lane * 4];
    ushort4 r2 = *(const ushort4*)&h1b[(size_t)s2 * D1 + lane * 4];
    ushort4 r3 = *(const ushort4*)&h1b[(size_t)s3 * D1 + lane * 4];
    float lg0 = lrelu(asrc[s0 * 8 + hh] + ad);
    float lg1 = lrelu(asrc[s1 * 8 + hh] + ad);
    float lg2 = lrelu(asrc[s2 * 8 + hh] + ad);
    float lg3 = lrelu(asrc[s3 * 8 + hh] + ad);
    float mx = fmaxf(fmaxf(lg0, lg1), fmaxf(lg2, lg3));
    float nm = fmaxf(m, mx);
    float c = __expf(m - nm);
    float w0 = __expf(lg0 - nm), w1 = __expf(lg1 - nm);
    float w2 = __expf(lg2 - nm), w3 = __expf(lg3 - nm);
    ssum = ssum * c + (w0 + w1) + (w2 + w3);
    ax = ax * c + w0 * bf2f(r0.x) + w1 * bf2f(r1.x) + w2 * bf2f(r2.x) + w3 * bf2f(r3.x);
    ay = ay * c + w0 * bf2f(r0.y) + w1 * bf2f(r1.y) + w2 * bf2f(r2.y) + w3 * bf2f(r3.y);
    az = az * c + w0 * bf2f(r0.z) + w1 * bf2f(r1.z) + w2 * bf2f(r2.z) + w3 * bf2f(r3.z);
    aw = aw * c + w0 * bf2f(r0.w) + w1 * bf2f(r1.w) + w2 * bf2f(r2.w) + w3 * bf2f(r3.w);
    m = nm;
  }
  for (; i < e2; ++i) {
    int s0 = csr_src[i];
    ushort4 r0 = *(const ushort4*)&h1b[(size_t)s0 * D1 + lane * 4];
    float lg0 = lrelu(asrc[s0 * 8 + hh] + ad);
    float nm = fmaxf(m, lg0);
    float c = __expf(m - nm);
    float w0 = __expf(lg0 - nm);
    ssum = ssum * c + w0;
    ax = ax * c + w0 * bf2f(r0.x);
    ay = ay * c + w0 * bf2f(r0.y);
    az = az * c + w0 * bf2f(r0.z);
    aw = aw * c + w0 * bf2f(r0.w);
    m = nm;
  }
  float rr = 1.f / ssum;
  float4 bb = *(const float4*)&b1[lane * 4];
  float4 o;
  o.x = elu1(ax * rr + bb.x);
  o.y = elu1(ay * rr + bb.y);
  o.z = elu1(az * rr + bb.z);
  o.w = elu1(aw * rr + bb.w);
  *(float4*)&helu[(size_t)wave * D1 + lane * 4] = o;
}

// ---------------- layer-2 aggregation: bf16 gather, online softmax, bias ----------------
__global__ void k_agg2(const int* __restrict__ offs, const int* __restrict__ csr_src,
                       const unsigned short* __restrict__ h2b, const float* __restrict__ asrc,
                       const float* __restrict__ adst, const float* __restrict__ b2,
                       int n, float* __restrict__ out) {
  int wave = (blockIdx.x * blockDim.x + threadIdx.x) >> 6;
  int lane = threadIdx.x & 63;
  if (wave >= n) return;
  int wv = __builtin_amdgcn_readfirstlane(wave);
  float ad = adst[wv];
  int b = offs[wv], e2 = offs[wv + 1];
  float m = -1e30f, ssum = 0.f, acc = 0.f;
  int i = b;
  for (; i + 3 < e2; i += 4) {
    int s0 = csr_src[i], s1 = csr_src[i + 1], s2 = csr_src[i + 2], s3 = csr_src[i + 3];
    float h0 = bf2f(h2b[(size_t)s0 * ODIM + lane]);
    float h1v = bf2f(h2b[(size_t)s1 * ODIM + lane]);
    float h2v = bf2f(h2b[(size_t)s2 * ODIM + lane]);
    float h3 = bf2f(h2b[(size_t)s3 * ODIM + lane]);
    float lg0 = lrelu(asrc[s0] + ad);
    float lg1 = lrelu(asrc[s1] + ad);
    float lg2 = lrelu(asrc[s2] + ad);
    float lg3 = lrelu(asrc[s3] + ad);
    float mx = fmaxf(fmaxf(lg0, lg1), fmaxf(lg2, lg3));
    float nm = fmaxf(m, mx);
    float c = __expf(m - nm);
    float w0 = __expf(lg0 - nm), w1 = __expf(lg1 - nm);
    float w2 = __expf(lg2 - nm), w3 = __expf(lg3 - nm);
    ssum = ssum * c + (w0 + w1) + (w2 + w3);
    acc = acc * c + w0 * h0 + w1 * h1v + w2 * h2v + w3 * h3;
    m = nm;
  }
  for (; i < e2; ++i) {
    int s0 = csr_src[i];
    float h0 = bf2f(h2b[(size_t)s0 * ODIM + lane]);
    float lg0 = lrelu(asrc[s0] + ad);
    float nm = fmaxf(m, lg0);
    float c = __expf(m - nm);
    float w0 = __expf(lg0 - nm);
    ssum = ssum * c + w0;
    acc = acc * c + w0 * h0;
    m = nm;
  }
  out[(size_t)wave * ODIM + lane] = acc / ssum + b2[lane];
}

extern "C" void kernel_launch(void* const* d_in, const int* in_sizes, int n_in,
                              void* d_out, int out_size, void* d_ws, size_t ws_size,
                              hipStream_t stream) {
  const float* x      = (const float*)d_in[0];
  const int* eidx     = (const int*)d_in[1];
  const float* W1     = (const float*)d_in[2];
  const float* asrc1w = (const float*)d_in[3];
  const float* adst1w = (const float*)d_in[4];
  const float* b1     = (const float*)d_in[5];
  const float* W2     = (const float*)d_in[6];
  const float* asrc2w = (const float*)d_in[7];
  const float* adst2w = (const float*)d_in[8];
  const float* b2     = (const float*)d_in[9];
  float* out = (float*)d_out;

  const int N = in_sizes[0] / D1;     // 50000
  const int E = in_sizes[1] / 2;      // 800000
  const int TE = E + N;
  const int* src = eidx;
  const int* dst = eidx + E;
  const int Mblk = (N + 127) / 128;   // 391
  const int Mpad = Mblk * 128;        // 50048

  // ---- workspace carve-up ----
  char* ws = (char*)d_ws;
  size_t off = 0;
  auto carve = [&](size_t bytes) -> char* {
    char* p = ws + off;
    off = (off + bytes + 255) & ~(size_t)255;
    return p;
  };
  // A2 (pre-GEMM1) and helu (post-agg1) never live simultaneously -> union
  char* unionAB = carve((size_t)Mpad * 512 * 2);        // 51.25 MB
  unsigned short* A2 = (unsigned short*)unionAB;
  float* helu = (float*)unionAB;
  unsigned short* h1b = (unsigned short*)carve((size_t)Mpad * D1 * 2);  // 25.6 MB
  unsigned short* h2b = (unsigned short*)carve((size_t)N * ODIM * 2);   // 6.4 MB
  unsigned short* B2T = (unsigned short*)carve((size_t)256 * 768 * 2);
  float* asrc1 = (float*)carve((size_t)N * HEADS * 4);
  float* adst1 = (float*)carve((size_t)N * HEADS * 4);
  float* asrc2 = (float*)carve((size_t)N * 4);
  float* adst2 = (float*)carve((size_t)N * 4);
  int* deg     = (int*)carve((size_t)N * 4);
  int* offs    = (int*)carve((size_t)(N + 1) * 4);
  int* cursor  = (int*)carve((size_t)N * 4);
  int* partial = (int*)carve(1024);
  int* csr_src = (int*)carve((size_t)TE * 4);

  const int nb_n = (N + 255) / 256;
  const int nb_te = (TE + 255) / 256;

  // ---- CSR build (by dst) ----
  k_zero<<<nb_n, 256, 0, stream>>>(deg, N);
  k_hist<<<nb_te, 256, 0, stream>>>(dst, E, TE, deg);
  k_scan1<<<nb_n, 256, 0, stream>>>(deg, N, cursor, partial);
  k_scan2<<<1, 256, 0, stream>>>(partial, nb_n);
  k_scan3<<<nb_n, 256, 0, stream>>>(cursor, partial, N, TE, offs, cursor);
  k_scatter<<<nb_te, 256, 0, stream>>>(src, dst, E, TE, cursor, csr_src);

  // ---- layer 1 ----
  k_splitA<<<(N * 64 + 255) / 256, 256, 0, stream>>>(x, A2, N);
  k_splitB<<<(256 * 256 + 255) / 256, 256, 0, stream>>>(W1, B2T);
  {
    dim3 g(Mblk, 2);
    k_gemm_mfma<<<g, 512, 0, stream>>>(A2, B2T, h1b, N);
  }
  k_alpha1<<<(N + 3) / 4, 256, 0, stream>>>(h1b, asrc1w, adst1w, N, asrc1, adst1);
  k_agg1<<<(N + 3) / 4, 256, 0, stream>>>(offs, csr_src, h1b, asrc1, adst1, b1, N, helu);

  // ---- layer 2 ----
  {
    dim3 g(Mblk, 1);
    k_gemm<<<g, 256, 0, stream>>>(helu, W2, h2b, N, ODIM, D1);
  }
  k_alpha2<<<(N + 3) / 4, 256, 0, stream>>>(h2b, asrc2w, adst2w, N, asrc2, adst2);
  k_agg2<<<(N + 3) / 4, 256, 0, stream>>>(offs, csr_src, h2b, asrc2, adst2, b2, N, out);
}

// Round 4
// 278.604 us; speedup vs baseline: 1.8489x; 1.1207x over previous
//
#include <hip/hip_runtime.h>
#include <hip/hip_bf16.h>

static constexpr int HEADS = 8;
static constexpr int D1 = 256;      // HEADS*HID
static constexpr int ODIM = 64;
static constexpr float NEG = 0.2f;

typedef __attribute__((ext_vector_type(8))) short bf16x8;
typedef __attribute__((ext_vector_type(8))) unsigned short u16x8;
typedef __attribute__((ext_vector_type(4))) float f32x4;

__device__ __forceinline__ float lrelu(float x) { return fmaxf(x, NEG * x); }
__device__ __forceinline__ float elu1(float x) { return x > 0.f ? x : expm1f(x); }

__device__ __forceinline__ unsigned short f2bf(float f) {
  unsigned u = __float_as_uint(f);
  unsigned r = (u + 0x7fffu + ((u >> 16) & 1u)) >> 16;
  return (unsigned short)r;
}
__device__ __forceinline__ float bf2f(unsigned short h) {
  return __uint_as_float((unsigned)h << 16);
}

__device__ __forceinline__ void gload_lds16(const void* g, void* l) {
  __builtin_amdgcn_global_load_lds(
      (const __attribute__((address_space(1))) void*)g,
      (__attribute__((address_space(3))) void*)l, 16, 0, 0);
}

// ---------------- CSR build ----------------
__global__ void k_zero(int* __restrict__ p, int n) {
  int i = blockIdx.x * blockDim.x + threadIdx.x;
  if (i < n) p[i] = 0;
}

__global__ void k_hist(const int* __restrict__ dst, int E, int TE, int* __restrict__ deg) {
  int i = blockIdx.x * blockDim.x + threadIdx.x;
  if (i >= TE) return;
  int d = (i < E) ? dst[i] : (i - E);
  atomicAdd(&deg[d], 1);
}

__global__ void k_scan1(const int* __restrict__ deg, int n,
                        int* __restrict__ excl, int* __restrict__ partial) {
  __shared__ int sm[256];
  int i = blockIdx.x * 256 + threadIdx.x;
  int v = (i < n) ? deg[i] : 0;
  sm[threadIdx.x] = v;
  __syncthreads();
  for (int off = 1; off < 256; off <<= 1) {
    int t = (threadIdx.x >= off) ? sm[threadIdx.x - off] : 0;
    __syncthreads();
    sm[threadIdx.x] += t;
    __syncthreads();
  }
  if (i < n) excl[i] = sm[threadIdx.x] - v;
  if (threadIdx.x == 255) partial[blockIdx.x] = sm[255];
}

__global__ void k_scan2(int* __restrict__ partial, int nb) {
  __shared__ int sm[256];
  int v = (threadIdx.x < nb) ? partial[threadIdx.x] : 0;
  sm[threadIdx.x] = v;
  __syncthreads();
  for (int off = 1; off < 256; off <<= 1) {
    int t = (threadIdx.x >= off) ? sm[threadIdx.x - off] : 0;
    __syncthreads();
    sm[threadIdx.x] += t;
    __syncthreads();
  }
  if (threadIdx.x < nb) partial[threadIdx.x] = sm[threadIdx.x] - v;  // exclusive
}

__global__ void k_scan3(const int* __restrict__ excl, const int* __restrict__ partial,
                        int n, int TE, int* __restrict__ offs, int* __restrict__ cursor) {
  int i = blockIdx.x * 256 + threadIdx.x;
  if (i < n) {
    int o = excl[i] + partial[i >> 8];
    offs[i] = o;
    cursor[i] = o;
  }
  if (i == 0) offs[n] = TE;
}

__global__ void k_scatter(const int* __restrict__ src, const int* __restrict__ dst,
                          int E, int TE, int* __restrict__ cursor, int* __restrict__ csr_src) {
  int i = blockIdx.x * blockDim.x + threadIdx.x;
  if (i >= TE) return;
  int s, d;
  if (i < E) { s = src[i]; d = dst[i]; } else { s = i - E; d = i - E; }
  int p = atomicAdd(&cursor[d], 1);
  csr_src[p] = s;
}

// ---------------- B-prep (tiny) ----------------
// BT1[buf][n][k]: buf0 = hi(W1[k][n]), buf1 = lo.  [2][256][256]
__global__ void k_prepB1(const float* __restrict__ W, unsigned short* __restrict__ BT) {
  int t = blockIdx.x * blockDim.x + threadIdx.x;
  if (t >= 256 * 256) return;
  int k = t >> 8, n = t & 255;
  float v = W[k * 256 + n];
  unsigned short hi = f2bf(v);
  unsigned short lo = f2bf(v - bf2f(hi));
  BT[n * 256 + k] = hi;
  BT[65536 + n * 256 + k] = lo;
}

// B2T2[n][k3]: k<256 hi(W2[k][n]); 256..511 lo; 512..767 hi.   [64][768]
__global__ void k_prepB2(const float* __restrict__ W, unsigned short* __restrict__ BT) {
  int t = blockIdx.x * blockDim.x + threadIdx.x;
  if (t >= 256 * 64) return;
  int k = t >> 6, n = t & 63;
  float v = W[k * 64 + n];
  unsigned short hi = f2bf(v);
  unsigned short lo = f2bf(v - bf2f(hi));
  BT[(size_t)n * 768 + k] = hi;
  BT[(size_t)n * 768 + 256 + k] = lo;
  BT[(size_t)n * 768 + 512 + k] = hi;
}

// ---------------- GEMM1 (fused fp32->split-bf16, 3-term): h1b = x @ W1 ----------------
// grid (2, Mblk), 512 threads = 8 waves (2m x 4n), BM=128, BN=128, BK=64.
__global__ __launch_bounds__(512) void k_gemm1(
    const float* __restrict__ X,            // [M][256]
    const unsigned short* __restrict__ BT,  // [2][256n][256k]
    unsigned short* __restrict__ h1b,       // [Mpad][256]
    int M) {
  __shared__ __align__(128) char AsH[16384];  // [128r][128B] XOR-swizzled
  __shared__ __align__(128) char AsL[16384];
  __shared__ __align__(128) char BsH[16384];  // [128c][128B] XOR-swizzled
  __shared__ __align__(128) char BsL[16384];
  const int tid = threadIdx.x;
  const int lane = tid & 63;
  const int wid = tid >> 6;
  const int bn = blockIdx.x * 128;
  const int bm = blockIdx.y * 128;
  const int wm = wid >> 2, wn = wid & 3;      // wave tile 64x32
  f32x4 acc[4][2] = {};
  for (int kb = 0; kb < 256; kb += 64) {
    // ---- A: load fp32, split, ds_write swizzled (write-XOR matches read-XOR) ----
#pragma unroll
    for (int q = 0; q < 2; ++q) {
      int c = q * 512 + tid;          // chunk 0..1023
      int r = c >> 3, kc = c & 7;     // row 0..127, 16B-chunk 0..7
      int gr = bm + r;
      float4 v0 = make_float4(0.f, 0.f, 0.f, 0.f), v1 = v0;
      if (gr < M) {
        v0 = *(const float4*)&X[(size_t)gr * 256 + kb + kc * 8];
        v1 = *(const float4*)&X[(size_t)gr * 256 + kb + kc * 8 + 4];
      }
      float vv[8] = {v0.x, v0.y, v0.z, v0.w, v1.x, v1.y, v1.z, v1.w};
      u16x8 hv, lv;
#pragma unroll
      for (int j = 0; j < 8; ++j) {
        unsigned short h = f2bf(vv[j]);
        hv[j] = h;
        lv[j] = f2bf(vv[j] - bf2f(h));
      }
      int wb = r * 128 + ((kc * 16) ^ ((r & 7) << 4));
      *(u16x8*)(AsH + wb) = hv;
      *(u16x8*)(AsL + wb) = lv;
    }
    // ---- B: gload_lds16, linear dest + pre-swizzled source offset ----
#pragma unroll
    for (int q = 0; q < 2; ++q) {
      int c = q * 512 + tid;                   // chunk 0..1023
      int col = c >> 3;                        // 0..127
      int b = ((c & 7) * 16) ^ ((col & 7) << 4);
      gload_lds16(BT + (size_t)(bn + col) * 256 + kb + (b >> 1),
                  BsH + (size_t)(q * 512 + (tid & ~63)) * 16);
      gload_lds16(BT + 65536 + (size_t)(bn + col) * 256 + kb + (b >> 1),
                  BsL + (size_t)(q * 512 + (tid & ~63)) * 16);
    }
    __syncthreads();
#pragma unroll
    for (int ks = 0; ks < 2; ++ks) {
      bf16x8 afH[4], afL[4], bfH[2], bfL[2];
      int bb = ks * 64 + (lane >> 4) * 16;
#pragma unroll
      for (int mi = 0; mi < 4; ++mi) {
        int row = wm * 64 + mi * 16 + (lane & 15);
        int ra = row * 128 + (bb ^ ((row & 7) << 4));
        afH[mi] = *(const bf16x8*)(AsH + ra);
        afL[mi] = *(const bf16x8*)(AsL + ra);
      }
#pragma unroll
      for (int ni = 0; ni < 2; ++ni) {
        int col = wn * 32 + ni * 16 + (lane & 15);
        int ca = col * 128 + (bb ^ ((col & 7) << 4));
        bfH[ni] = *(const bf16x8*)(BsH + ca);
        bfL[ni] = *(const bf16x8*)(BsL + ca);
      }
#pragma unroll
      for (int mi = 0; mi < 4; ++mi)
#pragma unroll
        for (int ni = 0; ni < 2; ++ni) {
          acc[mi][ni] = __builtin_amdgcn_mfma_f32_16x16x32_bf16(afH[mi], bfH[ni],
                                                                acc[mi][ni], 0, 0, 0);
          acc[mi][ni] = __builtin_amdgcn_mfma_f32_16x16x32_bf16(afH[mi], bfL[ni],
                                                                acc[mi][ni], 0, 0, 0);
          acc[mi][ni] = __builtin_amdgcn_mfma_f32_16x16x32_bf16(afL[mi], bfH[ni],
                                                                acc[mi][ni], 0, 0, 0);
        }
    }
    __syncthreads();
  }
#pragma unroll
  for (int mi = 0; mi < 4; ++mi) {
    int gr0 = bm + wm * 64 + mi * 16 + (lane >> 4) * 4;
#pragma unroll
    for (int ni = 0; ni < 2; ++ni) {
      int gc = bn + wn * 32 + ni * 16 + (lane & 15);
#pragma unroll
      for (int j = 0; j < 4; ++j) {
        int gr = gr0 + j;
        if (gr < M) h1b[(size_t)gr * 256 + gc] = f2bf(acc[mi][ni][j]);
      }
    }
  }
}

// ---------------- GEMM2 (split-bf16 3-term): h2b = heluS @ W2 ----------------
// grid (Mblk), 256 threads = 4 waves (2x2), BM=128, BN=64, virtual K=768.
__global__ __launch_bounds__(256) void k_gemm2(
    const unsigned short* __restrict__ A2,   // heluS [Mpad][512]: hi 0..255, lo 256..511
    const unsigned short* __restrict__ B2T,  // [64][768]
    unsigned short* __restrict__ C,          // h2b [M][64]
    int M) {
  __shared__ __align__(128) char As[16384];  // [128r][128B]
  __shared__ __align__(128) char Bs[8192];   // [64c][128B]
  const int tid = threadIdx.x;
  const int lane = tid & 63;
  const int wid = tid >> 6;
  const int bm = blockIdx.x * 128;
  const int wm = wid >> 1, wn = wid & 1;
  f32x4 acc[4][2] = {};
  for (int kb = 0; kb < 768; kb += 64) {
    int a_k0 = kb < 256 ? kb : (kb < 512 ? kb - 256 : kb - 256);  // hi,hi,lo schedule
    // A-term schedule: windows 0..255 -> hi, 256..511 -> A-hi vs B-lo, 512..767 -> A-lo vs B-hi
    int a_base = (kb < 512) ? (kb & 255) : (256 + (kb - 512));
    (void)a_k0;
#pragma unroll
    for (int q = 0; q < 4; ++q) {
      int c = q * 256 + tid;
      int r = c >> 3;
      int b = ((c & 7) * 16) ^ ((r & 7) << 4);
      gload_lds16(A2 + (size_t)(bm + r) * 512 + a_base + (b >> 1),
                  As + (size_t)(q * 256 + (tid & ~63)) * 16);
    }
#pragma unroll
    for (int q = 0; q < 2; ++q) {
      int c = q * 256 + tid;
      int col = c >> 3;
      int b = ((c & 7) * 16) ^ ((col & 7) << 4);
      gload_lds16(B2T + (size_t)col * 768 + kb + (b >> 1),
                  Bs + (size_t)(q * 256 + (tid & ~63)) * 16);
    }
    __syncthreads();
#pragma unroll
    for (int ks = 0; ks < 2; ++ks) {
      bf16x8 af[4], bfr[2];
      int bb = ks * 64 + (lane >> 4) * 16;
#pragma unroll
      for (int mi = 0; mi < 4; ++mi) {
        int row = wm * 64 + mi * 16 + (lane & 15);
        af[mi] = *(const bf16x8*)(As + row * 128 + (bb ^ ((row & 7) << 4)));
      }
#pragma unroll
      for (int ni = 0; ni < 2; ++ni) {
        int col = wn * 32 + ni * 16 + (lane & 15);
        bfr[ni] = *(const bf16x8*)(Bs + col * 128 + (bb ^ ((col & 7) << 4)));
      }
#pragma unroll
      for (int mi = 0; mi < 4; ++mi)
#pragma unroll
        for (int ni = 0; ni < 2; ++ni)
          acc[mi][ni] = __builtin_amdgcn_mfma_f32_16x16x32_bf16(af[mi], bfr[ni],
                                                                acc[mi][ni], 0, 0, 0);
    }
    __syncthreads();
  }
#pragma unroll
  for (int mi = 0; mi < 4; ++mi) {
    int gr0 = bm + wm * 64 + mi * 16 + (lane >> 4) * 4;
#pragma unroll
    for (int ni = 0; ni < 2; ++ni) {
      int gc = wn * 32 + ni * 16 + (lane & 15);
#pragma unroll
      for (int j = 0; j < 4; ++j) {
        int gr = gr0 + j;
        if (gr < M) C[(size_t)gr * 64 + gc] = f2bf(acc[mi][ni][j]);
      }
    }
  }
}

// ---------------- per-node attention coefficients ----------------
__global__ void k_alpha1(const unsigned short* __restrict__ h1b,
                         const float* __restrict__ a_src, const float* __restrict__ a_dst,
                         int n, float* __restrict__ asrc, float* __restrict__ adst) {
  int wave = (blockIdx.x * blockDim.x + threadIdx.x) >> 6;
  int lane = threadIdx.x & 63;
  if (wave >= n) return;
  int hh = lane >> 3;
  ushort4 hv4 = *(const ushort4*)&h1b[(size_t)wave * D1 + lane * 4];
  float4 as = *(const float4*)&a_src[lane * 4];
  float4 ad = *(const float4*)&a_dst[lane * 4];
  float hx = bf2f(hv4.x), hy = bf2f(hv4.y), hz = bf2f(hv4.z), hw = bf2f(hv4.w);
  float ps = hx * as.x + hy * as.y + hz * as.z + hw * as.w;
  float pd = hx * ad.x + hy * ad.y + hz * ad.z + hw * ad.w;
#pragma unroll
  for (int off = 1; off < 8; off <<= 1) {
    ps += __shfl_xor(ps, off);
    pd += __shfl_xor(pd, off);
  }
  if ((lane & 7) == 0) { asrc[wave * 8 + hh] = ps; adst[wave * 8 + hh] = pd; }
}

__global__ void k_alpha2(const unsigned short* __restrict__ h2b,
                         const float* __restrict__ a_src, const float* __restrict__ a_dst,
                         int n, float* __restrict__ asrc, float* __restrict__ adst) {
  int wave = (blockIdx.x * blockDim.x + threadIdx.x) >> 6;
  int lane = threadIdx.x & 63;
  if (wave >= n) return;
  float hv = bf2f(h2b[(size_t)wave * ODIM + lane]);
  float ps = hv * a_src[lane];
  float pd = hv * a_dst[lane];
#pragma unroll
  for (int off = 1; off < 64; off <<= 1) {
    ps += __shfl_xor(ps, off);
    pd += __shfl_xor(pd, off);
  }
  if (lane == 0) { asrc[wave] = ps; adst[wave] = pd; }
}

// ---------------- layer-1 aggregation: no-max softmax, bias+ELU, split-bf16 out ----------------
__global__ void k_agg1(const int* __restrict__ offs, const int* __restrict__ csr_src,
                       const unsigned short* __restrict__ h1b, const float* __restrict__ asrc,
                       const float* __restrict__ adst, const float* __restrict__ b1,
                       int n, unsigned short* __restrict__ heluS) {
  int wave = (blockIdx.x * blockDim.x + threadIdx.x) >> 6;
  int lane = threadIdx.x & 63;
  if (wave >= n) return;
  int wv = __builtin_amdgcn_readfirstlane(wave);
  int hh = lane >> 3;
  float ad = adst[wv * 8 + hh];
  int b = offs[wv], e2 = offs[wv + 1];
  float ssum = 0.f;
  float ax = 0.f, ay = 0.f, az = 0.f, aw = 0.f;
  int i = b;
  for (; i + 7 < e2; i += 8) {
    int s[8];
#pragma unroll
    for (int u = 0; u < 8; ++u) s[u] = csr_src[i + u];
    ushort4 r[8];
#pragma unroll
    for (int u = 0; u < 8; ++u) r[u] = *(const ushort4*)&h1b[(size_t)s[u] * D1 + lane * 4];
#pragma unroll
    for (int u = 0; u < 8; ++u) {
      float w = __expf(lrelu(asrc[s[u] * 8 + hh] + ad));
      ssum += w;
      ax += w * bf2f(r[u].x);
      ay += w * bf2f(r[u].y);
      az += w * bf2f(r[u].z);
      aw += w * bf2f(r[u].w);
    }
  }
  for (; i < e2; ++i) {
    int s0 = csr_src[i];
    ushort4 r0 = *(const ushort4*)&h1b[(size_t)s0 * D1 + lane * 4];
    float w = __expf(lrelu(asrc[s0 * 8 + hh] + ad));
    ssum += w;
    ax += w * bf2f(r0.x);
    ay += w * bf2f(r0.y);
    az += w * bf2f(r0.z);
    aw += w * bf2f(r0.w);
  }
  float rr = 1.f / ssum;
  float4 bb = *(const float4*)&b1[lane * 4];
  float o0 = elu1(ax * rr + bb.x);
  float o1 = elu1(ay * rr + bb.y);
  float o2 = elu1(az * rr + bb.z);
  float o3 = elu1(aw * rr + bb.w);
  unsigned short h0 = f2bf(o0), h1_ = f2bf(o1), h2_ = f2bf(o2), h3 = f2bf(o3);
  *(ushort4*)&heluS[(size_t)wave * 512 + lane * 4] = make_ushort4(h0, h1_, h2_, h3);
  *(ushort4*)&heluS[(size_t)wave * 512 + 256 + lane * 4] =
      make_ushort4(f2bf(o0 - bf2f(h0)), f2bf(o1 - bf2f(h1_)),
                   f2bf(o2 - bf2f(h2_)), f2bf(o3 - bf2f(h3)));
}

// ---------------- layer-2 aggregation: no-max softmax + bias ----------------
__global__ void k_agg2(const int* __restrict__ offs, const int* __restrict__ csr_src,
                       const unsigned short* __restrict__ h2b, const float* __restrict__ asrc,
                       const float* __restrict__ adst, const float* __restrict__ b2,
                       int n, float* __restrict__ out) {
  int wave = (blockIdx.x * blockDim.x + threadIdx.x) >> 6;
  int lane = threadIdx.x & 63;
  if (wave >= n) return;
  int wv = __builtin_amdgcn_readfirstlane(wave);
  float ad = adst[wv];
  int b = offs[wv], e2 = offs[wv + 1];
  float ssum = 0.f, acc = 0.f;
  int i = b;
  for (; i + 7 < e2; i += 8) {
    int s[8];
#pragma unroll
    for (int u = 0; u < 8; ++u) s[u] = csr_src[i + u];
    unsigned short hv[8];
#pragma unroll
    for (int u = 0; u < 8; ++u) hv[u] = h2b[(size_t)s[u] * ODIM + lane];
#pragma unroll
    for (int u = 0; u < 8; ++u) {
      float w = __expf(lrelu(asrc[s[u]] + ad));
      ssum += w;
      acc += w * bf2f(hv[u]);
    }
  }
  for (; i < e2; ++i) {
    int s0 = csr_src[i];
    float w = __expf(lrelu(asrc[s0] + ad));
    ssum += w;
    acc += w * bf2f(h2b[(size_t)s0 * ODIM + lane]);
  }
  out[(size_t)wave * ODIM + lane] = acc / ssum + b2[lane];
}

extern "C" void kernel_launch(void* const* d_in, const int* in_sizes, int n_in,
                              void* d_out, int out_size, void* d_ws, size_t ws_size,
                              hipStream_t stream) {
  const float* x      = (const float*)d_in[0];
  const int* eidx     = (const int*)d_in[1];
  const float* W1     = (const float*)d_in[2];
  const float* asrc1w = (const float*)d_in[3];
  const float* adst1w = (const float*)d_in[4];
  const float* b1     = (const float*)d_in[5];
  const float* W2     = (const float*)d_in[6];
  const float* asrc2w = (const float*)d_in[7];
  const float* adst2w = (const float*)d_in[8];
  const float* b2     = (const float*)d_in[9];
  float* out = (float*)d_out;

  const int N = in_sizes[0] / D1;     // 50000
  const int E = in_sizes[1] / 2;      // 800000
  const int TE = E + N;
  const int* src = eidx;
  const int* dst = eidx + E;
  const int Mblk = (N + 127) / 128;   // 391
  const int Mpad = Mblk * 128;        // 50048

  // ---- workspace carve-up ----
  char* ws = (char*)d_ws;
  size_t off = 0;
  auto carve = [&](size_t bytes) -> char* {
    char* p = ws + off;
    off = (off + bytes + 255) & ~(size_t)255;
    return p;
  };
  unsigned short* heluS = (unsigned short*)carve((size_t)Mpad * 512 * 2);  // 51.25 MB
  unsigned short* h1b   = (unsigned short*)carve((size_t)Mpad * D1 * 2);   // 25.6 MB
  unsigned short* h2b   = (unsigned short*)carve((size_t)N * ODIM * 2);    // 6.4 MB
  unsigned short* BT1   = (unsigned short*)carve((size_t)2 * 65536 * 2);
  unsigned short* B2T2  = (unsigned short*)carve((size_t)64 * 768 * 2);
  float* asrc1 = (float*)carve((size_t)N * HEADS * 4);
  float* adst1 = (float*)carve((size_t)N * HEADS * 4);
  float* asrc2 = (float*)carve((size_t)N * 4);
  float* adst2 = (float*)carve((size_t)N * 4);
  int* deg     = (int*)carve((size_t)N * 4);
  int* offs    = (int*)carve((size_t)(N + 1) * 4);
  int* cursor  = (int*)carve((size_t)N * 4);
  int* partial = (int*)carve(1024);
  int* csr_src = (int*)carve((size_t)TE * 4);

  const int nb_n = (N + 255) / 256;
  const int nb_te = (TE + 255) / 256;

  // ---- CSR build (by dst) ----
  k_zero<<<nb_n, 256, 0, stream>>>(deg, N);
  k_hist<<<nb_te, 256, 0, stream>>>(dst, E, TE, deg);
  k_scan1<<<nb_n, 256, 0, stream>>>(deg, N, cursor, partial);
  k_scan2<<<1, 256, 0, stream>>>(partial, nb_n);
  k_scan3<<<nb_n, 256, 0, stream>>>(cursor, partial, N, TE, offs, cursor);
  k_scatter<<<nb_te, 256, 0, stream>>>(src, dst, E, TE, cursor, csr_src);

  // ---- layer 1 ----
  k_prepB1<<<(256 * 256 + 255) / 256, 256, 0, stream>>>(W1, BT1);
  {
    dim3 g(2, Mblk);
    k_gemm1<<<g, 512, 0, stream>>>(x, BT1, h1b, N);
  }
  k_alpha1<<<(N + 3) / 4, 256, 0, stream>>>(h1b, asrc1w, adst1w, N, asrc1, adst1);
  k_agg1<<<(N + 3) / 4, 256, 0, stream>>>(offs, csr_src, h1b, asrc1, adst1, b1, N, heluS);

  // ---- layer 2 ----
  k_prepB2<<<(256 * 64 + 255) / 256, 256, 0, stream>>>(W2, B2T2);
  k_gemm2<<<Mblk, 256, 0, stream>>>(heluS, B2T2, h2b, N);
  k_alpha2<<<(N + 3) / 4, 256, 0, stream>>>(h2b, asrc2w, adst2w, N, asrc2, adst2);
  k_agg2<<<(N + 3) / 4, 256, 0, stream>>>(offs, csr_src, h2b, asrc2, adst2, b2, N, out);
}

// Round 5
// 253.525 us; speedup vs baseline: 2.0318x; 1.0989x over previous
//
#include <hip/hip_runtime.h>
#include <hip/hip_bf16.h>

static constexpr int HEADS = 8;
static constexpr int D1 = 256;      // HEADS*HID
static constexpr int ODIM = 64;
static constexpr float NEG = 0.2f;

typedef __attribute__((ext_vector_type(8))) short bf16x8;
typedef __attribute__((ext_vector_type(8))) unsigned short u16x8;
typedef __attribute__((ext_vector_type(4))) float f32x4;

__device__ __forceinline__ float lrelu(float x) { return fmaxf(x, NEG * x); }
__device__ __forceinline__ float elu1(float x) { return x > 0.f ? x : expm1f(x); }

__device__ __forceinline__ unsigned short f2bf(float f) {
  unsigned u = __float_as_uint(f);
  unsigned r = (u + 0x7fffu + ((u >> 16) & 1u)) >> 16;
  return (unsigned short)r;
}
__device__ __forceinline__ float bf2f(unsigned short h) {
  return __uint_as_float((unsigned)h << 16);
}

__device__ __forceinline__ void gload_lds16(const void* g, void* l) {
  __builtin_amdgcn_global_load_lds(
      (const __attribute__((address_space(1))) void*)g,
      (__attribute__((address_space(3))) void*)l, 16, 0, 0);
}

// ---------------- CSR build ----------------
__global__ void k_zero(int* __restrict__ p, int n) {
  int i = blockIdx.x * blockDim.x + threadIdx.x;
  if (i < n) p[i] = 0;
}

__global__ void k_hist(const int* __restrict__ dst, int E, int TE, int* __restrict__ deg) {
  int i = blockIdx.x * blockDim.x + threadIdx.x;
  if (i >= TE) return;
  int d = (i < E) ? dst[i] : (i - E);
  atomicAdd(&deg[d], 1);
}

__global__ void k_scan1(const int* __restrict__ deg, int n,
                        int* __restrict__ excl, int* __restrict__ partial) {
  __shared__ int sm[256];
  int i = blockIdx.x * 256 + threadIdx.x;
  int v = (i < n) ? deg[i] : 0;
  sm[threadIdx.x] = v;
  __syncthreads();
  for (int off = 1; off < 256; off <<= 1) {
    int t = (threadIdx.x >= off) ? sm[threadIdx.x - off] : 0;
    __syncthreads();
    sm[threadIdx.x] += t;
    __syncthreads();
  }
  if (i < n) excl[i] = sm[threadIdx.x] - v;
  if (threadIdx.x == 255) partial[blockIdx.x] = sm[255];
}

__global__ void k_scan2(int* __restrict__ partial, int nb) {
  __shared__ int sm[256];
  int v = (threadIdx.x < nb) ? partial[threadIdx.x] : 0;
  sm[threadIdx.x] = v;
  __syncthreads();
  for (int off = 1; off < 256; off <<= 1) {
    int t = (threadIdx.x >= off) ? sm[threadIdx.x - off] : 0;
    __syncthreads();
    sm[threadIdx.x] += t;
    __syncthreads();
  }
  if (threadIdx.x < nb) partial[threadIdx.x] = sm[threadIdx.x] - v;  // exclusive
}

__global__ void k_scan3(const int* __restrict__ excl, const int* __restrict__ partial,
                        int n, int TE, int* __restrict__ offs, int* __restrict__ cursor) {
  int i = blockIdx.x * 256 + threadIdx.x;
  if (i < n) {
    int o = excl[i] + partial[i >> 8];
    offs[i] = o;
    cursor[i] = o;
  }
  if (i == 0) offs[n] = TE;
}

__global__ void k_scatter(const int* __restrict__ src, const int* __restrict__ dst,
                          int E, int TE, int* __restrict__ cursor, int* __restrict__ csr_src) {
  int i = blockIdx.x * blockDim.x + threadIdx.x;
  if (i >= TE) return;
  int s, d;
  if (i < E) { s = src[i]; d = dst[i]; } else { s = i - E; d = i - E; }
  int p = atomicAdd(&cursor[d], 1);
  csr_src[p] = s;
}

// ---------------- B-prep: transpose hi-bf16 of both weights ----------------
// BT1[n][k] = hi(W1[k][n])  [256][256];  B2T[n][k] = hi(W2[k][n])  [64][256]
__global__ void k_prepB(const float* __restrict__ W1, const float* __restrict__ W2,
                        unsigned short* __restrict__ BT1, unsigned short* __restrict__ B2T) {
  int t = blockIdx.x * 256 + threadIdx.x;
  if (t < 65536) {
    int k = t >> 8, n = t & 255;
    BT1[n * 256 + k] = f2bf(W1[t]);
  } else {
    int t2 = t - 65536;
    if (t2 < 16384) {
      int k = t2 >> 6, n = t2 & 63;
      B2T[n * 256 + k] = f2bf(W2[t2]);
    }
  }
}

// ---------------- GEMM1 (x fp32 -> in-reg split, 2-term) + fused alpha1 ----------------
// grid (2, Mblk), 512 threads = 8 waves (2m x 4n), BM=128, BN=128, BK=64.
__global__ __launch_bounds__(512) void k_gemm1(
    const float* __restrict__ X,            // [M][256]
    const unsigned short* __restrict__ BT,  // BT1 [256n][256k] (hi)
    const float* __restrict__ a_src, const float* __restrict__ a_dst,
    unsigned short* __restrict__ h1b,       // [Mpad][256]
    float* __restrict__ asrc, float* __restrict__ adst,
    int M) {
  __shared__ __align__(128) char AsH[16384];  // [128r][128B] XOR-swizzled
  __shared__ __align__(128) char AsL[16384];
  __shared__ __align__(128) char Bs[16384];   // [128c][128B] XOR-swizzled
  const int tid = threadIdx.x;
  const int lane = tid & 63;
  const int wid = tid >> 6;
  const int bn = blockIdx.x * 128;
  const int bm = blockIdx.y * 128;
  const int wm = wid >> 2, wn = wid & 3;      // wave tile 64x32
  f32x4 acc[4][2] = {};
  for (int kb = 0; kb < 256; kb += 64) {
    // ---- A: load fp32, split hi/lo, ds_write swizzled ----
#pragma unroll
    for (int q = 0; q < 2; ++q) {
      int c = q * 512 + tid;          // chunk 0..1023
      int r = c >> 3, kc = c & 7;     // row 0..127, 16B-chunk 0..7
      int gr = bm + r;
      float4 v0 = make_float4(0.f, 0.f, 0.f, 0.f), v1 = v0;
      if (gr < M) {
        v0 = *(const float4*)&X[(size_t)gr * 256 + kb + kc * 8];
        v1 = *(const float4*)&X[(size_t)gr * 256 + kb + kc * 8 + 4];
      }
      float vv[8] = {v0.x, v0.y, v0.z, v0.w, v1.x, v1.y, v1.z, v1.w};
      u16x8 hv, lv;
#pragma unroll
      for (int j = 0; j < 8; ++j) {
        unsigned short h = f2bf(vv[j]);
        hv[j] = h;
        lv[j] = f2bf(vv[j] - bf2f(h));
      }
      int wb = r * 128 + ((kc * 16) ^ ((r & 7) << 4));
      *(u16x8*)(AsH + wb) = hv;
      *(u16x8*)(AsL + wb) = lv;
    }
    // ---- B(hi): gload_lds16, linear dest + pre-swizzled source ----
#pragma unroll
    for (int q = 0; q < 2; ++q) {
      int c = q * 512 + tid;                   // chunk 0..1023
      int col = c >> 3;                        // 0..127
      int b = ((c & 7) * 16) ^ ((col & 7) << 4);
      gload_lds16(BT + (size_t)(bn + col) * 256 + kb + (b >> 1),
                  Bs + (size_t)(q * 512 + (tid & ~63)) * 16);
    }
    __syncthreads();
#pragma unroll
    for (int ks = 0; ks < 2; ++ks) {
      bf16x8 afH[4], afL[4], bfr[2];
      int bb = ks * 64 + (lane >> 4) * 16;
#pragma unroll
      for (int mi = 0; mi < 4; ++mi) {
        int row = wm * 64 + mi * 16 + (lane & 15);
        int ra = row * 128 + (bb ^ ((row & 7) << 4));
        afH[mi] = *(const bf16x8*)(AsH + ra);
        afL[mi] = *(const bf16x8*)(AsL + ra);
      }
#pragma unroll
      for (int ni = 0; ni < 2; ++ni) {
        int col = wn * 32 + ni * 16 + (lane & 15);
        bfr[ni] = *(const bf16x8*)(Bs + col * 128 + (bb ^ ((col & 7) << 4)));
      }
#pragma unroll
      for (int mi = 0; mi < 4; ++mi)
#pragma unroll
        for (int ni = 0; ni < 2; ++ni) {
          acc[mi][ni] = __builtin_amdgcn_mfma_f32_16x16x32_bf16(afH[mi], bfr[ni],
                                                                acc[mi][ni], 0, 0, 0);
          acc[mi][ni] = __builtin_amdgcn_mfma_f32_16x16x32_bf16(afL[mi], bfr[ni],
                                                                acc[mi][ni], 0, 0, 0);
        }
    }
    __syncthreads();
  }
  // ---- epilogue: h1b write + fused alpha1 (head = bn/32 + wn) ----
  const int head = (bn >> 5) + wn;
  const float a_s0 = a_src[head * 32 + (lane & 15)];
  const float a_s1 = a_src[head * 32 + 16 + (lane & 15)];
  const float a_d0 = a_dst[head * 32 + (lane & 15)];
  const float a_d1 = a_dst[head * 32 + 16 + (lane & 15)];
#pragma unroll
  for (int mi = 0; mi < 4; ++mi) {
    int gr0 = bm + wm * 64 + mi * 16 + (lane >> 4) * 4;
#pragma unroll
    for (int j = 0; j < 4; ++j) {
      int gr = gr0 + j;
      // h1b write (2 cols per lane via ni)
#pragma unroll
      for (int ni = 0; ni < 2; ++ni) {
        int gc = bn + wn * 32 + ni * 16 + (lane & 15);
        if (gr < M) h1b[(size_t)gr * 256 + gc] = f2bf(acc[mi][ni][j]);
      }
      // alpha: dot over the 32 channels of this head
      float ps = acc[mi][0][j] * a_s0 + acc[mi][1][j] * a_s1;
      float pd = acc[mi][0][j] * a_d0 + acc[mi][1][j] * a_d1;
#pragma unroll
      for (int off = 1; off < 16; off <<= 1) {
        ps += __shfl_xor(ps, off);
        pd += __shfl_xor(pd, off);
      }
      if ((lane & 15) == 0 && gr < M) {
        asrc[gr * 8 + head] = ps;
        adst[gr * 8 + head] = pd;
      }
    }
  }
}

// ---------------- GEMM2 (split-A 2-term) + fused alpha2 ----------------
// grid (Mblk), 256 threads = 4 waves (2x2), BM=128, BN=64, virtual K=512.
__global__ __launch_bounds__(256) void k_gemm2(
    const unsigned short* __restrict__ A2,   // heluS [Mpad][512]: hi 0..255, lo 256..511
    const unsigned short* __restrict__ B2T,  // [64][256] (hi)
    const float* __restrict__ a_src, const float* __restrict__ a_dst,
    unsigned short* __restrict__ C,          // h2b [M][64]
    float* __restrict__ asrc, float* __restrict__ adst,
    int M) {
  __shared__ __align__(128) char As[16384];  // [128r][128B]
  __shared__ __align__(128) char Bs[8192];   // [64c][128B]
  __shared__ float red[2][128][2];           // [wn][row][ps/pd]
  const int tid = threadIdx.x;
  const int lane = tid & 63;
  const int wid = tid >> 6;
  const int bm = blockIdx.x * 128;
  const int wm = wid >> 1, wn = wid & 1;
  f32x4 acc[4][2] = {};
  for (int kb = 0; kb < 512; kb += 64) {
#pragma unroll
    for (int q = 0; q < 4; ++q) {
      int c = q * 256 + tid;
      int r = c >> 3;
      int b = ((c & 7) * 16) ^ ((r & 7) << 4);
      gload_lds16(A2 + (size_t)(bm + r) * 512 + kb + (b >> 1),
                  As + (size_t)(q * 256 + (tid & ~63)) * 16);
    }
#pragma unroll
    for (int q = 0; q < 2; ++q) {
      int c = q * 256 + tid;
      int col = c >> 3;
      int b = ((c & 7) * 16) ^ ((col & 7) << 4);
      gload_lds16(B2T + (size_t)col * 256 + (kb & 255) + (b >> 1),
                  Bs + (size_t)(q * 256 + (tid & ~63)) * 16);
    }
    __syncthreads();
#pragma unroll
    for (int ks = 0; ks < 2; ++ks) {
      bf16x8 af[4], bfr[2];
      int bb = ks * 64 + (lane >> 4) * 16;
#pragma unroll
      for (int mi = 0; mi < 4; ++mi) {
        int row = wm * 64 + mi * 16 + (lane & 15);
        af[mi] = *(const bf16x8*)(As + row * 128 + (bb ^ ((row & 7) << 4)));
      }
#pragma unroll
      for (int ni = 0; ni < 2; ++ni) {
        int col = wn * 32 + ni * 16 + (lane & 15);
        bfr[ni] = *(const bf16x8*)(Bs + col * 128 + (bb ^ ((col & 7) << 4)));
      }
#pragma unroll
      for (int mi = 0; mi < 4; ++mi)
#pragma unroll
        for (int ni = 0; ni < 2; ++ni)
          acc[mi][ni] = __builtin_amdgcn_mfma_f32_16x16x32_bf16(af[mi], bfr[ni],
                                                                acc[mi][ni], 0, 0, 0);
    }
    __syncthreads();
  }
  // ---- epilogue: h2b write + fused alpha2 ----
  const float a_s0 = a_src[wn * 32 + (lane & 15)];
  const float a_s1 = a_src[wn * 32 + 16 + (lane & 15)];
  const float a_d0 = a_dst[wn * 32 + (lane & 15)];
  const float a_d1 = a_dst[wn * 32 + 16 + (lane & 15)];
#pragma unroll
  for (int mi = 0; mi < 4; ++mi) {
    int rl0 = wm * 64 + mi * 16 + (lane >> 4) * 4;
#pragma unroll
    for (int j = 0; j < 4; ++j) {
      int rl = rl0 + j;
      int gr = bm + rl;
#pragma unroll
      for (int ni = 0; ni < 2; ++ni) {
        int gc = wn * 32 + ni * 16 + (lane & 15);
        if (gr < M) C[(size_t)gr * 64 + gc] = f2bf(acc[mi][ni][j]);
      }
      float ps = acc[mi][0][j] * a_s0 + acc[mi][1][j] * a_s1;
      float pd = acc[mi][0][j] * a_d0 + acc[mi][1][j] * a_d1;
#pragma unroll
      for (int off = 1; off < 16; off <<= 1) {
        ps += __shfl_xor(ps, off);
        pd += __shfl_xor(pd, off);
      }
      if ((lane & 15) == 0) {
        red[wn][rl][0] = ps;
        red[wn][rl][1] = pd;
      }
    }
  }
  __syncthreads();
  if (tid < 128) {
    int gr = bm + tid;
    if (gr < M) {
      asrc[gr] = red[0][tid][0] + red[1][tid][0];
      adst[gr] = red[0][tid][1] + red[1][tid][1];
    }
  }
}

// ---------------- layer-1 aggregation: no-max softmax, bias+ELU, split-bf16 out ----------------
__global__ void k_agg1(const int* __restrict__ offs, const int* __restrict__ csr_src,
                       const unsigned short* __restrict__ h1b, const float* __restrict__ asrc,
                       const float* __restrict__ adst, const float* __restrict__ b1,
                       int n, unsigned short* __restrict__ heluS) {
  int wave = (blockIdx.x * blockDim.x + threadIdx.x) >> 6;
  int lane = threadIdx.x & 63;
  if (wave >= n) return;
  int wv = __builtin_amdgcn_readfirstlane(wave);
  int hh = lane >> 3;
  float ad = adst[wv * 8 + hh];
  int b = offs[wv], e2 = offs[wv + 1];
  float ssum = 0.f;
  float ax = 0.f, ay = 0.f, az = 0.f, aw = 0.f;
  int i = b;
  for (; i + 7 < e2; i += 8) {
    int s[8];
#pragma unroll
    for (int u = 0; u < 8; ++u) s[u] = csr_src[i + u];
    ushort4 r[8];
#pragma unroll
    for (int u = 0; u < 8; ++u) r[u] = *(const ushort4*)&h1b[(size_t)s[u] * D1 + lane * 4];
#pragma unroll
    for (int u = 0; u < 8; ++u) {
      float w = __expf(lrelu(asrc[s[u] * 8 + hh] + ad));
      ssum += w;
      ax += w * bf2f(r[u].x);
      ay += w * bf2f(r[u].y);
      az += w * bf2f(r[u].z);
      aw += w * bf2f(r[u].w);
    }
  }
  for (; i < e2; ++i) {
    int s0 = csr_src[i];
    ushort4 r0 = *(const ushort4*)&h1b[(size_t)s0 * D1 + lane * 4];
    float w = __expf(lrelu(asrc[s0 * 8 + hh] + ad));
    ssum += w;
    ax += w * bf2f(r0.x);
    ay += w * bf2f(r0.y);
    az += w * bf2f(r0.z);
    aw += w * bf2f(r0.w);
  }
  float rr = 1.f / ssum;
  float4 bb = *(const float4*)&b1[lane * 4];
  float o0 = elu1(ax * rr + bb.x);
  float o1 = elu1(ay * rr + bb.y);
  float o2 = elu1(az * rr + bb.z);
  float o3 = elu1(aw * rr + bb.w);
  unsigned short h0 = f2bf(o0), h1_ = f2bf(o1), h2_ = f2bf(o2), h3 = f2bf(o3);
  *(ushort4*)&heluS[(size_t)wave * 512 + lane * 4] = make_ushort4(h0, h1_, h2_, h3);
  *(ushort4*)&heluS[(size_t)wave * 512 + 256 + lane * 4] =
      make_ushort4(f2bf(o0 - bf2f(h0)), f2bf(o1 - bf2f(h1_)),
                   f2bf(o2 - bf2f(h2_)), f2bf(o3 - bf2f(h3)));
}

// ---------------- layer-2 aggregation: 4 edges x 16 lanes, no-max softmax + bias ----------------
__global__ void k_agg2(const int* __restrict__ offs, const int* __restrict__ csr_src,
                       const unsigned short* __restrict__ h2b, const float* __restrict__ asrc,
                       const float* __restrict__ adst, const float* __restrict__ b2,
                       int n, float* __restrict__ out) {
  int wave = (blockIdx.x * blockDim.x + threadIdx.x) >> 6;
  int lane = threadIdx.x & 63;
  if (wave >= n) return;
  int wv = __builtin_amdgcn_readfirstlane(wave);
  float ad = adst[wv];
  int b = offs[wv], e2 = offs[wv + 1];
  const int u = lane >> 4;         // edge slot 0..3
  const int c4 = (lane & 15) * 4;  // channel base
  float ssum = 0.f;
  float ax = 0.f, ay = 0.f, az = 0.f, aw = 0.f;
#pragma unroll 2
  for (int i = b; i < e2; i += 4) {
    int idx = i + u;
    bool act = idx < e2;
    int s = csr_src[act ? idx : (e2 - 1)];
    ushort4 hv = *(const ushort4*)&h2b[(size_t)s * ODIM + c4];
    float w = act ? __expf(lrelu(asrc[s] + ad)) : 0.f;
    ssum += w;
    ax += w * bf2f(hv.x);
    ay += w * bf2f(hv.y);
    az += w * bf2f(hv.z);
    aw += w * bf2f(hv.w);
  }
#pragma unroll
  for (int off = 16; off < 64; off <<= 1) {
    ssum += __shfl_xor(ssum, off);
    ax += __shfl_xor(ax, off);
    ay += __shfl_xor(ay, off);
    az += __shfl_xor(az, off);
    aw += __shfl_xor(aw, off);
  }
  if (lane < 16) {
    float r = 1.f / ssum;
    float4 bb = *(const float4*)&b2[c4];
    float4 o;
    o.x = ax * r + bb.x;
    o.y = ay * r + bb.y;
    o.z = az * r + bb.z;
    o.w = aw * r + bb.w;
    *(float4*)&out[(size_t)wave * ODIM + c4] = o;
  }
}

extern "C" void kernel_launch(void* const* d_in, const int* in_sizes, int n_in,
                              void* d_out, int out_size, void* d_ws, size_t ws_size,
                              hipStream_t stream) {
  const float* x      = (const float*)d_in[0];
  const int* eidx     = (const int*)d_in[1];
  const float* W1     = (const float*)d_in[2];
  const float* asrc1w = (const float*)d_in[3];
  const float* adst1w = (const float*)d_in[4];
  const float* b1     = (const float*)d_in[5];
  const float* W2     = (const float*)d_in[6];
  const float* asrc2w = (const float*)d_in[7];
  const float* adst2w = (const float*)d_in[8];
  const float* b2     = (const float*)d_in[9];
  float* out = (float*)d_out;

  const int N = in_sizes[0] / D1;     // 50000
  const int E = in_sizes[1] / 2;      // 800000
  const int TE = E + N;
  const int* src = eidx;
  const int* dst = eidx + E;
  const int Mblk = (N + 127) / 128;   // 391
  const int Mpad = Mblk * 128;        // 50048

  // ---- workspace carve-up ----
  char* ws = (char*)d_ws;
  size_t off = 0;
  auto carve = [&](size_t bytes) -> char* {
    char* p = ws + off;
    off = (off + bytes + 255) & ~(size_t)255;
    return p;
  };
  unsigned short* heluS = (unsigned short*)carve((size_t)Mpad * 512 * 2);  // 51.25 MB
  unsigned short* h1b   = (unsigned short*)carve((size_t)Mpad * D1 * 2);   // 25.6 MB
  unsigned short* h2b   = (unsigned short*)carve((size_t)N * ODIM * 2);    // 6.4 MB
  unsigned short* BT1   = (unsigned short*)carve((size_t)256 * 256 * 2);
  unsigned short* B2T2  = (unsigned short*)carve((size_t)64 * 256 * 2);
  float* asrc1 = (float*)carve((size_t)N * HEADS * 4);
  float* adst1 = (float*)carve((size_t)N * HEADS * 4);
  float* asrc2 = (float*)carve((size_t)N * 4);
  float* adst2 = (float*)carve((size_t)N * 4);
  int* deg     = (int*)carve((size_t)N * 4);
  int* offs    = (int*)carve((size_t)(N + 1) * 4);
  int* cursor  = (int*)carve((size_t)N * 4);
  int* partial = (int*)carve(1024);
  int* csr_src = (int*)carve((size_t)TE * 4);

  const int nb_n = (N + 255) / 256;
  const int nb_te = (TE + 255) / 256;

  // ---- CSR build (by dst) ----
  k_zero<<<nb_n, 256, 0, stream>>>(deg, N);
  k_hist<<<nb_te, 256, 0, stream>>>(dst, E, TE, deg);
  k_scan1<<<nb_n, 256, 0, stream>>>(deg, N, cursor, partial);
  k_scan2<<<1, 256, 0, stream>>>(partial, nb_n);
  k_scan3<<<nb_n, 256, 0, stream>>>(cursor, partial, N, TE, offs, cursor);
  k_scatter<<<nb_te, 256, 0, stream>>>(src, dst, E, TE, cursor, csr_src);

  // ---- weight prep (both layers) ----
  k_prepB<<<(65536 + 16384 + 255) / 256, 256, 0, stream>>>(W1, W2, BT1, B2T2);

  // ---- layer 1: GEMM + fused alpha1 ----
  {
    dim3 g(2, Mblk);
    k_gemm1<<<g, 512, 0, stream>>>(x, BT1, asrc1w, adst1w, h1b, asrc1, adst1, N);
  }
  k_agg1<<<(N + 3) / 4, 256, 0, stream>>>(offs, csr_src, h1b, asrc1, adst1, b1, N, heluS);

  // ---- layer 2: GEMM + fused alpha2 ----
  k_gemm2<<<Mblk, 256, 0, stream>>>(heluS, B2T2, asrc2w, adst2w, h2b, asrc2, adst2, N);
  k_agg2<<<(N + 3) / 4, 256, 0, stream>>>(offs, csr_src, h2b, asrc2, adst2, b2, N, out);
}

// Round 6
// 252.538 us; speedup vs baseline: 2.0397x; 1.0039x over previous
//
#include <hip/hip_runtime.h>
#include <hip/hip_bf16.h>

static constexpr int HEADS = 8;
static constexpr int D1 = 256;      // HEADS*HID
static constexpr int ODIM = 64;
static constexpr float NEG = 0.2f;

typedef __attribute__((ext_vector_type(8))) short bf16x8;
typedef __attribute__((ext_vector_type(8))) unsigned short u16x8;
typedef __attribute__((ext_vector_type(4))) float f32x4;

__device__ __forceinline__ float lrelu(float x) { return fmaxf(x, NEG * x); }
__device__ __forceinline__ float elu1(float x) { return x > 0.f ? x : expm1f(x); }

__device__ __forceinline__ unsigned short f2bf(float f) {
  unsigned u = __float_as_uint(f);
  unsigned r = (u + 0x7fffu + ((u >> 16) & 1u)) >> 16;
  return (unsigned short)r;
}
__device__ __forceinline__ float bf2f(unsigned short h) {
  return __uint_as_float((unsigned)h << 16);
}

__device__ __forceinline__ void gload_lds16(const void* g, void* l) {
  __builtin_amdgcn_global_load_lds(
      (const __attribute__((address_space(1))) void*)g,
      (__attribute__((address_space(3))) void*)l, 16, 0, 0);
}

// ---------------- CSR build ----------------
__global__ void k_hist(const int* __restrict__ dst, int E, int TE, int* __restrict__ deg) {
  int i = blockIdx.x * blockDim.x + threadIdx.x;
  if (i >= TE) return;
  int d = (i < E) ? dst[i] : (i - E);
  atomicAdd(&deg[d], 1);
}

__global__ void k_scan1(const int* __restrict__ deg, int n,
                        int* __restrict__ excl, int* __restrict__ partial) {
  __shared__ int sm[256];
  int i = blockIdx.x * 256 + threadIdx.x;
  int v = (i < n) ? deg[i] : 0;
  sm[threadIdx.x] = v;
  __syncthreads();
  for (int off = 1; off < 256; off <<= 1) {
    int t = (threadIdx.x >= off) ? sm[threadIdx.x - off] : 0;
    __syncthreads();
    sm[threadIdx.x] += t;
    __syncthreads();
  }
  if (i < n) excl[i] = sm[threadIdx.x] - v;
  if (threadIdx.x == 255) partial[blockIdx.x] = sm[255];
}

__global__ void k_scan2(int* __restrict__ partial, int nb) {
  __shared__ int sm[256];
  int v = (threadIdx.x < nb) ? partial[threadIdx.x] : 0;
  sm[threadIdx.x] = v;
  __syncthreads();
  for (int off = 1; off < 256; off <<= 1) {
    int t = (threadIdx.x >= off) ? sm[threadIdx.x - off] : 0;
    __syncthreads();
    sm[threadIdx.x] += t;
    __syncthreads();
  }
  if (threadIdx.x < nb) partial[threadIdx.x] = sm[threadIdx.x] - v;  // exclusive
}

__global__ void k_scan3(const int* __restrict__ excl, const int* __restrict__ partial,
                        int n, int TE, int* __restrict__ offs, int* __restrict__ cursor) {
  int i = blockIdx.x * 256 + threadIdx.x;
  if (i < n) {
    int o = excl[i] + partial[i >> 8];
    offs[i] = o;
    cursor[i] = o;
  }
  if (i == 0) offs[n] = TE;
}

__global__ void k_scatter(const int* __restrict__ src, const int* __restrict__ dst,
                          int E, int TE, int* __restrict__ cursor, int* __restrict__ csr_src) {
  int i = blockIdx.x * blockDim.x + threadIdx.x;
  if (i >= TE) return;
  int s, d;
  if (i < E) { s = src[i]; d = dst[i]; } else { s = i - E; d = i - E; }
  int p = atomicAdd(&cursor[d], 1);
  csr_src[p] = s;
}

// ---------------- B-prep: transpose hi-bf16 of both weights ----------------
__global__ void k_prepB(const float* __restrict__ W1, const float* __restrict__ W2,
                        unsigned short* __restrict__ BT1, unsigned short* __restrict__ B2T) {
  int t = blockIdx.x * 256 + threadIdx.x;
  if (t < 65536) {
    int k = t >> 8, n = t & 255;
    BT1[n * 256 + k] = f2bf(W1[t]);
  } else {
    int t2 = t - 65536;
    if (t2 < 16384) {
      int k = t2 >> 6, n = t2 & 63;
      B2T[n * 256 + k] = f2bf(W2[t2]);
    }
  }
}

// ---------------- GEMM1 (1-term bf16, BN=256) + fused alpha1 ----------------
// grid (Mblk), 512 threads = 8 waves (2m x 4n), BM=128, BN=256, BK=64.
__global__ __launch_bounds__(512) void k_gemm1(
    const float* __restrict__ X,            // [M][256]
    const unsigned short* __restrict__ BT,  // BT1 [256n][256k] (hi)
    const float* __restrict__ a_src, const float* __restrict__ a_dst,
    unsigned short* __restrict__ h1b,       // [Mpad][256]
    float* __restrict__ asrc, float* __restrict__ adst,
    int M) {
  __shared__ __align__(128) char As[16384];   // [128r][128B] XOR-swizzled
  __shared__ __align__(128) char Bs[32768];   // [256c][128B] XOR-swizzled
  const int tid = threadIdx.x;
  const int lane = tid & 63;
  const int wid = tid >> 6;
  const int bm = blockIdx.x * 128;
  const int wm = wid >> 2, wn = wid & 3;      // wave tile 64x64
  f32x4 acc[4][4] = {};
  for (int kb = 0; kb < 256; kb += 64) {
    // ---- A: load fp32, convert bf16, ds_write swizzled ----
#pragma unroll
    for (int q = 0; q < 2; ++q) {
      int c = q * 512 + tid;          // chunk 0..1023
      int r = c >> 3, kc = c & 7;     // row 0..127, 16B-chunk 0..7
      int gr = bm + r;
      float4 v0 = make_float4(0.f, 0.f, 0.f, 0.f), v1 = v0;
      if (gr < M) {
        v0 = *(const float4*)&X[(size_t)gr * 256 + kb + kc * 8];
        v1 = *(const float4*)&X[(size_t)gr * 256 + kb + kc * 8 + 4];
      }
      float vv[8] = {v0.x, v0.y, v0.z, v0.w, v1.x, v1.y, v1.z, v1.w};
      u16x8 hv;
#pragma unroll
      for (int j = 0; j < 8; ++j) hv[j] = f2bf(vv[j]);
      *(u16x8*)(As + r * 128 + ((kc * 16) ^ ((r & 7) << 4))) = hv;
    }
    // ---- B(hi): gload_lds16, linear dest + pre-swizzled source ----
#pragma unroll
    for (int q = 0; q < 4; ++q) {
      int c = q * 512 + tid;                   // chunk 0..2047
      int col = c >> 3;                        // 0..255
      int b = ((c & 7) * 16) ^ ((col & 7) << 4);
      gload_lds16(BT + (size_t)col * 256 + kb + (b >> 1),
                  Bs + (size_t)(q * 512 + (tid & ~63)) * 16);
    }
    __syncthreads();
#pragma unroll
    for (int ks = 0; ks < 2; ++ks) {
      bf16x8 af[4], bfr[4];
      int bb = ks * 64 + (lane >> 4) * 16;
#pragma unroll
      for (int mi = 0; mi < 4; ++mi) {
        int row = wm * 64 + mi * 16 + (lane & 15);
        af[mi] = *(const bf16x8*)(As + row * 128 + (bb ^ ((row & 7) << 4)));
      }
#pragma unroll
      for (int ni = 0; ni < 4; ++ni) {
        int col = wn * 64 + ni * 16 + (lane & 15);
        bfr[ni] = *(const bf16x8*)(Bs + col * 128 + (bb ^ ((col & 7) << 4)));
      }
#pragma unroll
      for (int mi = 0; mi < 4; ++mi)
#pragma unroll
        for (int ni = 0; ni < 4; ++ni)
          acc[mi][ni] = __builtin_amdgcn_mfma_f32_16x16x32_bf16(af[mi], bfr[ni],
                                                                acc[mi][ni], 0, 0, 0);
    }
    __syncthreads();
  }
  // ---- epilogue: h1b write + fused alpha1 (heads 2wn, 2wn+1) ----
  const int h0 = 2 * wn, h1h = 2 * wn + 1;
  const int cl = lane & 15;
  const float as0 = a_src[h0 * 32 + cl],      ad0 = a_dst[h0 * 32 + cl];
  const float as1 = a_src[h0 * 32 + 16 + cl], ad1 = a_dst[h0 * 32 + 16 + cl];
  const float as2 = a_src[h1h * 32 + cl],      ad2 = a_dst[h1h * 32 + cl];
  const float as3 = a_src[h1h * 32 + 16 + cl], ad3 = a_dst[h1h * 32 + 16 + cl];
#pragma unroll
  for (int mi = 0; mi < 4; ++mi) {
    int gr0 = bm + wm * 64 + mi * 16 + (lane >> 4) * 4;
#pragma unroll
    for (int j = 0; j < 4; ++j) {
      int gr = gr0 + j;
#pragma unroll
      for (int ni = 0; ni < 4; ++ni) {
        int gc = wn * 64 + ni * 16 + cl;
        if (gr < M) h1b[(size_t)gr * 256 + gc] = f2bf(acc[mi][ni][j]);
      }
      float ps0 = acc[mi][0][j] * as0 + acc[mi][1][j] * as1;
      float pd0 = acc[mi][0][j] * ad0 + acc[mi][1][j] * ad1;
      float ps1 = acc[mi][2][j] * as2 + acc[mi][3][j] * as3;
      float pd1 = acc[mi][2][j] * ad2 + acc[mi][3][j] * ad3;
#pragma unroll
      for (int off = 1; off < 16; off <<= 1) {
        ps0 += __shfl_xor(ps0, off);
        pd0 += __shfl_xor(pd0, off);
        ps1 += __shfl_xor(ps1, off);
        pd1 += __shfl_xor(pd1, off);
      }
      if (cl == 0 && gr < M) {
        asrc[gr * 8 + h0] = ps0;
        adst[gr * 8 + h0] = pd0;
        asrc[gr * 8 + h1h] = ps1;
        adst[gr * 8 + h1h] = pd1;
      }
    }
  }
}

// ---------------- GEMM2 (1-term bf16, K=256) + fused alpha2 ----------------
// grid (Mblk), 512 threads = 8 waves (4m x 2n), BM=128, BN=64.
__global__ __launch_bounds__(512) void k_gemm2(
    const unsigned short* __restrict__ A,    // helu [Mpad][256] bf16
    const unsigned short* __restrict__ B2T,  // [64][256] (hi)
    const float* __restrict__ a_src, const float* __restrict__ a_dst,
    unsigned short* __restrict__ C,          // h2b [M][64]
    float* __restrict__ asrc, float* __restrict__ adst,
    int M) {
  __shared__ __align__(128) char As[16384];  // [128r][128B]
  __shared__ __align__(128) char Bs[8192];   // [64c][128B]
  __shared__ float red[2][128][2];           // [wn][row][ps/pd]
  const int tid = threadIdx.x;
  const int lane = tid & 63;
  const int wid = tid >> 6;
  const int bm = blockIdx.x * 128;
  const int wm = wid >> 1, wn = wid & 1;     // wave tile 32x32
  f32x4 acc[2][2] = {};
  for (int kb = 0; kb < 256; kb += 64) {
#pragma unroll
    for (int q = 0; q < 2; ++q) {
      int c = q * 512 + tid;
      int r = c >> 3;
      int b = ((c & 7) * 16) ^ ((r & 7) << 4);
      gload_lds16(A + (size_t)(bm + r) * 256 + kb + (b >> 1),
                  As + (size_t)(q * 512 + (tid & ~63)) * 16);
    }
    {
      int c = tid;  // 512 chunks
      int col = c >> 3;
      int b = ((c & 7) * 16) ^ ((col & 7) << 4);
      gload_lds16(B2T + (size_t)col * 256 + kb + (b >> 1),
                  Bs + (size_t)(tid & ~63) * 16);
    }
    __syncthreads();
#pragma unroll
    for (int ks = 0; ks < 2; ++ks) {
      bf16x8 af[2], bfr[2];
      int bb = ks * 64 + (lane >> 4) * 16;
#pragma unroll
      for (int mi = 0; mi < 2; ++mi) {
        int row = wm * 32 + mi * 16 + (lane & 15);
        af[mi] = *(const bf16x8*)(As + row * 128 + (bb ^ ((row & 7) << 4)));
      }
#pragma unroll
      for (int ni = 0; ni < 2; ++ni) {
        int col = wn * 32 + ni * 16 + (lane & 15);
        bfr[ni] = *(const bf16x8*)(Bs + col * 128 + (bb ^ ((col & 7) << 4)));
      }
#pragma unroll
      for (int mi = 0; mi < 2; ++mi)
#pragma unroll
        for (int ni = 0; ni < 2; ++ni)
          acc[mi][ni] = __builtin_amdgcn_mfma_f32_16x16x32_bf16(af[mi], bfr[ni],
                                                                acc[mi][ni], 0, 0, 0);
    }
    __syncthreads();
  }
  // ---- epilogue: h2b write + fused alpha2 ----
  const int cl = lane & 15;
  const float a_s0 = a_src[wn * 32 + cl],      a_d0 = a_dst[wn * 32 + cl];
  const float a_s1 = a_src[wn * 32 + 16 + cl], a_d1 = a_dst[wn * 32 + 16 + cl];
#pragma unroll
  for (int mi = 0; mi < 2; ++mi) {
    int rl0 = wm * 32 + mi * 16 + (lane >> 4) * 4;
#pragma unroll
    for (int j = 0; j < 4; ++j) {
      int rl = rl0 + j;
      int gr = bm + rl;
#pragma unroll
      for (int ni = 0; ni < 2; ++ni) {
        int gc = wn * 32 + ni * 16 + cl;
        if (gr < M) C[(size_t)gr * 64 + gc] = f2bf(acc[mi][ni][j]);
      }
      float ps = acc[mi][0][j] * a_s0 + acc[mi][1][j] * a_s1;
      float pd = acc[mi][0][j] * a_d0 + acc[mi][1][j] * a_d1;
#pragma unroll
      for (int off = 1; off < 16; off <<= 1) {
        ps += __shfl_xor(ps, off);
        pd += __shfl_xor(pd, off);
      }
      if (cl == 0) {
        red[wn][rl][0] = ps;
        red[wn][rl][1] = pd;
      }
    }
  }
  __syncthreads();
  if (tid < 128) {
    int gr = bm + tid;
    if (gr < M) {
      asrc[gr] = red[0][tid][0] + red[1][tid][0];
      adst[gr] = red[0][tid][1] + red[1][tid][1];
    }
  }
}

// ---------------- layer-1 aggregation: no-max softmax, bias+ELU, bf16 out ----------------
__global__ void k_agg1(const int* __restrict__ offs, const int* __restrict__ csr_src,
                       const unsigned short* __restrict__ h1b, const float* __restrict__ asrc,
                       const float* __restrict__ adst, const float* __restrict__ b1,
                       int n, unsigned short* __restrict__ helu) {
  int wave = (blockIdx.x * blockDim.x + threadIdx.x) >> 6;
  int lane = threadIdx.x & 63;
  if (wave >= n) return;
  int wv = __builtin_amdgcn_readfirstlane(wave);
  int hh = lane >> 3;
  float ad = adst[wv * 8 + hh];
  int b = offs[wv], e2 = offs[wv + 1];
  float ssum = 0.f;
  float ax = 0.f, ay = 0.f, az = 0.f, aw = 0.f;
  int i = b;
  for (; i + 7 < e2; i += 8) {
    int s[8];
#pragma unroll
    for (int u = 0; u < 8; ++u) s[u] = csr_src[i + u];
    ushort4 r[8];
#pragma unroll
    for (int u = 0; u < 8; ++u) r[u] = *(const ushort4*)&h1b[(size_t)s[u] * D1 + lane * 4];
#pragma unroll
    for (int u = 0; u < 8; ++u) {
      float w = __expf(lrelu(asrc[s[u] * 8 + hh] + ad));
      ssum += w;
      ax += w * bf2f(r[u].x);
      ay += w * bf2f(r[u].y);
      az += w * bf2f(r[u].z);
      aw += w * bf2f(r[u].w);
    }
  }
  for (; i < e2; ++i) {
    int s0 = csr_src[i];
    ushort4 r0 = *(const ushort4*)&h1b[(size_t)s0 * D1 + lane * 4];
    float w = __expf(lrelu(asrc[s0 * 8 + hh] + ad));
    ssum += w;
    ax += w * bf2f(r0.x);
    ay += w * bf2f(r0.y);
    az += w * bf2f(r0.z);
    aw += w * bf2f(r0.w);
  }
  float rr = 1.f / ssum;
  float4 bb = *(const float4*)&b1[lane * 4];
  *(ushort4*)&helu[(size_t)wave * D1 + lane * 4] =
      make_ushort4(f2bf(elu1(ax * rr + bb.x)), f2bf(elu1(ay * rr + bb.y)),
                   f2bf(elu1(az * rr + bb.z)), f2bf(elu1(aw * rr + bb.w)));
}

// ---------------- layer-2 aggregation: 4 edges x 16 lanes, no-max softmax + bias ----------------
__global__ void k_agg2(const int* __restrict__ offs, const int* __restrict__ csr_src,
                       const unsigned short* __restrict__ h2b, const float* __restrict__ asrc,
                       const float* __restrict__ adst, const float* __restrict__ b2,
                       int n, float* __restrict__ out) {
  int wave = (blockIdx.x * blockDim.x + threadIdx.x) >> 6;
  int lane = threadIdx.x & 63;
  if (wave >= n) return;
  int wv = __builtin_amdgcn_readfirstlane(wave);
  float ad = adst[wv];
  int b = offs[wv], e2 = offs[wv + 1];
  const int u = lane >> 4;         // edge slot 0..3
  const int c4 = (lane & 15) * 4;  // channel base
  float ssum = 0.f;
  float ax = 0.f, ay = 0.f, az = 0.f, aw = 0.f;
#pragma unroll 2
  for (int i = b; i < e2; i += 4) {
    int idx = i + u;
    bool act = idx < e2;
    int s = csr_src[act ? idx : (e2 - 1)];
    ushort4 hv = *(const ushort4*)&h2b[(size_t)s * ODIM + c4];
    float w = act ? __expf(lrelu(asrc[s] + ad)) : 0.f;
    ssum += w;
    ax += w * bf2f(hv.x);
    ay += w * bf2f(hv.y);
    az += w * bf2f(hv.z);
    aw += w * bf2f(hv.w);
  }
#pragma unroll
  for (int off = 16; off < 64; off <<= 1) {
    ssum += __shfl_xor(ssum, off);
    ax += __shfl_xor(ax, off);
    ay += __shfl_xor(ay, off);
    az += __shfl_xor(az, off);
    aw += __shfl_xor(aw, off);
  }
  if (lane < 16) {
    float r = 1.f / ssum;
    float4 bb = *(const float4*)&b2[c4];
    float4 o;
    o.x = ax * r + bb.x;
    o.y = ay * r + bb.y;
    o.z = az * r + bb.z;
    o.w = aw * r + bb.w;
    *(float4*)&out[(size_t)wave * ODIM + c4] = o;
  }
}

extern "C" void kernel_launch(void* const* d_in, const int* in_sizes, int n_in,
                              void* d_out, int out_size, void* d_ws, size_t ws_size,
                              hipStream_t stream) {
  const float* x      = (const float*)d_in[0];
  const int* eidx     = (const int*)d_in[1];
  const float* W1     = (const float*)d_in[2];
  const float* asrc1w = (const float*)d_in[3];
  const float* adst1w = (const float*)d_in[4];
  const float* b1     = (const float*)d_in[5];
  const float* W2     = (const float*)d_in[6];
  const float* asrc2w = (const float*)d_in[7];
  const float* adst2w = (const float*)d_in[8];
  const float* b2     = (const float*)d_in[9];
  float* out = (float*)d_out;

  const int N = in_sizes[0] / D1;     // 50000
  const int E = in_sizes[1] / 2;      // 800000
  const int TE = E + N;
  const int* src = eidx;
  const int* dst = eidx + E;
  const int Mblk = (N + 127) / 128;   // 391
  const int Mpad = Mblk * 128;        // 50048

  // ---- workspace carve-up ----
  char* ws = (char*)d_ws;
  size_t off = 0;
  auto carve = [&](size_t bytes) -> char* {
    char* p = ws + off;
    off = (off + bytes + 255) & ~(size_t)255;
    return p;
  };
  unsigned short* helu = (unsigned short*)carve((size_t)Mpad * D1 * 2);   // 25.6 MB
  unsigned short* h1b  = (unsigned short*)carve((size_t)Mpad * D1 * 2);   // 25.6 MB
  unsigned short* h2b  = (unsigned short*)carve((size_t)N * ODIM * 2);    // 6.4 MB
  unsigned short* BT1  = (unsigned short*)carve((size_t)256 * 256 * 2);
  unsigned short* B2T2 = (unsigned short*)carve((size_t)64 * 256 * 2);
  float* asrc1 = (float*)carve((size_t)N * HEADS * 4);
  float* adst1 = (float*)carve((size_t)N * HEADS * 4);
  float* asrc2 = (float*)carve((size_t)N * 4);
  float* adst2 = (float*)carve((size_t)N * 4);
  int* deg     = (int*)carve((size_t)N * 4);
  int* offs    = (int*)carve((size_t)(N + 1) * 4);
  int* cursor  = (int*)carve((size_t)N * 4);
  int* partial = (int*)carve(1024);
  int* csr_src = (int*)carve((size_t)TE * 4);

  const int nb_n = (N + 255) / 256;
  const int nb_te = (TE + 255) / 256;

  // ---- CSR build (by dst) ----
  hipMemsetAsync(deg, 0, (size_t)N * 4, stream);
  k_hist<<<nb_te, 256, 0, stream>>>(dst, E, TE, deg);
  k_scan1<<<nb_n, 256, 0, stream>>>(deg, N, cursor, partial);
  k_scan2<<<1, 256, 0, stream>>>(partial, nb_n);
  k_scan3<<<nb_n, 256, 0, stream>>>(cursor, partial, N, TE, offs, cursor);
  k_scatter<<<nb_te, 256, 0, stream>>>(src, dst, E, TE, cursor, csr_src);

  // ---- weight prep (both layers) ----
  k_prepB<<<(65536 + 16384 + 255) / 256, 256, 0, stream>>>(W1, W2, BT1, B2T2);

  // ---- layer 1: GEMM + fused alpha1 ----
  k_gemm1<<<Mblk, 512, 0, stream>>>(x, BT1, asrc1w, adst1w, h1b, asrc1, adst1, N);
  k_agg1<<<(N + 3) / 4, 256, 0, stream>>>(offs, csr_src, h1b, asrc1, adst1, b1, N, helu);

  // ---- layer 2: GEMM + fused alpha2 ----
  k_gemm2<<<Mblk, 512, 0, stream>>>(helu, B2T2, asrc2w, adst2w, h2b, asrc2, adst2, N);
  k_agg2<<<(N + 3) / 4, 256, 0, stream>>>(offs, csr_src, h2b, asrc2, adst2, b2, N, out);
}

// Round 7
// 241.828 us; speedup vs baseline: 2.1301x; 1.0443x over previous
//
#include <hip/hip_runtime.h>
#include <hip/hip_bf16.h>

static constexpr int HEADS = 8;
static constexpr int D1 = 256;      // HEADS*HID
static constexpr int ODIM = 64;
static constexpr float NEG = 0.2f;

typedef __attribute__((ext_vector_type(8))) short bf16x8;
typedef __attribute__((ext_vector_type(8))) unsigned short u16x8;
typedef __attribute__((ext_vector_type(4))) float f32x4;

__device__ __forceinline__ float lrelu(float x) { return fmaxf(x, NEG * x); }
__device__ __forceinline__ float elu1(float x) { return x > 0.f ? x : expm1f(x); }

__device__ __forceinline__ unsigned short f2bf(float f) {
  unsigned u = __float_as_uint(f);
  unsigned r = (u + 0x7fffu + ((u >> 16) & 1u)) >> 16;
  return (unsigned short)r;
}
__device__ __forceinline__ float bf2f(unsigned short h) {
  return __uint_as_float((unsigned)h << 16);
}

__device__ __forceinline__ void gload_lds16(const void* g, void* l) {
  __builtin_amdgcn_global_load_lds(
      (const __attribute__((address_space(1))) void*)g,
      (__attribute__((address_space(3))) void*)l, 16, 0, 0);
}

// ---------------- hist + weight-prep (merged, independent block ranges) ----------------
__global__ void k_hist_prep(const int* __restrict__ dst, int E, int TE,
                            int* __restrict__ deg,
                            const float* __restrict__ W1, const float* __restrict__ W2,
                            unsigned short* __restrict__ BT1, unsigned short* __restrict__ B2T,
                            int HB) {
  int b = blockIdx.x;
  if (b < HB) {
    int i = b * 256 + threadIdx.x;
    if (i < TE) {
      int d = (i < E) ? dst[i] : (i - E);
      atomicAdd(&deg[d], 1);
    }
  } else {
    int t = (b - HB) * 256 + threadIdx.x;
    if (t < 65536) {
      int k = t >> 8, nn = t & 255;
      BT1[nn * 256 + k] = f2bf(W1[t]);
    } else if (t < 65536 + 16384) {
      int t2 = t - 65536;
      int k = t2 >> 6, nn = t2 & 63;
      B2T[nn * 256 + k] = f2bf(W2[t2]);
    }
  }
}

// ---------------- single-launch exclusive scan (decoupled lookback) ----------------
// tstate[t]: 0 = unpublished, (1<<24)|agg, (2<<24)|inclusive_prefix. Sums < 2^24.
__global__ void k_scan_lb(const int* __restrict__ deg, int n, int TE,
                          int* __restrict__ offs, int* __restrict__ cursor,
                          int* __restrict__ tstate, int* __restrict__ ticket) {
  __shared__ int sm[256];
  __shared__ int sh[2];  // [0]=tile, [1]=base
  if (threadIdx.x == 0) sh[0] = atomicAdd(ticket, 1);
  __syncthreads();
  const int tile = sh[0];
  int i = tile * 256 + threadIdx.x;
  int v = (i < n) ? deg[i] : 0;
  sm[threadIdx.x] = v;
  __syncthreads();
  for (int off = 1; off < 256; off <<= 1) {
    int t = (threadIdx.x >= off) ? sm[threadIdx.x - off] : 0;
    __syncthreads();
    sm[threadIdx.x] += t;
    __syncthreads();
  }
  const int total = sm[255];
  if (threadIdx.x == 0) {
    if (tile == 0) {
      __hip_atomic_store(&tstate[0], (2 << 24) | total, __ATOMIC_RELEASE,
                         __HIP_MEMORY_SCOPE_AGENT);
      sh[1] = 0;
    } else {
      __hip_atomic_store(&tstate[tile], (1 << 24) | total, __ATOMIC_RELEASE,
                         __HIP_MEMORY_SCOPE_AGENT);
    }
  }
  __syncthreads();
  if (tile != 0) {
    if (threadIdx.x < 64) {
      const int lane = threadIdx.x;
      int running = 0;
      int wstart = tile - 1;
      for (;;) {
        int idx = wstart - lane;
        int st = (idx >= 0)
                     ? __hip_atomic_load(&tstate[idx], __ATOMIC_ACQUIRE,
                                         __HIP_MEMORY_SCOPE_AGENT)
                     : (2 << 24);
        if (__ballot(st == 0)) continue;  // window not fully published yet
        unsigned long long pref = __ballot((st >> 24) == 2);
        int contrib;
        if (pref) {
          int flane = (int)__ffsll(pref) - 1;
          contrib = (lane <= flane) ? (st & 0xFFFFFF) : 0;
        } else {
          contrib = st & 0xFFFFFF;
        }
#pragma unroll
        for (int off2 = 1; off2 < 64; off2 <<= 1) contrib += __shfl_xor(contrib, off2);
        running += contrib;
        if (pref) break;
        wstart -= 64;
      }
      if (lane == 0) {
        sh[1] = running;
        __hip_atomic_store(&tstate[tile], (2 << 24) | (running + total),
                           __ATOMIC_RELEASE, __HIP_MEMORY_SCOPE_AGENT);
      }
    }
    __syncthreads();
  }
  const int base = sh[1];
  if (i < n) {
    int o = base + sm[threadIdx.x] - v;
    offs[i] = o;
    cursor[i] = o;
  }
  if (i == 0) offs[n] = TE;
}

__global__ void k_scatter(const int* __restrict__ src, const int* __restrict__ dst,
                          int E, int TE, int* __restrict__ cursor, int* __restrict__ csr_src) {
  int i = blockIdx.x * blockDim.x + threadIdx.x;
  if (i >= TE) return;
  int s, d;
  if (i < E) { s = src[i]; d = dst[i]; } else { s = i - E; d = i - E; }
  int p = atomicAdd(&cursor[d], 1);
  csr_src[p] = s;
}

// ---------------- GEMM1 (1-term bf16, BN=256) + fused alpha1 ----------------
// grid (Mblk), 512 threads = 8 waves (2m x 4n), BM=128, BN=256, BK=64.
__global__ __launch_bounds__(512) void k_gemm1(
    const float* __restrict__ X,            // [M][256]
    const unsigned short* __restrict__ BT,  // BT1 [256n][256k] (hi)
    const float* __restrict__ a_src, const float* __restrict__ a_dst,
    unsigned short* __restrict__ h1b,       // [Mpad][256]
    float* __restrict__ asrc, float* __restrict__ adst,
    int M) {
  __shared__ __align__(128) char As[16384];   // [128r][128B] XOR-swizzled
  __shared__ __align__(128) char Bs[32768];   // [256c][128B] XOR-swizzled
  const int tid = threadIdx.x;
  const int lane = tid & 63;
  const int wid = tid >> 6;
  const int bm = blockIdx.x * 128;
  const int wm = wid >> 2, wn = wid & 3;      // wave tile 64x64
  f32x4 acc[4][4] = {};
  for (int kb = 0; kb < 256; kb += 64) {
#pragma unroll
    for (int q = 0; q < 2; ++q) {
      int c = q * 512 + tid;          // chunk 0..1023
      int r = c >> 3, kc = c & 7;     // row 0..127, 16B-chunk 0..7
      int gr = bm + r;
      float4 v0 = make_float4(0.f, 0.f, 0.f, 0.f), v1 = v0;
      if (gr < M) {
        v0 = *(const float4*)&X[(size_t)gr * 256 + kb + kc * 8];
        v1 = *(const float4*)&X[(size_t)gr * 256 + kb + kc * 8 + 4];
      }
      float vv[8] = {v0.x, v0.y, v0.z, v0.w, v1.x, v1.y, v1.z, v1.w};
      u16x8 hv;
#pragma unroll
      for (int j = 0; j < 8; ++j) hv[j] = f2bf(vv[j]);
      *(u16x8*)(As + r * 128 + ((kc * 16) ^ ((r & 7) << 4))) = hv;
    }
#pragma unroll
    for (int q = 0; q < 4; ++q) {
      int c = q * 512 + tid;                   // chunk 0..2047
      int col = c >> 3;                        // 0..255
      int b = ((c & 7) * 16) ^ ((col & 7) << 4);
      gload_lds16(BT + (size_t)col * 256 + kb + (b >> 1),
                  Bs + (size_t)(q * 512 + (tid & ~63)) * 16);
    }
    __syncthreads();
#pragma unroll
    for (int ks = 0; ks < 2; ++ks) {
      bf16x8 af[4], bfr[4];
      int bb = ks * 64 + (lane >> 4) * 16;
#pragma unroll
      for (int mi = 0; mi < 4; ++mi) {
        int row = wm * 64 + mi * 16 + (lane & 15);
        af[mi] = *(const bf16x8*)(As + row * 128 + (bb ^ ((row & 7) << 4)));
      }
#pragma unroll
      for (int ni = 0; ni < 4; ++ni) {
        int col = wn * 64 + ni * 16 + (lane & 15);
        bfr[ni] = *(const bf16x8*)(Bs + col * 128 + (bb ^ ((col & 7) << 4)));
      }
#pragma unroll
      for (int mi = 0; mi < 4; ++mi)
#pragma unroll
        for (int ni = 0; ni < 4; ++ni)
          acc[mi][ni] = __builtin_amdgcn_mfma_f32_16x16x32_bf16(af[mi], bfr[ni],
                                                                acc[mi][ni], 0, 0, 0);
    }
    __syncthreads();
  }
  // ---- epilogue: h1b write + fused alpha1 (heads 2wn, 2wn+1) ----
  const int h0 = 2 * wn, h1h = 2 * wn + 1;
  const int cl = lane & 15;
  const float as0 = a_src[h0 * 32 + cl],      ad0 = a_dst[h0 * 32 + cl];
  const float as1 = a_src[h0 * 32 + 16 + cl], ad1 = a_dst[h0 * 32 + 16 + cl];
  const float as2 = a_src[h1h * 32 + cl],      ad2 = a_dst[h1h * 32 + cl];
  const float as3 = a_src[h1h * 32 + 16 + cl], ad3 = a_dst[h1h * 32 + 16 + cl];
#pragma unroll
  for (int mi = 0; mi < 4; ++mi) {
    int gr0 = bm + wm * 64 + mi * 16 + (lane >> 4) * 4;
#pragma unroll
    for (int j = 0; j < 4; ++j) {
      int gr = gr0 + j;
#pragma unroll
      for (int ni = 0; ni < 4; ++ni) {
        int gc = wn * 64 + ni * 16 + cl;
        if (gr < M) h1b[(size_t)gr * 256 + gc] = f2bf(acc[mi][ni][j]);
      }
      float ps0 = acc[mi][0][j] * as0 + acc[mi][1][j] * as1;
      float pd0 = acc[mi][0][j] * ad0 + acc[mi][1][j] * ad1;
      float ps1 = acc[mi][2][j] * as2 + acc[mi][3][j] * as3;
      float pd1 = acc[mi][2][j] * ad2 + acc[mi][3][j] * ad3;
#pragma unroll
      for (int off = 1; off < 16; off <<= 1) {
        ps0 += __shfl_xor(ps0, off);
        pd0 += __shfl_xor(pd0, off);
        ps1 += __shfl_xor(ps1, off);
        pd1 += __shfl_xor(pd1, off);
      }
      if (cl == 0 && gr < M) {
        asrc[gr * 8 + h0] = ps0;
        adst[gr * 8 + h0] = pd0;
        asrc[gr * 8 + h1h] = ps1;
        adst[gr * 8 + h1h] = pd1;
      }
    }
  }
}

// ---------------- GEMM2 (1-term bf16, K=256) + fused alpha2 ----------------
__global__ __launch_bounds__(512) void k_gemm2(
    const unsigned short* __restrict__ A,    // helu [Mpad][256] bf16
    const unsigned short* __restrict__ B2T,  // [64][256] (hi)
    const float* __restrict__ a_src, const float* __restrict__ a_dst,
    unsigned short* __restrict__ C,          // h2b [M][64]
    float* __restrict__ asrc, float* __restrict__ adst,
    int M) {
  __shared__ __align__(128) char As[16384];  // [128r][128B]
  __shared__ __align__(128) char Bs[8192];   // [64c][128B]
  __shared__ float red[2][128][2];           // [wn][row][ps/pd]
  const int tid = threadIdx.x;
  const int lane = tid & 63;
  const int wid = tid >> 6;
  const int bm = blockIdx.x * 128;
  const int wm = wid >> 1, wn = wid & 1;     // wave tile 32x32
  f32x4 acc[2][2] = {};
  for (int kb = 0; kb < 256; kb += 64) {
#pragma unroll
    for (int q = 0; q < 2; ++q) {
      int c = q * 512 + tid;
      int r = c >> 3;
      int b = ((c & 7) * 16) ^ ((r & 7) << 4);
      gload_lds16(A + (size_t)(bm + r) * 256 + kb + (b >> 1),
                  As + (size_t)(q * 512 + (tid & ~63)) * 16);
    }
    {
      int c = tid;  // 512 chunks
      int col = c >> 3;
      int b = ((c & 7) * 16) ^ ((col & 7) << 4);
      gload_lds16(B2T + (size_t)col * 256 + kb + (b >> 1),
                  Bs + (size_t)(tid & ~63) * 16);
    }
    __syncthreads();
#pragma unroll
    for (int ks = 0; ks < 2; ++ks) {
      bf16x8 af[2], bfr[2];
      int bb = ks * 64 + (lane >> 4) * 16;
#pragma unroll
      for (int mi = 0; mi < 2; ++mi) {
        int row = wm * 32 + mi * 16 + (lane & 15);
        af[mi] = *(const bf16x8*)(As + row * 128 + (bb ^ ((row & 7) << 4)));
      }
#pragma unroll
      for (int ni = 0; ni < 2; ++ni) {
        int col = wn * 32 + ni * 16 + (lane & 15);
        bfr[ni] = *(const bf16x8*)(Bs + col * 128 + (bb ^ ((col & 7) << 4)));
      }
#pragma unroll
      for (int mi = 0; mi < 2; ++mi)
#pragma unroll
        for (int ni = 0; ni < 2; ++ni)
          acc[mi][ni] = __builtin_amdgcn_mfma_f32_16x16x32_bf16(af[mi], bfr[ni],
                                                                acc[mi][ni], 0, 0, 0);
    }
    __syncthreads();
  }
  const int cl = lane & 15;
  const float a_s0 = a_src[wn * 32 + cl],      a_d0 = a_dst[wn * 32 + cl];
  const float a_s1 = a_src[wn * 32 + 16 + cl], a_d1 = a_dst[wn * 32 + 16 + cl];
#pragma unroll
  for (int mi = 0; mi < 2; ++mi) {
    int rl0 = wm * 32 + mi * 16 + (lane >> 4) * 4;
#pragma unroll
    for (int j = 0; j < 4; ++j) {
      int rl = rl0 + j;
      int gr = bm + rl;
#pragma unroll
      for (int ni = 0; ni < 2; ++ni) {
        int gc = wn * 32 + ni * 16 + cl;
        if (gr < M) C[(size_t)gr * 64 + gc] = f2bf(acc[mi][ni][j]);
      }
      float ps = acc[mi][0][j] * a_s0 + acc[mi][1][j] * a_s1;
      float pd = acc[mi][0][j] * a_d0 + acc[mi][1][j] * a_d1;
#pragma unroll
      for (int off = 1; off < 16; off <<= 1) {
        ps += __shfl_xor(ps, off);
        pd += __shfl_xor(pd, off);
      }
      if (cl == 0) {
        red[wn][rl][0] = ps;
        red[wn][rl][1] = pd;
      }
    }
  }
  __syncthreads();
  if (tid < 128) {
    int gr = bm + tid;
    if (gr < M) {
      asrc[gr] = red[0][tid][0] + red[1][tid][0];
      adst[gr] = red[0][tid][1] + red[1][tid][1];
    }
  }
}

// ---------------- layer-1 aggregation: 2 edge slots x 32 lanes, u16x8 gathers ----------------
__global__ void k_agg1(const int* __restrict__ offs, const int* __restrict__ csr_src,
                       const unsigned short* __restrict__ h1b, const float* __restrict__ asrc,
                       const float* __restrict__ adst, const float* __restrict__ b1,
                       int n, unsigned short* __restrict__ helu) {
  int wave = (blockIdx.x * blockDim.x + threadIdx.x) >> 6;
  int lane = threadIdx.x & 63;
  if (wave >= n) return;
  int wv = __builtin_amdgcn_readfirstlane(wave);
  const int es = lane >> 5;   // edge slot 0..1
  const int cg = lane & 31;   // channel octet
  const int hh = cg >> 2;     // head
  float ad = adst[wv * 8 + hh];
  int b = offs[wv], e2 = offs[wv + 1];
  float ssum = 0.f;
  float acc[8] = {};
  int i = b;
  for (; i + 7 < e2; i += 8) {
#pragma unroll
    for (int u = 0; u < 4; ++u) {
      int s = csr_src[i + 2 * u + es];
      u16x8 r = *(const u16x8*)&h1b[(size_t)s * D1 + cg * 8];
      float w = __expf(lrelu(asrc[s * 8 + hh] + ad));
      ssum += w;
#pragma unroll
      for (int j = 0; j < 8; ++j) acc[j] += w * bf2f(r[j]);
    }
  }
  for (; i < e2; i += 2) {
    int idx = i + es;
    bool act = idx < e2;
    int s = csr_src[act ? idx : e2 - 1];
    u16x8 r = *(const u16x8*)&h1b[(size_t)s * D1 + cg * 8];
    float w = act ? __expf(lrelu(asrc[s * 8 + hh] + ad)) : 0.f;
    ssum += w;
#pragma unroll
    for (int j = 0; j < 8; ++j) acc[j] += w * bf2f(r[j]);
  }
  ssum += __shfl_xor(ssum, 32);
#pragma unroll
  for (int j = 0; j < 8; ++j) acc[j] += __shfl_xor(acc[j], 32);
  if (lane < 32) {
    float rr = 1.f / ssum;
    float4 bb0 = *(const float4*)&b1[cg * 8];
    float4 bb1 = *(const float4*)&b1[cg * 8 + 4];
    float bbv[8] = {bb0.x, bb0.y, bb0.z, bb0.w, bb1.x, bb1.y, bb1.z, bb1.w};
    u16x8 o;
#pragma unroll
    for (int j = 0; j < 8; ++j) o[j] = f2bf(elu1(acc[j] * rr + bbv[j]));
    *(u16x8*)&helu[(size_t)wave * D1 + cg * 8] = o;
  }
}

// ---------------- layer-2 aggregation: 8 edge slots x 8 lanes, u16x8 gathers ----------------
__global__ void k_agg2(const int* __restrict__ offs, const int* __restrict__ csr_src,
                       const unsigned short* __restrict__ h2b, const float* __restrict__ asrc,
                       const float* __restrict__ adst, const float* __restrict__ b2,
                       int n, float* __restrict__ out) {
  int wave = (blockIdx.x * blockDim.x + threadIdx.x) >> 6;
  int lane = threadIdx.x & 63;
  if (wave >= n) return;
  int wv = __builtin_amdgcn_readfirstlane(wave);
  float ad = adst[wv];
  int b = offs[wv], e2 = offs[wv + 1];
  const int es = lane >> 3;  // edge slot 0..7
  const int cg = lane & 7;   // channel octet 0..7
  float ssum = 0.f;
  float acc[8] = {};
  int i = b;
  for (; i + 7 < e2; i += 8) {
    int s = csr_src[i + es];
    u16x8 r = *(const u16x8*)&h2b[(size_t)s * ODIM + cg * 8];
    float w = __expf(lrelu(asrc[s] + ad));
    ssum += w;
#pragma unroll
    for (int j = 0; j < 8; ++j) acc[j] += w * bf2f(r[j]);
  }
  if (i < e2) {
    int idx = i + es;
    bool act = idx < e2;
    int s = csr_src[act ? idx : e2 - 1];
    u16x8 r = *(const u16x8*)&h2b[(size_t)s * ODIM + cg * 8];
    float w = act ? __expf(lrelu(asrc[s] + ad)) : 0.f;
    ssum += w;
#pragma unroll
    for (int j = 0; j < 8; ++j) acc[j] += w * bf2f(r[j]);
  }
#pragma unroll
  for (int off = 8; off < 64; off <<= 1) {
    ssum += __shfl_xor(ssum, off);
#pragma unroll
    for (int j = 0; j < 8; ++j) acc[j] += __shfl_xor(acc[j], off);
  }
  if (lane < 8) {
    float r = 1.f / ssum;
    float4 bb0 = *(const float4*)&b2[cg * 8];
    float4 bb1 = *(const float4*)&b2[cg * 8 + 4];
    float4 o0, o1;
    o0.x = acc[0] * r + bb0.x; o0.y = acc[1] * r + bb0.y;
    o0.z = acc[2] * r + bb0.z; o0.w = acc[3] * r + bb0.w;
    o1.x = acc[4] * r + bb1.x; o1.y = acc[5] * r + bb1.y;
    o1.z = acc[6] * r + bb1.z; o1.w = acc[7] * r + bb1.w;
    *(float4*)&out[(size_t)wave * ODIM + cg * 8] = o0;
    *(float4*)&out[(size_t)wave * ODIM + cg * 8 + 4] = o1;
  }
}

extern "C" void kernel_launch(void* const* d_in, const int* in_sizes, int n_in,
                              void* d_out, int out_size, void* d_ws, size_t ws_size,
                              hipStream_t stream) {
  const float* x      = (const float*)d_in[0];
  const int* eidx     = (const int*)d_in[1];
  const float* W1     = (const float*)d_in[2];
  const float* asrc1w = (const float*)d_in[3];
  const float* adst1w = (const float*)d_in[4];
  const float* b1     = (const float*)d_in[5];
  const float* W2     = (const float*)d_in[6];
  const float* asrc2w = (const float*)d_in[7];
  const float* adst2w = (const float*)d_in[8];
  const float* b2     = (const float*)d_in[9];
  float* out = (float*)d_out;

  const int N = in_sizes[0] / D1;     // 50000
  const int E = in_sizes[1] / 2;      // 800000
  const int TE = E + N;
  const int* src = eidx;
  const int* dst = eidx + E;
  const int Mblk = (N + 127) / 128;   // 391
  const int Mpad = Mblk * 128;        // 50048
  const int nb_n = (N + 255) / 256;   // 196
  const int nb_te = (TE + 255) / 256;

  // ---- workspace carve-up ----
  char* ws = (char*)d_ws;
  size_t off = 0;
  auto carve = [&](size_t bytes) -> char* {
    char* p = ws + off;
    off = (off + bytes + 255) & ~(size_t)255;
    return p;
  };
  unsigned short* helu = (unsigned short*)carve((size_t)Mpad * D1 * 2);   // 25.6 MB
  unsigned short* h1b  = (unsigned short*)carve((size_t)Mpad * D1 * 2);   // 25.6 MB
  unsigned short* h2b  = (unsigned short*)carve((size_t)N * ODIM * 2);    // 6.4 MB
  unsigned short* BT1  = (unsigned short*)carve((size_t)256 * 256 * 2);
  unsigned short* B2T2 = (unsigned short*)carve((size_t)64 * 256 * 2);
  float* asrc1 = (float*)carve((size_t)N * HEADS * 4);
  float* adst1 = (float*)carve((size_t)N * HEADS * 4);
  float* asrc2 = (float*)carve((size_t)N * 4);
  float* adst2 = (float*)carve((size_t)N * 4);
  // zero region: deg | tstate | ticket  (single memset)
  int* zr      = (int*)carve((size_t)(N + nb_n + 64) * 4);
  int* deg     = zr;
  int* tstate  = zr + N;
  int* ticket  = zr + N + nb_n;
  int* offs    = (int*)carve((size_t)(N + 1) * 4);
  int* cursor  = (int*)carve((size_t)N * 4);
  int* csr_src = (int*)carve((size_t)TE * 4);

  // ---- CSR build ----
  hipMemsetAsync(zr, 0, (size_t)(N + nb_n + 1) * 4, stream);
  {
    const int HB = nb_te;
    const int PB = (65536 + 16384) / 256;  // 320 prep blocks
    k_hist_prep<<<HB + PB, 256, 0, stream>>>(dst, E, TE, deg, W1, W2, BT1, B2T2, HB);
  }
  k_scan_lb<<<nb_n, 256, 0, stream>>>(deg, N, TE, offs, cursor, tstate, ticket);
  k_scatter<<<nb_te, 256, 0, stream>>>(src, dst, E, TE, cursor, csr_src);

  // ---- layer 1: GEMM + fused alpha1 ----
  k_gemm1<<<Mblk, 512, 0, stream>>>(x, BT1, asrc1w, adst1w, h1b, asrc1, adst1, N);
  k_agg1<<<(N + 3) / 4, 256, 0, stream>>>(offs, csr_src, h1b, asrc1, adst1, b1, N, helu);

  // ---- layer 2: GEMM + fused alpha2 ----
  k_gemm2<<<Mblk, 512, 0, stream>>>(helu, B2T2, asrc2w, adst2w, h2b, asrc2, adst2, N);
  k_agg2<<<(N + 3) / 4, 256, 0, stream>>>(offs, csr_src, h2b, asrc2, adst2, b2, N, out);
}

// Round 8
// 239.533 us; speedup vs baseline: 2.1505x; 1.0096x over previous
//
#include <hip/hip_runtime.h>
#include <hip/hip_bf16.h>

static constexpr int HEADS = 8;
static constexpr int D1 = 256;      // HEADS*HID
static constexpr int ODIM = 64;
static constexpr float NEG = 0.2f;

typedef __attribute__((ext_vector_type(8))) short bf16x8;
typedef __attribute__((ext_vector_type(8))) unsigned short u16x8;
typedef __attribute__((ext_vector_type(4))) float f32x4;

__device__ __forceinline__ float lrelu(float x) { return fmaxf(x, NEG * x); }
__device__ __forceinline__ float elu1(float x) { return x > 0.f ? x : expm1f(x); }

__device__ __forceinline__ unsigned short f2bf(float f) {
  unsigned u = __float_as_uint(f);
  unsigned r = (u + 0x7fffu + ((u >> 16) & 1u)) >> 16;
  return (unsigned short)r;
}
__device__ __forceinline__ float bf2f(unsigned short h) {
  return __uint_as_float((unsigned)h << 16);
}

__device__ __forceinline__ void gload_lds16(const void* g, void* l) {
  __builtin_amdgcn_global_load_lds(
      (const __attribute__((address_space(1))) void*)g,
      (__attribute__((address_space(3))) void*)l, 16, 0, 0);
}

// ---------------- hist + weight-prep (merged, independent block ranges) ----------------
__global__ void k_hist_prep(const int* __restrict__ dst, int E, int TE,
                            int* __restrict__ deg,
                            const float* __restrict__ W1, const float* __restrict__ W2,
                            unsigned short* __restrict__ BT1, unsigned short* __restrict__ B2T,
                            int HB) {
  int b = blockIdx.x;
  if (b < HB) {
    int i = b * 256 + threadIdx.x;
    if (i < TE) {
      int d = (i < E) ? dst[i] : (i - E);
      atomicAdd(&deg[d], 1);
    }
  } else {
    int t = (b - HB) * 256 + threadIdx.x;
    if (t < 65536) {
      int k = t >> 8, nn = t & 255;
      BT1[nn * 256 + k] = f2bf(W1[t]);
    } else if (t < 65536 + 16384) {
      int t2 = t - 65536;
      int k = t2 >> 6, nn = t2 & 63;
      B2T[nn * 256 + k] = f2bf(W2[t2]);
    }
  }
}

// ---------------- single-launch exclusive scan (decoupled lookback) ----------------
__global__ void k_scan_lb(const int* __restrict__ deg, int n, int TE,
                          int* __restrict__ offs, int* __restrict__ cursor,
                          int* __restrict__ tstate, int* __restrict__ ticket) {
  __shared__ int sm[256];
  __shared__ int sh[2];  // [0]=tile, [1]=base
  if (threadIdx.x == 0) sh[0] = atomicAdd(ticket, 1);
  __syncthreads();
  const int tile = sh[0];
  int i = tile * 256 + threadIdx.x;
  int v = (i < n) ? deg[i] : 0;
  sm[threadIdx.x] = v;
  __syncthreads();
  for (int off = 1; off < 256; off <<= 1) {
    int t = (threadIdx.x >= off) ? sm[threadIdx.x - off] : 0;
    __syncthreads();
    sm[threadIdx.x] += t;
    __syncthreads();
  }
  const int total = sm[255];
  if (threadIdx.x == 0) {
    if (tile == 0) {
      __hip_atomic_store(&tstate[0], (2 << 24) | total, __ATOMIC_RELEASE,
                         __HIP_MEMORY_SCOPE_AGENT);
      sh[1] = 0;
    } else {
      __hip_atomic_store(&tstate[tile], (1 << 24) | total, __ATOMIC_RELEASE,
                         __HIP_MEMORY_SCOPE_AGENT);
    }
  }
  __syncthreads();
  if (tile != 0) {
    if (threadIdx.x < 64) {
      const int lane = threadIdx.x;
      int running = 0;
      int wstart = tile - 1;
      for (;;) {
        int idx = wstart - lane;
        int st = (idx >= 0)
                     ? __hip_atomic_load(&tstate[idx], __ATOMIC_ACQUIRE,
                                         __HIP_MEMORY_SCOPE_AGENT)
                     : (2 << 24);
        if (__ballot(st == 0)) continue;
        unsigned long long pref = __ballot((st >> 24) == 2);
        int contrib;
        if (pref) {
          int flane = (int)__ffsll(pref) - 1;
          contrib = (lane <= flane) ? (st & 0xFFFFFF) : 0;
        } else {
          contrib = st & 0xFFFFFF;
        }
#pragma unroll
        for (int off2 = 1; off2 < 64; off2 <<= 1) contrib += __shfl_xor(contrib, off2);
        running += contrib;
        if (pref) break;
        wstart -= 64;
      }
      if (lane == 0) {
        sh[1] = running;
        __hip_atomic_store(&tstate[tile], (2 << 24) | (running + total),
                           __ATOMIC_RELEASE, __HIP_MEMORY_SCOPE_AGENT);
      }
    }
    __syncthreads();
  }
  const int base = sh[1];
  if (i < n) {
    int o = base + sm[threadIdx.x] - v;
    offs[i] = o;
    cursor[i] = o;
  }
  if (i == 0) offs[n] = TE;
}

// ---------------- GEMM1 (1-term bf16, BN=256, x-prefetch) + fused alpha1 ∥ scatter ----------------
// blocks [0,Mblk): GEMM tiles. blocks [Mblk,..): CSR scatter (independent work overlap).
__global__ __launch_bounds__(512) void k_gemm1s(
    const float* __restrict__ X,            // [M][256]
    const unsigned short* __restrict__ BT,  // BT1 [256n][256k] (hi)
    const float* __restrict__ a_src, const float* __restrict__ a_dst,
    unsigned short* __restrict__ h1b,       // [Mpad][256]
    float* __restrict__ asrc, float* __restrict__ adst,
    int M, int Mblk,
    const int* __restrict__ src, const int* __restrict__ dst, int E, int TE,
    int* __restrict__ cursor, int* __restrict__ csr_src) {
  __shared__ __align__(128) char As[16384];   // [128r][128B] XOR-swizzled
  __shared__ __align__(128) char Bs[32768];   // [256c][128B] XOR-swizzled
  if (blockIdx.x >= Mblk) {
    // ---- scatter part ----
    int i = (blockIdx.x - Mblk) * 512 + threadIdx.x;
    if (i < TE) {
      int s, d;
      if (i < E) { s = src[i]; d = dst[i]; } else { s = i - E; d = i - E; }
      int p = atomicAdd(&cursor[d], 1);
      csr_src[p] = s;
    }
    return;
  }
  const int tid = threadIdx.x;
  const int lane = tid & 63;
  const int wid = tid >> 6;
  const int bm = blockIdx.x * 128;
  const int wm = wid >> 2, wn = wid & 3;      // wave tile 64x64
  f32x4 acc[4][4] = {};
  float4 xv[2][2];
  auto loadX = [&](int kb) {
#pragma unroll
    for (int q = 0; q < 2; ++q) {
      int c = q * 512 + tid;
      int r = c >> 3, kc = c & 7;
      int gr = bm + r;
      xv[q][0] = make_float4(0.f, 0.f, 0.f, 0.f);
      xv[q][1] = xv[q][0];
      if (gr < M) {
        xv[q][0] = *(const float4*)&X[(size_t)gr * 256 + kb + kc * 8];
        xv[q][1] = *(const float4*)&X[(size_t)gr * 256 + kb + kc * 8 + 4];
      }
    }
  };
  loadX(0);
  for (int kb = 0; kb < 256; kb += 64) {
    // ---- A: convert staged regs to bf16, ds_write swizzled ----
#pragma unroll
    for (int q = 0; q < 2; ++q) {
      int c = q * 512 + tid;
      int r = c >> 3, kc = c & 7;
      float vv[8] = {xv[q][0].x, xv[q][0].y, xv[q][0].z, xv[q][0].w,
                     xv[q][1].x, xv[q][1].y, xv[q][1].z, xv[q][1].w};
      u16x8 hv;
#pragma unroll
      for (int j = 0; j < 8; ++j) hv[j] = f2bf(vv[j]);
      *(u16x8*)(As + r * 128 + ((kc * 16) ^ ((r & 7) << 4))) = hv;
    }
    // ---- B(hi): gload_lds16, linear dest + pre-swizzled source ----
#pragma unroll
    for (int q = 0; q < 4; ++q) {
      int c = q * 512 + tid;                   // chunk 0..2047
      int col = c >> 3;                        // 0..255
      int b = ((c & 7) * 16) ^ ((col & 7) << 4);
      gload_lds16(BT + (size_t)col * 256 + kb + (b >> 1),
                  Bs + (size_t)(q * 512 + (tid & ~63)) * 16);
    }
    __syncthreads();
    if (kb + 64 < 256) loadX(kb + 64);  // prefetch next x under MFMA
#pragma unroll
    for (int ks = 0; ks < 2; ++ks) {
      bf16x8 af[4], bfr[4];
      int bb = ks * 64 + (lane >> 4) * 16;
#pragma unroll
      for (int mi = 0; mi < 4; ++mi) {
        int row = wm * 64 + mi * 16 + (lane & 15);
        af[mi] = *(const bf16x8*)(As + row * 128 + (bb ^ ((row & 7) << 4)));
      }
#pragma unroll
      for (int ni = 0; ni < 4; ++ni) {
        int col = wn * 64 + ni * 16 + (lane & 15);
        bfr[ni] = *(const bf16x8*)(Bs + col * 128 + (bb ^ ((col & 7) << 4)));
      }
#pragma unroll
      for (int mi = 0; mi < 4; ++mi)
#pragma unroll
        for (int ni = 0; ni < 4; ++ni)
          acc[mi][ni] = __builtin_amdgcn_mfma_f32_16x16x32_bf16(af[mi], bfr[ni],
                                                                acc[mi][ni], 0, 0, 0);
    }
    __syncthreads();
  }
  // ---- epilogue: h1b write + fused alpha1 (heads 2wn, 2wn+1) ----
  const int h0 = 2 * wn, h1h = 2 * wn + 1;
  const int cl = lane & 15;
  const float as0 = a_src[h0 * 32 + cl],      ad0 = a_dst[h0 * 32 + cl];
  const float as1 = a_src[h0 * 32 + 16 + cl], ad1 = a_dst[h0 * 32 + 16 + cl];
  const float as2 = a_src[h1h * 32 + cl],      ad2 = a_dst[h1h * 32 + cl];
  const float as3 = a_src[h1h * 32 + 16 + cl], ad3 = a_dst[h1h * 32 + 16 + cl];
#pragma unroll
  for (int mi = 0; mi < 4; ++mi) {
    int gr0 = bm + wm * 64 + mi * 16 + (lane >> 4) * 4;
#pragma unroll
    for (int j = 0; j < 4; ++j) {
      int gr = gr0 + j;
#pragma unroll
      for (int ni = 0; ni < 4; ++ni) {
        int gc = wn * 64 + ni * 16 + cl;
        if (gr < M) h1b[(size_t)gr * 256 + gc] = f2bf(acc[mi][ni][j]);
      }
      float ps0 = acc[mi][0][j] * as0 + acc[mi][1][j] * as1;
      float pd0 = acc[mi][0][j] * ad0 + acc[mi][1][j] * ad1;
      float ps1 = acc[mi][2][j] * as2 + acc[mi][3][j] * as3;
      float pd1 = acc[mi][2][j] * ad2 + acc[mi][3][j] * ad3;
#pragma unroll
      for (int off = 1; off < 16; off <<= 1) {
        ps0 += __shfl_xor(ps0, off);
        pd0 += __shfl_xor(pd0, off);
        ps1 += __shfl_xor(ps1, off);
        pd1 += __shfl_xor(pd1, off);
      }
      if (cl == 0 && gr < M) {
        asrc[gr * 8 + h0] = ps0;
        adst[gr * 8 + h0] = pd0;
        asrc[gr * 8 + h1h] = ps1;
        adst[gr * 8 + h1h] = pd1;
      }
    }
  }
}

// ---------------- GEMM2 (1-term bf16, K=256) + fused alpha2 ----------------
__global__ __launch_bounds__(512) void k_gemm2(
    const unsigned short* __restrict__ A,    // helu [Mpad][256] bf16
    const unsigned short* __restrict__ B2T,  // [64][256] (hi)
    const float* __restrict__ a_src, const float* __restrict__ a_dst,
    unsigned short* __restrict__ C,          // h2b [M][64]
    float* __restrict__ asrc, float* __restrict__ adst,
    int M) {
  __shared__ __align__(128) char As[16384];  // [128r][128B]
  __shared__ __align__(128) char Bs[8192];   // [64c][128B]
  __shared__ float red[2][128][2];           // [wn][row][ps/pd]
  const int tid = threadIdx.x;
  const int lane = tid & 63;
  const int wid = tid >> 6;
  const int bm = blockIdx.x * 128;
  const int wm = wid >> 1, wn = wid & 1;     // wave tile 32x32
  f32x4 acc[2][2] = {};
  for (int kb = 0; kb < 256; kb += 64) {
#pragma unroll
    for (int q = 0; q < 2; ++q) {
      int c = q * 512 + tid;
      int r = c >> 3;
      int b = ((c & 7) * 16) ^ ((r & 7) << 4);
      gload_lds16(A + (size_t)(bm + r) * 256 + kb + (b >> 1),
                  As + (size_t)(q * 512 + (tid & ~63)) * 16);
    }
    {
      int c = tid;  // 512 chunks
      int col = c >> 3;
      int b = ((c & 7) * 16) ^ ((col & 7) << 4);
      gload_lds16(B2T + (size_t)col * 256 + kb + (b >> 1),
                  Bs + (size_t)(tid & ~63) * 16);
    }
    __syncthreads();
#pragma unroll
    for (int ks = 0; ks < 2; ++ks) {
      bf16x8 af[2], bfr[2];
      int bb = ks * 64 + (lane >> 4) * 16;
#pragma unroll
      for (int mi = 0; mi < 2; ++mi) {
        int row = wm * 32 + mi * 16 + (lane & 15);
        af[mi] = *(const bf16x8*)(As + row * 128 + (bb ^ ((row & 7) << 4)));
      }
#pragma unroll
      for (int ni = 0; ni < 2; ++ni) {
        int col = wn * 32 + ni * 16 + (lane & 15);
        bfr[ni] = *(const bf16x8*)(Bs + col * 128 + (bb ^ ((col & 7) << 4)));
      }
#pragma unroll
      for (int mi = 0; mi < 2; ++mi)
#pragma unroll
        for (int ni = 0; ni < 2; ++ni)
          acc[mi][ni] = __builtin_amdgcn_mfma_f32_16x16x32_bf16(af[mi], bfr[ni],
                                                                acc[mi][ni], 0, 0, 0);
    }
    __syncthreads();
  }
  const int cl = lane & 15;
  const float a_s0 = a_src[wn * 32 + cl],      a_d0 = a_dst[wn * 32 + cl];
  const float a_s1 = a_src[wn * 32 + 16 + cl], a_d1 = a_dst[wn * 32 + 16 + cl];
#pragma unroll
  for (int mi = 0; mi < 2; ++mi) {
    int rl0 = wm * 32 + mi * 16 + (lane >> 4) * 4;
#pragma unroll
    for (int j = 0; j < 4; ++j) {
      int rl = rl0 + j;
      int gr = bm + rl;
#pragma unroll
      for (int ni = 0; ni < 2; ++ni) {
        int gc = wn * 32 + ni * 16 + cl;
        if (gr < M) C[(size_t)gr * 64 + gc] = f2bf(acc[mi][ni][j]);
      }
      float ps = acc[mi][0][j] * a_s0 + acc[mi][1][j] * a_s1;
      float pd = acc[mi][0][j] * a_d0 + acc[mi][1][j] * a_d1;
#pragma unroll
      for (int off = 1; off < 16; off <<= 1) {
        ps += __shfl_xor(ps, off);
        pd += __shfl_xor(pd, off);
      }
      if (cl == 0) {
        red[wn][rl][0] = ps;
        red[wn][rl][1] = pd;
      }
    }
  }
  __syncthreads();
  if (tid < 128) {
    int gr = bm + tid;
    if (gr < M) {
      asrc[gr] = red[0][tid][0] + red[1][tid][0];
      adst[gr] = red[0][tid][1] + red[1][tid][1];
    }
  }
}

// ---------------- layer-1 aggregation: 2 edge slots x 32 lanes, batched phases ----------------
__global__ void k_agg1(const int* __restrict__ offs, const int* __restrict__ csr_src,
                       const unsigned short* __restrict__ h1b, const float* __restrict__ asrc,
                       const float* __restrict__ adst, const float* __restrict__ b1,
                       int n, unsigned short* __restrict__ helu) {
  int wave = (blockIdx.x * blockDim.x + threadIdx.x) >> 6;
  int lane = threadIdx.x & 63;
  if (wave >= n) return;
  int wv = __builtin_amdgcn_readfirstlane(wave);
  const int es = lane >> 5;   // edge slot 0..1
  const int cg = lane & 31;   // channel octet
  const int hh = cg >> 2;     // head
  float ad = adst[wv * 8 + hh];
  int b = offs[wv], e2 = offs[wv + 1];
  float ssum = 0.f;
  float acc[8] = {};
  int i = b;
  for (; i + 7 < e2; i += 8) {
    int s[4];
#pragma unroll
    for (int u = 0; u < 4; ++u) s[u] = csr_src[i + 2 * u + es];
    u16x8 r[4];
    float as_[4];
#pragma unroll
    for (int u = 0; u < 4; ++u) {
      r[u] = *(const u16x8*)&h1b[(size_t)s[u] * D1 + cg * 8];
      as_[u] = asrc[s[u] * 8 + hh];
    }
#pragma unroll
    for (int u = 0; u < 4; ++u) {
      float w = __expf(lrelu(as_[u] + ad));
      ssum += w;
#pragma unroll
      for (int j = 0; j < 8; ++j) acc[j] += w * bf2f(r[u][j]);
    }
  }
  for (; i < e2; i += 2) {
    int idx = i + es;
    bool act = idx < e2;
    int s = csr_src[act ? idx : e2 - 1];
    u16x8 r = *(const u16x8*)&h1b[(size_t)s * D1 + cg * 8];
    float w = act ? __expf(lrelu(asrc[s * 8 + hh] + ad)) : 0.f;
    ssum += w;
#pragma unroll
    for (int j = 0; j < 8; ++j) acc[j] += w * bf2f(r[j]);
  }
  ssum += __shfl_xor(ssum, 32);
#pragma unroll
  for (int j = 0; j < 8; ++j) acc[j] += __shfl_xor(acc[j], 32);
  if (lane < 32) {
    float rr = 1.f / ssum;
    float4 bb0 = *(const float4*)&b1[cg * 8];
    float4 bb1 = *(const float4*)&b1[cg * 8 + 4];
    float bbv[8] = {bb0.x, bb0.y, bb0.z, bb0.w, bb1.x, bb1.y, bb1.z, bb1.w};
    u16x8 o;
#pragma unroll
    for (int j = 0; j < 8; ++j) o[j] = f2bf(elu1(acc[j] * rr + bbv[j]));
    *(u16x8*)&helu[(size_t)wave * D1 + cg * 8] = o;
  }
}

// ---------------- layer-2 aggregation: 8 edge slots x 8 lanes, batched ----------------
__global__ void k_agg2(const int* __restrict__ offs, const int* __restrict__ csr_src,
                       const unsigned short* __restrict__ h2b, const float* __restrict__ asrc,
                       const float* __restrict__ adst, const float* __restrict__ b2,
                       int n, float* __restrict__ out) {
  int wave = (blockIdx.x * blockDim.x + threadIdx.x) >> 6;
  int lane = threadIdx.x & 63;
  if (wave >= n) return;
  int wv = __builtin_amdgcn_readfirstlane(wave);
  float ad = adst[wv];
  int b = offs[wv], e2 = offs[wv + 1];
  const int es = lane >> 3;  // edge slot 0..7
  const int cg = lane & 7;   // channel octet 0..7
  float ssum = 0.f;
  float acc[8] = {};
  int i = b;
  for (; i + 15 < e2; i += 16) {
    int s0 = csr_src[i + es], s1 = csr_src[i + 8 + es];
    u16x8 r0 = *(const u16x8*)&h2b[(size_t)s0 * ODIM + cg * 8];
    u16x8 r1 = *(const u16x8*)&h2b[(size_t)s1 * ODIM + cg * 8];
    float a0 = asrc[s0], a1 = asrc[s1];
    float w0 = __expf(lrelu(a0 + ad));
    float w1 = __expf(lrelu(a1 + ad));
    ssum += w0 + w1;
#pragma unroll
    for (int j = 0; j < 8; ++j) acc[j] += w0 * bf2f(r0[j]) + w1 * bf2f(r1[j]);
  }
  for (; i < e2; i += 8) {
    int idx = i + es;
    bool act = idx < e2;
    int s = csr_src[act ? idx : e2 - 1];
    u16x8 r = *(const u16x8*)&h2b[(size_t)s * ODIM + cg * 8];
    float w = act ? __expf(lrelu(asrc[s] + ad)) : 0.f;
    ssum += w;
#pragma unroll
    for (int j = 0; j < 8; ++j) acc[j] += w * bf2f(r[j]);
  }
#pragma unroll
  for (int off = 8; off < 64; off <<= 1) {
    ssum += __shfl_xor(ssum, off);
#pragma unroll
    for (int j = 0; j < 8; ++j) acc[j] += __shfl_xor(acc[j], off);
  }
  if (lane < 8) {
    float r = 1.f / ssum;
    float4 bb0 = *(const float4*)&b2[cg * 8];
    float4 bb1 = *(const float4*)&b2[cg * 8 + 4];
    float4 o0, o1;
    o0.x = acc[0] * r + bb0.x; o0.y = acc[1] * r + bb0.y;
    o0.z = acc[2] * r + bb0.z; o0.w = acc[3] * r + bb0.w;
    o1.x = acc[4] * r + bb1.x; o1.y = acc[5] * r + bb1.y;
    o1.z = acc[6] * r + bb1.z; o1.w = acc[7] * r + bb1.w;
    *(float4*)&out[(size_t)wave * ODIM + cg * 8] = o0;
    *(float4*)&out[(size_t)wave * ODIM + cg * 8 + 4] = o1;
  }
}

extern "C" void kernel_launch(void* const* d_in, const int* in_sizes, int n_in,
                              void* d_out, int out_size, void* d_ws, size_t ws_size,
                              hipStream_t stream) {
  const float* x      = (const float*)d_in[0];
  const int* eidx     = (const int*)d_in[1];
  const float* W1     = (const float*)d_in[2];
  const float* asrc1w = (const float*)d_in[3];
  const float* adst1w = (const float*)d_in[4];
  const float* b1     = (const float*)d_in[5];
  const float* W2     = (const float*)d_in[6];
  const float* asrc2w = (const float*)d_in[7];
  const float* adst2w = (const float*)d_in[8];
  const float* b2     = (const float*)d_in[9];
  float* out = (float*)d_out;

  const int N = in_sizes[0] / D1;     // 50000
  const int E = in_sizes[1] / 2;      // 800000
  const int TE = E + N;
  const int* src = eidx;
  const int* dst = eidx + E;
  const int Mblk = (N + 127) / 128;   // 391
  const int Mpad = Mblk * 128;        // 50048
  const int nb_n = (N + 255) / 256;   // 196
  const int nb_te = (TE + 255) / 256;
  const int nb_sc = (TE + 511) / 512; // scatter blocks (512 thr)

  // ---- workspace carve-up ----
  char* ws = (char*)d_ws;
  size_t off = 0;
  auto carve = [&](size_t bytes) -> char* {
    char* p = ws + off;
    off = (off + bytes + 255) & ~(size_t)255;
    return p;
  };
  unsigned short* helu = (unsigned short*)carve((size_t)Mpad * D1 * 2);   // 25.6 MB
  unsigned short* h1b  = (unsigned short*)carve((size_t)Mpad * D1 * 2);   // 25.6 MB
  unsigned short* h2b  = (unsigned short*)carve((size_t)N * ODIM * 2);    // 6.4 MB
  unsigned short* BT1  = (unsigned short*)carve((size_t)256 * 256 * 2);
  unsigned short* B2T2 = (unsigned short*)carve((size_t)64 * 256 * 2);
  float* asrc1 = (float*)carve((size_t)N * HEADS * 4);
  float* adst1 = (float*)carve((size_t)N * HEADS * 4);
  float* asrc2 = (float*)carve((size_t)N * 4);
  float* adst2 = (float*)carve((size_t)N * 4);
  // zero region: deg | tstate | ticket  (single memset)
  int* zr      = (int*)carve((size_t)(N + nb_n + 64) * 4);
  int* deg     = zr;
  int* tstate  = zr + N;
  int* ticket  = zr + N + nb_n;
  int* offs    = (int*)carve((size_t)(N + 1) * 4);
  int* cursor  = (int*)carve((size_t)N * 4);
  int* csr_src = (int*)carve((size_t)TE * 4);

  // ---- CSR build (hist + prep merged; scatter overlapped with gemm1) ----
  hipMemsetAsync(zr, 0, (size_t)(N + nb_n + 1) * 4, stream);
  {
    const int HB = nb_te;
    const int PB = (65536 + 16384) / 256;  // 320 prep blocks
    k_hist_prep<<<HB + PB, 256, 0, stream>>>(dst, E, TE, deg, W1, W2, BT1, B2T2, HB);
  }
  k_scan_lb<<<nb_n, 256, 0, stream>>>(deg, N, TE, offs, cursor, tstate, ticket);

  // ---- layer 1: GEMM + fused alpha1, overlapped with scatter ----
  k_gemm1s<<<Mblk + nb_sc, 512, 0, stream>>>(x, BT1, asrc1w, adst1w, h1b, asrc1, adst1,
                                             N, Mblk, src, dst, E, TE, cursor, csr_src);
  k_agg1<<<(N + 3) / 4, 256, 0, stream>>>(offs, csr_src, h1b, asrc1, adst1, b1, N, helu);

  // ---- layer 2: GEMM + fused alpha2 ----
  k_gemm2<<<Mblk, 512, 0, stream>>>(helu, B2T2, asrc2w, adst2w, h2b, asrc2, adst2, N);
  k_agg2<<<(N + 3) / 4, 256, 0, stream>>>(offs, csr_src, h2b, asrc2, adst2, b2, N, out);
}

// Round 9
// 197.397 us; speedup vs baseline: 2.6095x; 1.2135x over previous
//
#include <hip/hip_runtime.h>
#include <hip/hip_bf16.h>

static constexpr int HEADS = 8;
static constexpr int D1 = 256;      // HEADS*HID
static constexpr int ODIM = 64;
static constexpr float NEG = 0.2f;

typedef __attribute__((ext_vector_type(8))) short bf16x8;
typedef __attribute__((ext_vector_type(8))) unsigned short u16x8;
typedef __attribute__((ext_vector_type(4))) float f32x4;

__device__ __forceinline__ float lrelu(float x) { return fmaxf(x, NEG * x); }
__device__ __forceinline__ float elu1(float x) { return x > 0.f ? x : expm1f(x); }

__device__ __forceinline__ unsigned short f2bf(float f) {
  unsigned u = __float_as_uint(f);
  unsigned r = (u + 0x7fffu + ((u >> 16) & 1u)) >> 16;
  return (unsigned short)r;
}
__device__ __forceinline__ float bf2f(unsigned short h) {
  return __uint_as_float((unsigned)h << 16);
}

__device__ __forceinline__ void gload_lds16(const void* g, void* l) {
  __builtin_amdgcn_global_load_lds(
      (const __attribute__((address_space(1))) void*)g,
      (__attribute__((address_space(3))) void*)l, 16, 0, 0);
}

// ---------------- hist (rank-capturing) + weight-prep (merged) ----------------
__global__ void k_hist_prep(const int* __restrict__ dst, int E, int TE,
                            int* __restrict__ deg, int* __restrict__ erank,
                            const float* __restrict__ W1, const float* __restrict__ W2,
                            unsigned short* __restrict__ BT1, unsigned short* __restrict__ B2T,
                            int HB) {
  int b = blockIdx.x;
  if (b < HB) {
    int i = b * 256 + threadIdx.x;
    if (i < TE) {
      int d = (i < E) ? dst[i] : (i - E);
      erank[i] = atomicAdd(&deg[d], 1);   // rank within segment, fixes scatter order
    }
  } else {
    int t = (b - HB) * 256 + threadIdx.x;
    if (t < 65536) {
      int k = t >> 8, nn = t & 255;
      BT1[nn * 256 + k] = f2bf(W1[t]);
    } else if (t < 65536 + 16384) {
      int t2 = t - 65536;
      int k = t2 >> 6, nn = t2 & 63;
      B2T[nn * 256 + k] = f2bf(W2[t2]);
    }
  }
}

// ---------------- single-launch exclusive scan (decoupled lookback) ----------------
__global__ void k_scan_lb(const int* __restrict__ deg, int n, int TE,
                          int* __restrict__ offs,
                          int* __restrict__ tstate, int* __restrict__ ticket) {
  __shared__ int sm[256];
  __shared__ int sh[2];  // [0]=tile, [1]=base
  if (threadIdx.x == 0) sh[0] = atomicAdd(ticket, 1);
  __syncthreads();
  const int tile = sh[0];
  int i = tile * 256 + threadIdx.x;
  int v = (i < n) ? deg[i] : 0;
  sm[threadIdx.x] = v;
  __syncthreads();
  for (int off = 1; off < 256; off <<= 1) {
    int t = (threadIdx.x >= off) ? sm[threadIdx.x - off] : 0;
    __syncthreads();
    sm[threadIdx.x] += t;
    __syncthreads();
  }
  const int total = sm[255];
  if (threadIdx.x == 0) {
    if (tile == 0) {
      __hip_atomic_store(&tstate[0], (2 << 24) | total, __ATOMIC_RELEASE,
                         __HIP_MEMORY_SCOPE_AGENT);
      sh[1] = 0;
    } else {
      __hip_atomic_store(&tstate[tile], (1 << 24) | total, __ATOMIC_RELEASE,
                         __HIP_MEMORY_SCOPE_AGENT);
    }
  }
  __syncthreads();
  if (tile != 0) {
    if (threadIdx.x < 64) {
      const int lane = threadIdx.x;
      int running = 0;
      int wstart = tile - 1;
      for (;;) {
        int idx = wstart - lane;
        int st = (idx >= 0)
                     ? __hip_atomic_load(&tstate[idx], __ATOMIC_ACQUIRE,
                                         __HIP_MEMORY_SCOPE_AGENT)
                     : (2 << 24);
        if (__ballot(st == 0)) continue;
        unsigned long long pref = __ballot((st >> 24) == 2);
        int contrib;
        if (pref) {
          int flane = (int)__ffsll(pref) - 1;
          contrib = (lane <= flane) ? (st & 0xFFFFFF) : 0;
        } else {
          contrib = st & 0xFFFFFF;
        }
#pragma unroll
        for (int off2 = 1; off2 < 64; off2 <<= 1) contrib += __shfl_xor(contrib, off2);
        running += contrib;
        if (pref) break;
        wstart -= 64;
      }
      if (lane == 0) {
        sh[1] = running;
        __hip_atomic_store(&tstate[tile], (2 << 24) | (running + total),
                           __ATOMIC_RELEASE, __HIP_MEMORY_SCOPE_AGENT);
      }
    }
    __syncthreads();
  }
  const int base = sh[1];
  if (i < n) offs[i] = base + sm[threadIdx.x] - v;
  if (i == 0) offs[n] = TE;
}

// ---------------- GEMM1 (1-term bf16, BN=256, x-prefetch) + fused alpha1 ∥ atomic-free scatter ----
__global__ __launch_bounds__(512) void k_gemm1s(
    const float* __restrict__ X,            // [M][256]
    const unsigned short* __restrict__ BT,  // BT1 [256n][256k] (hi)
    const float* __restrict__ a_src, const float* __restrict__ a_dst,
    unsigned short* __restrict__ h1b,       // [Mpad][256]
    float* __restrict__ asrc, float* __restrict__ adst,
    int M, int Mblk,
    const int* __restrict__ src, const int* __restrict__ dst, int E, int TE,
    const int* __restrict__ offs, const int* __restrict__ erank,
    int* __restrict__ csr_src) {
  __shared__ __align__(128) char As[16384];   // [128r][128B] XOR-swizzled
  __shared__ __align__(128) char Bs[32768];   // [256c][128B] XOR-swizzled
  if (blockIdx.x >= Mblk) {
    // ---- scatter part: pure writes, no atomics ----
    int i = (blockIdx.x - Mblk) * 512 + threadIdx.x;
    if (i < TE) {
      int s, d;
      if (i < E) { s = src[i]; d = dst[i]; } else { s = i - E; d = i - E; }
      csr_src[offs[d] + erank[i]] = s;
    }
    return;
  }
  const int tid = threadIdx.x;
  const int lane = tid & 63;
  const int wid = tid >> 6;
  const int bm = blockIdx.x * 128;
  const int wm = wid >> 2, wn = wid & 3;      // wave tile 64x64
  f32x4 acc[4][4] = {};
  float4 xv[2][2];
  auto loadX = [&](int kb) {
#pragma unroll
    for (int q = 0; q < 2; ++q) {
      int c = q * 512 + tid;
      int r = c >> 3, kc = c & 7;
      int gr = bm + r;
      xv[q][0] = make_float4(0.f, 0.f, 0.f, 0.f);
      xv[q][1] = xv[q][0];
      if (gr < M) {
        xv[q][0] = *(const float4*)&X[(size_t)gr * 256 + kb + kc * 8];
        xv[q][1] = *(const float4*)&X[(size_t)gr * 256 + kb + kc * 8 + 4];
      }
    }
  };
  loadX(0);
  for (int kb = 0; kb < 256; kb += 64) {
#pragma unroll
    for (int q = 0; q < 2; ++q) {
      int c = q * 512 + tid;
      int r = c >> 3, kc = c & 7;
      float vv[8] = {xv[q][0].x, xv[q][0].y, xv[q][0].z, xv[q][0].w,
                     xv[q][1].x, xv[q][1].y, xv[q][1].z, xv[q][1].w};
      u16x8 hv;
#pragma unroll
      for (int j = 0; j < 8; ++j) hv[j] = f2bf(vv[j]);
      *(u16x8*)(As + r * 128 + ((kc * 16) ^ ((r & 7) << 4))) = hv;
    }
#pragma unroll
    for (int q = 0; q < 4; ++q) {
      int c = q * 512 + tid;                   // chunk 0..2047
      int col = c >> 3;                        // 0..255
      int b = ((c & 7) * 16) ^ ((col & 7) << 4);
      gload_lds16(BT + (size_t)col * 256 + kb + (b >> 1),
                  Bs + (size_t)(q * 512 + (tid & ~63)) * 16);
    }
    __syncthreads();
    if (kb + 64 < 256) loadX(kb + 64);  // prefetch next x under MFMA
#pragma unroll
    for (int ks = 0; ks < 2; ++ks) {
      bf16x8 af[4], bfr[4];
      int bb = ks * 64 + (lane >> 4) * 16;
#pragma unroll
      for (int mi = 0; mi < 4; ++mi) {
        int row = wm * 64 + mi * 16 + (lane & 15);
        af[mi] = *(const bf16x8*)(As + row * 128 + (bb ^ ((row & 7) << 4)));
      }
#pragma unroll
      for (int ni = 0; ni < 4; ++ni) {
        int col = wn * 64 + ni * 16 + (lane & 15);
        bfr[ni] = *(const bf16x8*)(Bs + col * 128 + (bb ^ ((col & 7) << 4)));
      }
#pragma unroll
      for (int mi = 0; mi < 4; ++mi)
#pragma unroll
        for (int ni = 0; ni < 4; ++ni)
          acc[mi][ni] = __builtin_amdgcn_mfma_f32_16x16x32_bf16(af[mi], bfr[ni],
                                                                acc[mi][ni], 0, 0, 0);
    }
    __syncthreads();
  }
  // ---- epilogue: h1b write + fused alpha1 (heads 2wn, 2wn+1) ----
  const int h0 = 2 * wn, h1h = 2 * wn + 1;
  const int cl = lane & 15;
  const float as0 = a_src[h0 * 32 + cl],      ad0 = a_dst[h0 * 32 + cl];
  const float as1 = a_src[h0 * 32 + 16 + cl], ad1 = a_dst[h0 * 32 + 16 + cl];
  const float as2 = a_src[h1h * 32 + cl],      ad2 = a_dst[h1h * 32 + cl];
  const float as3 = a_src[h1h * 32 + 16 + cl], ad3 = a_dst[h1h * 32 + 16 + cl];
#pragma unroll
  for (int mi = 0; mi < 4; ++mi) {
    int gr0 = bm + wm * 64 + mi * 16 + (lane >> 4) * 4;
#pragma unroll
    for (int j = 0; j < 4; ++j) {
      int gr = gr0 + j;
#pragma unroll
      for (int ni = 0; ni < 4; ++ni) {
        int gc = wn * 64 + ni * 16 + cl;
        if (gr < M) h1b[(size_t)gr * 256 + gc] = f2bf(acc[mi][ni][j]);
      }
      float ps0 = acc[mi][0][j] * as0 + acc[mi][1][j] * as1;
      float pd0 = acc[mi][0][j] * ad0 + acc[mi][1][j] * ad1;
      float ps1 = acc[mi][2][j] * as2 + acc[mi][3][j] * as3;
      float pd1 = acc[mi][2][j] * ad2 + acc[mi][3][j] * ad3;
#pragma unroll
      for (int off = 1; off < 16; off <<= 1) {
        ps0 += __shfl_xor(ps0, off);
        pd0 += __shfl_xor(pd0, off);
        ps1 += __shfl_xor(ps1, off);
        pd1 += __shfl_xor(pd1, off);
      }
      if (cl == 0 && gr < M) {
        asrc[gr * 8 + h0] = ps0;
        adst[gr * 8 + h0] = pd0;
        asrc[gr * 8 + h1h] = ps1;
        adst[gr * 8 + h1h] = pd1;
      }
    }
  }
}

// ---------------- GEMM2 (1-term bf16, K=256) + fused alpha2 ----------------
__global__ __launch_bounds__(512) void k_gemm2(
    const unsigned short* __restrict__ A,    // helu [Mpad][256] bf16
    const unsigned short* __restrict__ B2T,  // [64][256] (hi)
    const float* __restrict__ a_src, const float* __restrict__ a_dst,
    unsigned short* __restrict__ C,          // h2b [M][64]
    float* __restrict__ asrc, float* __restrict__ adst,
    int M) {
  __shared__ __align__(128) char As[16384];  // [128r][128B]
  __shared__ __align__(128) char Bs[8192];   // [64c][128B]
  __shared__ float red[2][128][2];           // [wn][row][ps/pd]
  const int tid = threadIdx.x;
  const int lane = tid & 63;
  const int wid = tid >> 6;
  const int bm = blockIdx.x * 128;
  const int wm = wid >> 1, wn = wid & 1;     // wave tile 32x32
  f32x4 acc[2][2] = {};
  for (int kb = 0; kb < 256; kb += 64) {
#pragma unroll
    for (int q = 0; q < 2; ++q) {
      int c = q * 512 + tid;
      int r = c >> 3;
      int b = ((c & 7) * 16) ^ ((r & 7) << 4);
      gload_lds16(A + (size_t)(bm + r) * 256 + kb + (b >> 1),
                  As + (size_t)(q * 512 + (tid & ~63)) * 16);
    }
    {
      int c = tid;  // 512 chunks
      int col = c >> 3;
      int b = ((c & 7) * 16) ^ ((col & 7) << 4);
      gload_lds16(B2T + (size_t)col * 256 + kb + (b >> 1),
                  Bs + (size_t)(tid & ~63) * 16);
    }
    __syncthreads();
#pragma unroll
    for (int ks = 0; ks < 2; ++ks) {
      bf16x8 af[2], bfr[2];
      int bb = ks * 64 + (lane >> 4) * 16;
#pragma unroll
      for (int mi = 0; mi < 2; ++mi) {
        int row = wm * 32 + mi * 16 + (lane & 15);
        af[mi] = *(const bf16x8*)(As + row * 128 + (bb ^ ((row & 7) << 4)));
      }
#pragma unroll
      for (int ni = 0; ni < 2; ++ni) {
        int col = wn * 32 + ni * 16 + (lane & 15);
        bfr[ni] = *(const bf16x8*)(Bs + col * 128 + (bb ^ ((col & 7) << 4)));
      }
#pragma unroll
      for (int mi = 0; mi < 2; ++mi)
#pragma unroll
        for (int ni = 0; ni < 2; ++ni)
          acc[mi][ni] = __builtin_amdgcn_mfma_f32_16x16x32_bf16(af[mi], bfr[ni],
                                                                acc[mi][ni], 0, 0, 0);
    }
    __syncthreads();
  }
  const int cl = lane & 15;
  const float a_s0 = a_src[wn * 32 + cl],      a_d0 = a_dst[wn * 32 + cl];
  const float a_s1 = a_src[wn * 32 + 16 + cl], a_d1 = a_dst[wn * 32 + 16 + cl];
#pragma unroll
  for (int mi = 0; mi < 2; ++mi) {
    int rl0 = wm * 32 + mi * 16 + (lane >> 4) * 4;
#pragma unroll
    for (int j = 0; j < 4; ++j) {
      int rl = rl0 + j;
      int gr = bm + rl;
#pragma unroll
      for (int ni = 0; ni < 2; ++ni) {
        int gc = wn * 32 + ni * 16 + cl;
        if (gr < M) C[(size_t)gr * 64 + gc] = f2bf(acc[mi][ni][j]);
      }
      float ps = acc[mi][0][j] * a_s0 + acc[mi][1][j] * a_s1;
      float pd = acc[mi][0][j] * a_d0 + acc[mi][1][j] * a_d1;
#pragma unroll
      for (int off = 1; off < 16; off <<= 1) {
        ps += __shfl_xor(ps, off);
        pd += __shfl_xor(pd, off);
      }
      if (cl == 0) {
        red[wn][rl][0] = ps;
        red[wn][rl][1] = pd;
      }
    }
  }
  __syncthreads();
  if (tid < 128) {
    int gr = bm + tid;
    if (gr < M) {
      asrc[gr] = red[0][tid][0] + red[1][tid][0];
      adst[gr] = red[0][tid][1] + red[1][tid][1];
    }
  }
}

// ---------------- layer-1 aggregation: 2 edge slots x 32 lanes, batched phases ----------------
__global__ void k_agg1(const int* __restrict__ offs, const int* __restrict__ csr_src,
                       const unsigned short* __restrict__ h1b, const float* __restrict__ asrc,
                       const float* __restrict__ adst, const float* __restrict__ b1,
                       int n, unsigned short* __restrict__ helu) {
  int wave = (blockIdx.x * blockDim.x + threadIdx.x) >> 6;
  int lane = threadIdx.x & 63;
  if (wave >= n) return;
  int wv = __builtin_amdgcn_readfirstlane(wave);
  const int es = lane >> 5;   // edge slot 0..1
  const int cg = lane & 31;   // channel octet
  const int hh = cg >> 2;     // head
  float ad = adst[wv * 8 + hh];
  int b = offs[wv], e2 = offs[wv + 1];
  float ssum = 0.f;
  float acc[8] = {};
  int i = b;
  for (; i + 7 < e2; i += 8) {
    int s[4];
#pragma unroll
    for (int u = 0; u < 4; ++u) s[u] = csr_src[i + 2 * u + es];
    u16x8 r[4];
    float as_[4];
#pragma unroll
    for (int u = 0; u < 4; ++u) {
      r[u] = *(const u16x8*)&h1b[(size_t)s[u] * D1 + cg * 8];
      as_[u] = asrc[s[u] * 8 + hh];
    }
#pragma unroll
    for (int u = 0; u < 4; ++u) {
      float w = __expf(lrelu(as_[u] + ad));
      ssum += w;
#pragma unroll
      for (int j = 0; j < 8; ++j) acc[j] += w * bf2f(r[u][j]);
    }
  }
  for (; i < e2; i += 2) {
    int idx = i + es;
    bool act = idx < e2;
    int s = csr_src[act ? idx : e2 - 1];
    u16x8 r = *(const u16x8*)&h1b[(size_t)s * D1 + cg * 8];
    float w = act ? __expf(lrelu(asrc[s * 8 + hh] + ad)) : 0.f;
    ssum += w;
#pragma unroll
    for (int j = 0; j < 8; ++j) acc[j] += w * bf2f(r[j]);
  }
  ssum += __shfl_xor(ssum, 32);
#pragma unroll
  for (int j = 0; j < 8; ++j) acc[j] += __shfl_xor(acc[j], 32);
  if (lane < 32) {
    float rr = 1.f / ssum;
    float4 bb0 = *(const float4*)&b1[cg * 8];
    float4 bb1 = *(const float4*)&b1[cg * 8 + 4];
    float bbv[8] = {bb0.x, bb0.y, bb0.z, bb0.w, bb1.x, bb1.y, bb1.z, bb1.w};
    u16x8 o;
#pragma unroll
    for (int j = 0; j < 8; ++j) o[j] = f2bf(elu1(acc[j] * rr + bbv[j]));
    *(u16x8*)&helu[(size_t)wave * D1 + cg * 8] = o;
  }
}

// ---------------- layer-2 aggregation: 8 edge slots x 8 lanes, batched ----------------
__global__ void k_agg2(const int* __restrict__ offs, const int* __restrict__ csr_src,
                       const unsigned short* __restrict__ h2b, const float* __restrict__ asrc,
                       const float* __restrict__ adst, const float* __restrict__ b2,
                       int n, float* __restrict__ out) {
  int wave = (blockIdx.x * blockDim.x + threadIdx.x) >> 6;
  int lane = threadIdx.x & 63;
  if (wave >= n) return;
  int wv = __builtin_amdgcn_readfirstlane(wave);
  float ad = adst[wv];
  int b = offs[wv], e2 = offs[wv + 1];
  const int es = lane >> 3;  // edge slot 0..7
  const int cg = lane & 7;   // channel octet 0..7
  float ssum = 0.f;
  float acc[8] = {};
  int i = b;
  for (; i + 15 < e2; i += 16) {
    int s0 = csr_src[i + es], s1 = csr_src[i + 8 + es];
    u16x8 r0 = *(const u16x8*)&h2b[(size_t)s0 * ODIM + cg * 8];
    u16x8 r1 = *(const u16x8*)&h2b[(size_t)s1 * ODIM + cg * 8];
    float a0 = asrc[s0], a1 = asrc[s1];
    float w0 = __expf(lrelu(a0 + ad));
    float w1 = __expf(lrelu(a1 + ad));
    ssum += w0 + w1;
#pragma unroll
    for (int j = 0; j < 8; ++j) acc[j] += w0 * bf2f(r0[j]) + w1 * bf2f(r1[j]);
  }
  for (; i < e2; i += 8) {
    int idx = i + es;
    bool act = idx < e2;
    int s = csr_src[act ? idx : e2 - 1];
    u16x8 r = *(const u16x8*)&h2b[(size_t)s * ODIM + cg * 8];
    float w = act ? __expf(lrelu(asrc[s] + ad)) : 0.f;
    ssum += w;
#pragma unroll
    for (int j = 0; j < 8; ++j) acc[j] += w * bf2f(r[j]);
  }
#pragma unroll
  for (int off = 8; off < 64; off <<= 1) {
    ssum += __shfl_xor(ssum, off);
#pragma unroll
    for (int j = 0; j < 8; ++j) acc[j] += __shfl_xor(acc[j], off);
  }
  if (lane < 8) {
    float r = 1.f / ssum;
    float4 bb0 = *(const float4*)&b2[cg * 8];
    float4 bb1 = *(const float4*)&b2[cg * 8 + 4];
    float4 o0, o1;
    o0.x = acc[0] * r + bb0.x; o0.y = acc[1] * r + bb0.y;
    o0.z = acc[2] * r + bb0.z; o0.w = acc[3] * r + bb0.w;
    o1.x = acc[4] * r + bb1.x; o1.y = acc[5] * r + bb1.y;
    o1.z = acc[6] * r + bb1.z; o1.w = acc[7] * r + bb1.w;
    *(float4*)&out[(size_t)wave * ODIM + cg * 8] = o0;
    *(float4*)&out[(size_t)wave * ODIM + cg * 8 + 4] = o1;
  }
}

extern "C" void kernel_launch(void* const* d_in, const int* in_sizes, int n_in,
                              void* d_out, int out_size, void* d_ws, size_t ws_size,
                              hipStream_t stream) {
  const float* x      = (const float*)d_in[0];
  const int* eidx     = (const int*)d_in[1];
  const float* W1     = (const float*)d_in[2];
  const float* asrc1w = (const float*)d_in[3];
  const float* adst1w = (const float*)d_in[4];
  const float* b1     = (const float*)d_in[5];
  const float* W2     = (const float*)d_in[6];
  const float* asrc2w = (const float*)d_in[7];
  const float* adst2w = (const float*)d_in[8];
  const float* b2     = (const float*)d_in[9];
  float* out = (float*)d_out;

  const int N = in_sizes[0] / D1;     // 50000
  const int E = in_sizes[1] / 2;      // 800000
  const int TE = E + N;
  const int* src = eidx;
  const int* dst = eidx + E;
  const int Mblk = (N + 127) / 128;   // 391
  const int Mpad = Mblk * 128;        // 50048
  const int nb_n = (N + 255) / 256;   // 196
  const int nb_te = (TE + 255) / 256;
  const int nb_sc = (TE + 511) / 512; // scatter blocks (512 thr)

  // ---- workspace carve-up ----
  char* ws = (char*)d_ws;
  size_t off = 0;
  auto carve = [&](size_t bytes) -> char* {
    char* p = ws + off;
    off = (off + bytes + 255) & ~(size_t)255;
    return p;
  };
  unsigned short* helu = (unsigned short*)carve((size_t)Mpad * D1 * 2);   // 25.6 MB
  unsigned short* h1b  = (unsigned short*)carve((size_t)Mpad * D1 * 2);   // 25.6 MB
  unsigned short* h2b  = (unsigned short*)carve((size_t)N * ODIM * 2);    // 6.4 MB
  unsigned short* BT1  = (unsigned short*)carve((size_t)256 * 256 * 2);
  unsigned short* B2T2 = (unsigned short*)carve((size_t)64 * 256 * 2);
  float* asrc1 = (float*)carve((size_t)N * HEADS * 4);
  float* adst1 = (float*)carve((size_t)N * HEADS * 4);
  float* asrc2 = (float*)carve((size_t)N * 4);
  float* adst2 = (float*)carve((size_t)N * 4);
  // zero region: deg | tstate | ticket  (single memset)
  int* zr      = (int*)carve((size_t)(N + nb_n + 64) * 4);
  int* deg     = zr;
  int* tstate  = zr + N;
  int* ticket  = zr + N + nb_n;
  int* offs    = (int*)carve((size_t)(N + 1) * 4);
  int* erank   = (int*)carve((size_t)TE * 4);
  int* csr_src = (int*)carve((size_t)TE * 4);

  // ---- CSR build (hist captures ranks; scatter is atomic-free, overlapped with gemm1) ----
  hipMemsetAsync(zr, 0, (size_t)(N + nb_n + 1) * 4, stream);
  {
    const int HB = nb_te;
    const int PB = (65536 + 16384) / 256;  // 320 prep blocks
    k_hist_prep<<<HB + PB, 256, 0, stream>>>(dst, E, TE, deg, erank, W1, W2, BT1, B2T2, HB);
  }
  k_scan_lb<<<nb_n, 256, 0, stream>>>(deg, N, TE, offs, tstate, ticket);

  // ---- layer 1: GEMM + fused alpha1, overlapped with atomic-free scatter ----
  k_gemm1s<<<Mblk + nb_sc, 512, 0, stream>>>(x, BT1, asrc1w, adst1w, h1b, asrc1, adst1,
                                             N, Mblk, src, dst, E, TE, offs, erank, csr_src);
  k_agg1<<<(N + 3) / 4, 256, 0, stream>>>(offs, csr_src, h1b, asrc1, adst1, b1, N, helu);

  // ---- layer 2: GEMM + fused alpha2 ----
  k_gemm2<<<Mblk, 512, 0, stream>>>(helu, B2T2, asrc2w, adst2w, h2b, asrc2, adst2, N);
  k_agg2<<<(N + 3) / 4, 256, 0, stream>>>(offs, csr_src, h2b, asrc2, adst2, b2, N, out);
}